// Round 1
// baseline (807.871 us; speedup 1.0000x reference)
//
#include <hip/hip_runtime.h>
#include <math.h>

#define NBATCH 4
#define LTOK   4096
#define FD     64

// ---------------------------------------------------------------------------
// K1: GroupNorm stats. One block per (b,g): mean/rstd over 16 ch x 64x64 spatial.
// x layout: [b, h, w, c] (NHWC), group g = channels [16g, 16g+16).
__global__ void gn_stats_kernel(const float* __restrict__ x, float* __restrict__ stats) {
    const int bg = blockIdx.x;          // 0..15
    const int b = bg >> 2, g = bg & 3;
    float s = 0.f, ss = 0.f;
    for (int idx = threadIdx.x; idx < 65536; idx += 256) {
        int ij = idx >> 4, cc = idx & 15;
        float v = x[((size_t)b * LTOK + ij) * 64 + g * 16 + cc];
        s += v; ss += v * v;
    }
    for (int o = 32; o; o >>= 1) { s += __shfl_xor(s, o, 64); ss += __shfl_xor(ss, o, 64); }
    __shared__ float ps[4], pss[4];
    const int w = threadIdx.x >> 6;
    if ((threadIdx.x & 63) == 0) { ps[w] = s; pss[w] = ss; }
    __syncthreads();
    if (threadIdx.x == 0) {
        float S = ps[0] + ps[1] + ps[2] + ps[3];
        float SS = pss[0] + pss[1] + pss[2] + pss[3];
        float mean = S * (1.f / 65536.f);
        float var = SS * (1.f / 65536.f) - mean * mean;
        stats[bg * 2] = mean;
        stats[bg * 2 + 1] = rsqrtf(var + 1e-5f);
    }
}

// ---------------------------------------------------------------------------
// K2: GN-apply + conv1 (1x1) + the torch-faithful channels-first reshape:
// xs[b][o*64+i][j] = sum_c gn(x)[b,c,i,j] * w1[o][c] + b1[o].
// One block per (b, i).
__global__ void gn_conv1_kernel(const float* __restrict__ x, const float* __restrict__ stats,
                                const float* __restrict__ gg, const float* __restrict__ gb,
                                const float* __restrict__ w, const float* __restrict__ bias,
                                float* __restrict__ out) {
    const int b = blockIdx.x >> 6, i = blockIdx.x & 63;
    const int t = threadIdx.x;
    __shared__ float xn[64][65];    // [j][c]
    __shared__ float wsm[64][65];   // [o][c]
    for (int lin = t; lin < 4096; lin += 256) {
        int j = lin >> 6, c = lin & 63;
        float raw = x[(((size_t)b * 64 + i) * 64 + j) * 64 + c];
        int g = c >> 4;
        float mean = stats[(b * 4 + g) * 2];
        float rstd = stats[(b * 4 + g) * 2 + 1];
        xn[j][c] = (raw - mean) * rstd * gg[c] + gb[c];
        wsm[lin >> 6][lin & 63] = w[lin];   // conv1_w is [o][c]
    }
    __syncthreads();
    const int jj = t & 63, olo = (t >> 6) * 16;
    float acc[16];
#pragma unroll
    for (int oi = 0; oi < 16; oi++) acc[oi] = bias[olo + oi];
    for (int c = 0; c < 64; c++) {
        float xv = xn[jj][c];
#pragma unroll
        for (int oi = 0; oi < 16; oi++) acc[oi] += xv * wsm[olo + oi][c];
    }
#pragma unroll
    for (int oi = 0; oi < 16; oi++)
        out[((size_t)b * LTOK + (size_t)(olo + oi) * 64 + i) * 64 + jj] = acc[oi];
}

// ---------------------------------------------------------------------------
// Generic 64-wide matmul: out[t][o] = sum_f in[t][f] * W + bias.
// WT=false: W flat [f][o] (xs @ W convention).  WT=true: W flat [o][f] (conv).
template <bool WT>
__global__ void matmul64_kernel(const float* __restrict__ in, const float* __restrict__ W,
                                const float* __restrict__ bias, float* __restrict__ out) {
    __shared__ float xt[64][65];
    __shared__ float wt[64][65];   // always stored [f][o]
    const int t = threadIdx.x;
    const size_t tok0 = (size_t)blockIdx.x * 64;
    for (int lin = t; lin < 4096; lin += 256) {
        xt[lin >> 6][lin & 63] = in[tok0 * 64 + lin];
        int a = lin >> 6, c = lin & 63;
        if (WT) wt[c][a] = W[lin]; else wt[a][c] = W[lin];
    }
    __syncthreads();
    const int r = t >> 2, olo = (t & 3) * 16;
    float acc[16];
#pragma unroll
    for (int oi = 0; oi < 16; oi++) acc[oi] = bias[olo + oi];
    for (int f = 0; f < 64; f++) {
        float xv = xt[r][f];
#pragma unroll
        for (int oi = 0; oi < 16; oi++) acc[oi] += xv * wt[f][olo + oi];
    }
    float* op = out + (tok0 + r) * 64 + olo;
#pragma unroll
    for (int oi = 0; oi < 16; oi++) op[oi] = acc[oi];
}

// ---------------------------------------------------------------------------
// K3: fused Q/K/V projection (loads the xs tile once).
__global__ void qkv_kernel(const float* __restrict__ in,
                           const float* __restrict__ qw, const float* __restrict__ qb,
                           const float* __restrict__ kw, const float* __restrict__ kb,
                           const float* __restrict__ vw, const float* __restrict__ vb,
                           float* __restrict__ Qo, float* __restrict__ Ko, float* __restrict__ Vo) {
    __shared__ float xt[64][65];
    __shared__ float wt[64][65];
    const int t = threadIdx.x;
    const size_t tok0 = (size_t)blockIdx.x * 64;
    for (int lin = t; lin < 4096; lin += 256) xt[lin >> 6][lin & 63] = in[tok0 * 64 + lin];
    const int r = t >> 2, olo = (t & 3) * 16;
    const float* Wp[3] = {qw, kw, vw};
    const float* Bp[3] = {qb, kb, vb};
    float* Op[3] = {Qo, Ko, Vo};
#pragma unroll 1
    for (int ph = 0; ph < 3; ph++) {
        __syncthreads();                 // xt ready / previous phase's wt reads done
        for (int lin = t; lin < 4096; lin += 256) wt[lin >> 6][lin & 63] = Wp[ph][lin];
        __syncthreads();
        float acc[16];
#pragma unroll
        for (int oi = 0; oi < 16; oi++) acc[oi] = Bp[ph][olo + oi];
        for (int f = 0; f < 64; f++) {
            float xv = xt[r][f];
#pragma unroll
            for (int oi = 0; oi < 16; oi++) acc[oi] += xv * wt[f][olo + oi];
        }
        float* op = Op[ph] + (tok0 + r) * 64 + olo;
#pragma unroll
        for (int oi = 0; oi < 16; oi++) op[oi] = acc[oi];
    }
}

// ---------------------------------------------------------------------------
// K4: flash self-attention, fp32. Q-tile 128, K-tile 32, dh=32, 2 heads.
// Grid: (qt=32, bh=8). 256 threads; each owns a 4q x 4d output block and a
// 4q x 4k score block. Online softmax; S stored transposed [kj][qi].
__global__ __launch_bounds__(256) void flash_kernel(const float* __restrict__ Q,
                                                    const float* __restrict__ K,
                                                    const float* __restrict__ V,
                                                    float* __restrict__ Z) {
    const int qt = blockIdx.x;
    const int b = blockIdx.y >> 1, h = blockIdx.y & 1;
    const int t = threadIdx.x;
    __shared__ __align__(16) float Qs[128][36];
    __shared__ __align__(16) float Ks[32][36];
    __shared__ __align__(16) float Vs[32][36];
    __shared__ __align__(16) float Ss[32][132];   // [kj][qi]
    __shared__ float mrow[128], lrow[128], arow[128];

    const size_t base = ((size_t)b * LTOK) * 64 + h * 32;

    for (int lin = t; lin < 128 * 32; lin += 256) {
        int r = lin >> 5, d = lin & 31;
        Qs[r][d] = Q[base + (size_t)(qt * 128 + r) * 64 + d] * 0.125f;  // fold 1/sqrt(hid)=1/8
    }
    if (t < 128) { mrow[t] = -3.0e38f; lrow[t] = 0.0f; }

    const int qg = t >> 3, kg = t & 7;
    const int qi0 = qg * 4, kj0 = kg * 4, d0 = kg * 4;
    float oacc[4][4];
#pragma unroll
    for (int i = 0; i < 4; i++)
#pragma unroll
        for (int j = 0; j < 4; j++) oacc[i][j] = 0.0f;

    __syncthreads();

    for (int kt = 0; kt < 128; kt++) {
        for (int lin = t; lin < 32 * 32; lin += 256) {
            int r = lin >> 5, d = lin & 31;
            size_t ga = base + (size_t)(kt * 32 + r) * 64 + d;
            Ks[r][d] = K[ga];
            Vs[r][d] = V[ga];
        }
        __syncthreads();

        float s[4][4];
#pragma unroll
        for (int i = 0; i < 4; i++)
#pragma unroll
            for (int j = 0; j < 4; j++) s[i][j] = 0.0f;

        for (int dd = 0; dd < 32; dd += 4) {
            float4 qv[4], kv[4];
#pragma unroll
            for (int i = 0; i < 4; i++) qv[i] = *(const float4*)&Qs[qi0 + i][dd];
#pragma unroll
            for (int j = 0; j < 4; j++) kv[j] = *(const float4*)&Ks[kj0 + j][dd];
#pragma unroll
            for (int i = 0; i < 4; i++)
#pragma unroll
                for (int j = 0; j < 4; j++)
                    s[i][j] += qv[i].x * kv[j].x + qv[i].y * kv[j].y +
                               qv[i].z * kv[j].z + qv[i].w * kv[j].w;
        }
#pragma unroll
        for (int j = 0; j < 4; j++)
            *(float4*)&Ss[kj0 + j][qi0] = make_float4(s[0][j], s[1][j], s[2][j], s[3][j]);
        __syncthreads();

        if (t < 128) {   // one thread per query row: online softmax update
            float m_old = mrow[t];
            float mx = m_old;
            for (int kj = 0; kj < 32; kj++) mx = fmaxf(mx, Ss[kj][t]);
            float al = __expf(m_old - mx);
            float sum = 0.0f;
            for (int kj = 0; kj < 32; kj++) {
                float p = __expf(Ss[kj][t] - mx);
                Ss[kj][t] = p;
                sum += p;
            }
            mrow[t] = mx;
            lrow[t] = lrow[t] * al + sum;
            arow[t] = al;
        }
        __syncthreads();

#pragma unroll
        for (int i = 0; i < 4; i++) {
            float al = arow[qi0 + i];
#pragma unroll
            for (int j = 0; j < 4; j++) oacc[i][j] *= al;
        }
        for (int kj = 0; kj < 32; kj++) {
            float4 p = *(const float4*)&Ss[kj][qi0];
            float4 v = *(const float4*)&Vs[kj][d0];
            oacc[0][0] += p.x * v.x; oacc[0][1] += p.x * v.y; oacc[0][2] += p.x * v.z; oacc[0][3] += p.x * v.w;
            oacc[1][0] += p.y * v.x; oacc[1][1] += p.y * v.y; oacc[1][2] += p.y * v.z; oacc[1][3] += p.y * v.w;
            oacc[2][0] += p.z * v.x; oacc[2][1] += p.z * v.y; oacc[2][2] += p.z * v.z; oacc[2][3] += p.z * v.w;
            oacc[3][0] += p.w * v.x; oacc[3][1] += p.w * v.y; oacc[3][2] += p.w * v.z; oacc[3][3] += p.w * v.w;
        }
        __syncthreads();
    }

#pragma unroll
    for (int i = 0; i < 4; i++) {
        float inv = 1.0f / lrow[qi0 + i];
        float4 r = make_float4(oacc[i][0] * inv, oacc[i][1] * inv,
                               oacc[i][2] * inv, oacc[i][3] * inv);
        *(float4*)&Z[base + (size_t)(qt * 128 + qi0 + i) * 64 + d0] = r;
    }
}

// ---------------------------------------------------------------------------
// K5: LayerNorm(a) * g + b + res, optional exact GELU on the sum. Wave per token.
template <bool GELU>
__global__ void ln_kernel(const float* __restrict__ A, const float* __restrict__ g,
                          const float* __restrict__ bta, const float* __restrict__ R,
                          float* __restrict__ out) {
    const int tok = blockIdx.x * 4 + (threadIdx.x >> 6);
    const int lane = threadIdx.x & 63;
    const size_t idx = (size_t)tok * 64 + lane;
    float a = A[idx];
    float s = a;
    for (int o = 32; o; o >>= 1) s += __shfl_xor(s, o, 64);
    float mean = s * (1.f / 64.f);
    float d = a - mean;
    float v = d * d;
    for (int o = 32; o; o >>= 1) v += __shfl_xor(v, o, 64);
    float rstd = rsqrtf(v * (1.f / 64.f) + 1e-5f);
    float y = d * rstd * g[lane] + bta[lane] + R[idx];
    if (GELU) y = 0.5f * y * (1.0f + erff(y * 0.70710678118654752f));
    out[idx] = y;
}

// ---------------------------------------------------------------------------
// K6: cross-attn K/V from slots: kv[0][b][j][o]=K, kv[1][b][j][o]=V.
__global__ void kv_ca_kernel(const float* __restrict__ slots,
                             const float* __restrict__ kw, const float* __restrict__ kb,
                             const float* __restrict__ vw, const float* __restrict__ vb,
                             float* __restrict__ kv) {
    __shared__ float sl[2048];
    for (int i = threadIdx.x; i < 2048; i += 256) sl[i] = slots[i];
    __syncthreads();
    for (int idx = threadIdx.x; idx < 4096; idx += 256) {
        int which = idx >> 11, rem = idx & 2047, bj = rem >> 6, o = rem & 63;
        const float* W = which ? vw : kw;
        const float* Bb = which ? vb : kb;
        float acc = Bb[o];
        for (int c = 0; c < 64; c++) acc += sl[bj * 64 + c] * W[c * 64 + o];
        kv[idx] = acc;
    }
}

// ---------------------------------------------------------------------------
// K7: cross-attention (8 slots) — thread per token, K/V in LDS.
__global__ void ca_attend_kernel(const float* __restrict__ Qc, const float* __restrict__ kv,
                                 float* __restrict__ Z) {
    const int tok = blockIdx.x * 64 + threadIdx.x;   // 16 blocks per batch -> b uniform
    const int b = tok >> 12;
    __shared__ float kc[8][64], vc[8][64];
    for (int lin = threadIdx.x; lin < 512; lin += 64) {
        kc[lin >> 6][lin & 63] = kv[(size_t)b * 512 + lin];
        vc[lin >> 6][lin & 63] = kv[2048 + (size_t)b * 512 + lin];
    }
    __syncthreads();
    float q[64];
#pragma unroll
    for (int c = 0; c < 64; c++) q[c] = Qc[(size_t)tok * 64 + c];
#pragma unroll
    for (int h = 0; h < 2; h++) {
        float sarr[8];
        float mx = -3e38f;
#pragma unroll
        for (int j = 0; j < 8; j++) {
            float s = 0.f;
#pragma unroll
            for (int d = 0; d < 32; d++) s += q[h * 32 + d] * kc[j][h * 32 + d];
            s *= 0.125f;
            sarr[j] = s;
            mx = fmaxf(mx, s);
        }
        float sum = 0.f;
#pragma unroll
        for (int j = 0; j < 8; j++) { sarr[j] = __expf(sarr[j] - mx); sum += sarr[j]; }
        float inv = 1.f / sum;
#pragma unroll
        for (int d = 0; d < 32; d++) {
            float z = 0.f;
#pragma unroll
            for (int j = 0; j < 8; j++) z += sarr[j] * vc[j][h * 32 + d];
            Z[(size_t)tok * 64 + h * 32 + d] = z * inv;
        }
    }
}

// ---------------------------------------------------------------------------
extern "C" void kernel_launch(void* const* d_in, const int* in_sizes, int n_in,
                              void* d_out, int out_size, void* d_ws, size_t ws_size,
                              hipStream_t stream) {
    const float* x       = (const float*)d_in[0];
    const float* slots   = (const float*)d_in[1];
    const float* conv1_w = (const float*)d_in[2];
    const float* conv1_b = (const float*)d_in[3];
    const float* conv2_w = (const float*)d_in[4];
    const float* conv2_b = (const float*)d_in[5];
    const float* gn_g    = (const float*)d_in[6];
    const float* gn_b    = (const float*)d_in[7];
    const float* ln2_g   = (const float*)d_in[8];
    const float* ln2_b   = (const float*)d_in[9];
    const float* ln3_g   = (const float*)d_in[10];
    const float* ln3_b   = (const float*)d_in[11];
    const float* ln4_g   = (const float*)d_in[12];
    const float* ln4_b   = (const float*)d_in[13];
    const float* sa_qw   = (const float*)d_in[14];
    const float* sa_qb   = (const float*)d_in[15];
    const float* sa_kw   = (const float*)d_in[16];
    const float* sa_kb   = (const float*)d_in[17];
    const float* sa_vw   = (const float*)d_in[18];
    const float* sa_vb   = (const float*)d_in[19];
    const float* sa_ow   = (const float*)d_in[20];
    const float* sa_ob   = (const float*)d_in[21];
    const float* ca_qw   = (const float*)d_in[22];
    const float* ca_qb   = (const float*)d_in[23];
    const float* ca_kw   = (const float*)d_in[24];
    const float* ca_kb   = (const float*)d_in[25];
    const float* ca_vw   = (const float*)d_in[26];
    const float* ca_vb   = (const float*)d_in[27];
    const float* ca_ow   = (const float*)d_in[28];
    const float* ca_ob   = (const float*)d_in[29];
    const float* ff1_w   = (const float*)d_in[30];
    const float* ff1_b   = (const float*)d_in[31];

    float* ws = (float*)d_ws;
    const size_t NBUF = (size_t)NBATCH * LTOK * FD;   // 1,048,576 floats
    float* stats = ws;            // 32 floats
    float* kvca  = ws + 64;       // 4096 floats
    float* A  = ws + 8192;        // xs0 / xs2
    float* Bf = A + NBUF;         // q / t0 / qca / t1 / t2
    float* C  = Bf + NBUF;        // k / xs1 / xs3
    float* D  = C + NBUF;         // v
    float* E  = (float*)d_out;    // z scratch; fully overwritten by final conv2

    gn_stats_kernel<<<16, 256, 0, stream>>>(x, stats);
    gn_conv1_kernel<<<256, 256, 0, stream>>>(x, stats, gn_g, gn_b, conv1_w, conv1_b, A);
    qkv_kernel<<<256, 256, 0, stream>>>(A, sa_qw, sa_qb, sa_kw, sa_kb, sa_vw, sa_vb, Bf, C, D);
    flash_kernel<<<dim3(32, 8), 256, 0, stream>>>(Bf, C, D, E);
    matmul64_kernel<false><<<256, 256, 0, stream>>>(E, sa_ow, sa_ob, Bf);        // t0
    ln_kernel<true><<<4096, 256, 0, stream>>>(Bf, ln2_g, ln2_b, A, C);           // xs1 = gelu(LN(t0)+xs0)
    matmul64_kernel<false><<<256, 256, 0, stream>>>(C, ca_qw, ca_qb, Bf);        // qca
    kv_ca_kernel<<<1, 256, 0, stream>>>(slots, ca_kw, ca_kb, ca_vw, ca_vb, kvca);
    ca_attend_kernel<<<256, 64, 0, stream>>>(Bf, kvca, E);                       // zca
    matmul64_kernel<false><<<256, 256, 0, stream>>>(E, ca_ow, ca_ob, Bf);        // t1
    ln_kernel<false><<<4096, 256, 0, stream>>>(Bf, ln3_g, ln3_b, C, A);          // xs2 = LN(t1)+xs1
    matmul64_kernel<false><<<256, 256, 0, stream>>>(A, ff1_w, ff1_b, Bf);        // t2
    ln_kernel<false><<<4096, 256, 0, stream>>>(Bf, ln4_g, ln4_b, A, C);          // xs3 = LN(t2)+xs2
    matmul64_kernel<true><<<256, 256, 0, stream>>>(C, conv2_w, conv2_b, (float*)d_out);
}

// Round 2
// 371.712 us; speedup vs baseline: 2.1734x; 2.1734x over previous
//
#include <hip/hip_runtime.h>
#include <math.h>

#define NBATCH 4
#define LTOK   4096
#define FD     64

typedef __attribute__((ext_vector_type(8))) short short8v;   // 8 bf16 = 4 VGPR
typedef __attribute__((ext_vector_type(4))) float f32x4;

static __device__ inline uint32_t bf16r(float f) {           // f32 -> bf16 bits, RNE
    uint32_t x = __float_as_uint(f);
    return (x + 0x7fffu + ((x >> 16) & 1u)) >> 16;
}
static __device__ inline uint32_t pack2(float a, float b) {
    return bf16r(a) | (bf16r(b) << 16);
}

// ---------------------------------------------------------------------------
// K1: GroupNorm stats. One block per (b,g).
__global__ void gn_stats_kernel(const float* __restrict__ x, float* __restrict__ stats) {
    const int bg = blockIdx.x;
    const int b = bg >> 2, g = bg & 3;
    float s = 0.f, ss = 0.f;
    for (int idx = threadIdx.x; idx < 65536; idx += 256) {
        int ij = idx >> 4, cc = idx & 15;
        float v = x[((size_t)b * LTOK + ij) * 64 + g * 16 + cc];
        s += v; ss += v * v;
    }
    for (int o = 32; o; o >>= 1) { s += __shfl_xor(s, o, 64); ss += __shfl_xor(ss, o, 64); }
    __shared__ float ps[4], pss[4];
    const int w = threadIdx.x >> 6;
    if ((threadIdx.x & 63) == 0) { ps[w] = s; pss[w] = ss; }
    __syncthreads();
    if (threadIdx.x == 0) {
        float S = ps[0] + ps[1] + ps[2] + ps[3];
        float SS = pss[0] + pss[1] + pss[2] + pss[3];
        float mean = S * (1.f / 65536.f);
        float var = SS * (1.f / 65536.f) - mean * mean;
        stats[bg * 2] = mean;
        stats[bg * 2 + 1] = rsqrtf(var + 1e-5f);
    }
}

// ---------------------------------------------------------------------------
// K2: GN-apply + conv1 + channels-first reshape.
__global__ void gn_conv1_kernel(const float* __restrict__ x, const float* __restrict__ stats,
                                const float* __restrict__ gg, const float* __restrict__ gb,
                                const float* __restrict__ w, const float* __restrict__ bias,
                                float* __restrict__ out) {
    const int b = blockIdx.x >> 6, i = blockIdx.x & 63;
    const int t = threadIdx.x;
    __shared__ float xn[64][65];
    __shared__ float wsm[64][65];
    for (int lin = t; lin < 4096; lin += 256) {
        int j = lin >> 6, c = lin & 63;
        float raw = x[(((size_t)b * 64 + i) * 64 + j) * 64 + c];
        int g = c >> 4;
        float mean = stats[(b * 4 + g) * 2];
        float rstd = stats[(b * 4 + g) * 2 + 1];
        xn[j][c] = (raw - mean) * rstd * gg[c] + gb[c];
        wsm[lin >> 6][lin & 63] = w[lin];
    }
    __syncthreads();
    const int jj = t & 63, olo = (t >> 6) * 16;
    float acc[16];
#pragma unroll
    for (int oi = 0; oi < 16; oi++) acc[oi] = bias[olo + oi];
    for (int c = 0; c < 64; c++) {
        float xv = xn[jj][c];
#pragma unroll
        for (int oi = 0; oi < 16; oi++) acc[oi] += xv * wsm[olo + oi][c];
    }
#pragma unroll
    for (int oi = 0; oi < 16; oi++)
        out[((size_t)b * LTOK + (size_t)(olo + oi) * 64 + i) * 64 + jj] = acc[oi];
}

// ---------------------------------------------------------------------------
// Generic 64-wide matmul (fp32 in/out).
template <bool WT>
__global__ void matmul64_kernel(const float* __restrict__ in, const float* __restrict__ W,
                                const float* __restrict__ bias, float* __restrict__ out) {
    __shared__ float xt[64][65];
    __shared__ float wt[64][65];
    const int t = threadIdx.x;
    const size_t tok0 = (size_t)blockIdx.x * 64;
    for (int lin = t; lin < 4096; lin += 256) {
        xt[lin >> 6][lin & 63] = in[tok0 * 64 + lin];
        int a = lin >> 6, c = lin & 63;
        if (WT) wt[c][a] = W[lin]; else wt[a][c] = W[lin];
    }
    __syncthreads();
    const int r = t >> 2, olo = (t & 3) * 16;
    float acc[16];
#pragma unroll
    for (int oi = 0; oi < 16; oi++) acc[oi] = bias[olo + oi];
    for (int f = 0; f < 64; f++) {
        float xv = xt[r][f];
#pragma unroll
        for (int oi = 0; oi < 16; oi++) acc[oi] += xv * wt[f][olo + oi];
    }
    float* op = out + (tok0 + r) * 64 + olo;
#pragma unroll
    for (int oi = 0; oi < 16; oi++) op[oi] = acc[oi];
}

// ---------------------------------------------------------------------------
// K3: fused Q/K/V projection -> bf16 outputs. Q pre-scaled by 0.125*log2(e).
__global__ void qkv_kernel(const float* __restrict__ in,
                           const float* __restrict__ qw, const float* __restrict__ qb,
                           const float* __restrict__ kw, const float* __restrict__ kb,
                           const float* __restrict__ vw, const float* __restrict__ vb,
                           ushort* __restrict__ Qo, ushort* __restrict__ Ko, ushort* __restrict__ Vo) {
    __shared__ float xt[64][65];
    __shared__ float wt[64][65];
    const int t = threadIdx.x;
    const size_t tok0 = (size_t)blockIdx.x * 64;
    for (int lin = t; lin < 4096; lin += 256) xt[lin >> 6][lin & 63] = in[tok0 * 64 + lin];
    const int r = t >> 2, olo = (t & 3) * 16;
    const float* Wp[3] = {qw, kw, vw};
    const float* Bp[3] = {qb, kb, vb};
    ushort* Op[3] = {Qo, Ko, Vo};
#pragma unroll 1
    for (int ph = 0; ph < 3; ph++) {
        __syncthreads();
        for (int lin = t; lin < 4096; lin += 256) wt[lin >> 6][lin & 63] = Wp[ph][lin];
        __syncthreads();
        float acc[16];
#pragma unroll
        for (int oi = 0; oi < 16; oi++) acc[oi] = Bp[ph][olo + oi];
        for (int f = 0; f < 64; f++) {
            float xv = xt[r][f];
#pragma unroll
            for (int oi = 0; oi < 16; oi++) acc[oi] += xv * wt[f][olo + oi];
        }
        const float sc = (ph == 0) ? 0.180336880111f : 1.0f;   // 0.125 * log2(e)
        uint32_t u[8];
#pragma unroll
        for (int i = 0; i < 8; i++) u[i] = pack2(acc[2 * i] * sc, acc[2 * i + 1] * sc);
        ushort* op = Op[ph] + ((size_t)(tok0 + r)) * 64 + olo;
        *(uint4*)op = make_uint4(u[0], u[1], u[2], u[3]);
        *(uint4*)(op + 8) = make_uint4(u[4], u[5], u[6], u[7]);
    }
}

// ---------------------------------------------------------------------------
// K4: MFMA flash self-attention (bf16 in, fp32 out).
// Block: 4 waves x 16 q-rows (QBLK=64). Grid (64 qtiles, 8 bh). KBLK=64.
// S^T = mfma(K, Q): per-lane col q = l&15, rows k = 16*tk + 4*(l>>4)+reg.
// Softmax reduce = per-lane regs + shfl_xor(16,32). P -> swizzled per-wave LDS.
// PV: Z = mfma(P, V^T-in-LDS).
__global__ __launch_bounds__(256) void flash_mfma(const ushort* __restrict__ Q,
                                                  const ushort* __restrict__ K,
                                                  const ushort* __restrict__ V,
                                                  float* __restrict__ Z) {
    const int qt = blockIdx.x;            // 0..63
    const int bh = blockIdx.y;            // 0..7
    const int b = bh >> 1, h = bh & 1;
    const int t = threadIdx.x;
    const int w = t >> 6, l = t & 63;
    const int lg = l >> 4, lq = l & 15;

    __shared__ ushort Ks[64 * 32];        // [k][dh], swz ^((k&7)<<3)   (ushort units)
    __shared__ ushort VT[32 * 64];        // [dh][k], swz ^((dh&7)<<3)
    __shared__ ushort Pl[4 * 16 * 64];    // per-wave [q][k], swz ^((q&7)<<3)

    const size_t base = (size_t)b * LTOK * 64 + h * 32;

    // Q fragment (B operand): lane holds Q[w*16+lq][8*lg + 0..7]
    const short8v qf = *(const short8v*)(Q + base + (size_t)(qt * 64 + w * 16 + lq) * 64 + 8 * lg);

    f32x4 accZ[2];
#pragma unroll
    for (int d = 0; d < 2; d++) accZ[d] = (f32x4){0.f, 0.f, 0.f, 0.f};
    float mreg = -3.0e38f, lreg = 0.0f;
    const f32x4 zero4 = {0.f, 0.f, 0.f, 0.f};

    for (int kt = 0; kt < 64; kt++) {
        // --- stage K tile [64][32] (one b128 per thread, swizzled) ---
        {
            const int krow = t >> 2, dg = t & 3;
            const uint4 kq = *(const uint4*)(K + base + (size_t)(kt * 64 + krow) * 64 + dg * 8);
            *(uint4*)(Ks + ((((krow << 5) + dg * 8)) ^ ((krow & 7) << 3))) = kq;
        }
        // --- stage V^T [32][64] (ushort2 coalesced reads, scattered b16 writes) ---
#pragma unroll
        for (int e = 0; e < 4; e++) {
            const int lin = e * 256 + t;                  // 0..1023
            const int vk = lin >> 4, vd = (lin & 15) * 2;
            const ushort2 vv = *(const ushort2*)(V + base + (size_t)(kt * 64 + vk) * 64 + vd);
            VT[(((vd) << 6) + vk) ^ ((vd & 7) << 3)] = vv.x;
            VT[(((vd + 1) << 6) + vk) ^ (((vd + 1) & 7) << 3)] = vv.y;
        }
        __syncthreads();

        // --- S^T: 4 MFMAs (k-tiles) ---
        f32x4 s4[4];
#pragma unroll
        for (int tk = 0; tk < 4; tk++) {
            const int krow = tk * 16 + lq;
            const short8v aK = *(const short8v*)(Ks + ((((krow << 5) + lg * 8)) ^ ((lq & 7) << 3)));
            s4[tk] = __builtin_amdgcn_mfma_f32_16x16x32_bf16(aK, qf, zero4, 0, 0, 0);
        }

        // --- online softmax (per-lane 16 regs for column q=lq) ---
        float mx = s4[0][0];
#pragma unroll
        for (int tk = 0; tk < 4; tk++)
#pragma unroll
            for (int r = 0; r < 4; r++) mx = fmaxf(mx, s4[tk][r]);
        mx = fmaxf(mx, __shfl_xor(mx, 16, 64));
        mx = fmaxf(mx, __shfl_xor(mx, 32, 64));
        const float mnew = fmaxf(mreg, mx);
        const float alpha = exp2f(mreg - mnew);
        mreg = mnew;

        float psum = 0.f;
        uint32_t pw[8];
#pragma unroll
        for (int tk = 0; tk < 4; tk++) {
            float p0 = exp2f(s4[tk][0] - mnew);
            float p1 = exp2f(s4[tk][1] - mnew);
            float p2 = exp2f(s4[tk][2] - mnew);
            float p3 = exp2f(s4[tk][3] - mnew);
            psum += (p0 + p1) + (p2 + p3);
            pw[2 * tk]     = pack2(p0, p1);
            pw[2 * tk + 1] = pack2(p2, p3);
        }
        psum += __shfl_xor(psum, 16, 64);
        psum += __shfl_xor(psum, 32, 64);
        lreg = lreg * alpha + psum;

        // --- write P (bf16, swizzled, per-wave region) ---
        const int pb = w << 10;
#pragma unroll
        for (int tk = 0; tk < 4; tk++) {
            const int idx = (((lq << 6) + tk * 16 + lg * 4)) ^ ((lq & 7) << 3);
            *(uint2*)(Pl + pb + idx) = make_uint2(pw[2 * tk], pw[2 * tk + 1]);
        }

        // --- rescale accumulator (alpha indexed by D-row q = 4*lg+r) ---
#pragma unroll
        for (int r = 0; r < 4; r++) {
            const float ar = __shfl(alpha, lg * 4 + r, 64);
            accZ[0][r] *= ar;
            accZ[1][r] *= ar;
        }

        // --- PV: Z += P * V ---
#pragma unroll
        for (int kc = 0; kc < 2; kc++) {
            const int ia = (((lq << 6) + kc * 32 + lg * 8)) ^ ((lq & 7) << 3);
            const short8v aP = *(const short8v*)(Pl + pb + ia);
#pragma unroll
            for (int dt = 0; dt < 2; dt++) {
                const int ib = ((((dt * 16 + lq) << 6) + kc * 32 + lg * 8)) ^ ((lq & 7) << 3);
                const short8v bV = *(const short8v*)(VT + ib);
                accZ[dt] = __builtin_amdgcn_mfma_f32_16x16x32_bf16(aP, bV, accZ[dt], 0, 0, 0);
            }
        }
        __syncthreads();
    }

    // --- epilogue: divide by l, write fp32 Z ---
    const float inv = 1.0f / lreg;
#pragma unroll
    for (int r = 0; r < 4; r++) {
        const float ivr = __shfl(inv, lg * 4 + r, 64);
        const int qrow = qt * 64 + w * 16 + lg * 4 + r;
#pragma unroll
        for (int dt = 0; dt < 2; dt++)
            Z[base + (size_t)qrow * 64 + dt * 16 + lq] = accZ[dt][r] * ivr;
    }
}

// ---------------------------------------------------------------------------
// K5: LayerNorm + residual (+ optional exact GELU).
template <bool GELU>
__global__ void ln_kernel(const float* __restrict__ A, const float* __restrict__ g,
                          const float* __restrict__ bta, const float* __restrict__ R,
                          float* __restrict__ out) {
    const int tok = blockIdx.x * 4 + (threadIdx.x >> 6);
    const int lane = threadIdx.x & 63;
    const size_t idx = (size_t)tok * 64 + lane;
    float a = A[idx];
    float s = a;
    for (int o = 32; o; o >>= 1) s += __shfl_xor(s, o, 64);
    float mean = s * (1.f / 64.f);
    float d = a - mean;
    float v = d * d;
    for (int o = 32; o; o >>= 1) v += __shfl_xor(v, o, 64);
    float rstd = rsqrtf(v * (1.f / 64.f) + 1e-5f);
    float y = d * rstd * g[lane] + bta[lane] + R[idx];
    if (GELU) y = 0.5f * y * (1.0f + erff(y * 0.70710678118654752f));
    out[idx] = y;
}

// ---------------------------------------------------------------------------
// K6: cross-attn K/V from slots.
__global__ void kv_ca_kernel(const float* __restrict__ slots,
                             const float* __restrict__ kw, const float* __restrict__ kb,
                             const float* __restrict__ vw, const float* __restrict__ vb,
                             float* __restrict__ kv) {
    __shared__ float sl[2048];
    for (int i = threadIdx.x; i < 2048; i += 256) sl[i] = slots[i];
    __syncthreads();
    for (int idx = threadIdx.x; idx < 4096; idx += 256) {
        int which = idx >> 11, rem = idx & 2047, bj = rem >> 6, o = rem & 63;
        const float* W = which ? vw : kw;
        const float* Bb = which ? vb : kb;
        float acc = Bb[o];
        for (int c = 0; c < 64; c++) acc += sl[bj * 64 + c] * W[c * 64 + o];
        kv[idx] = acc;
    }
}

// ---------------------------------------------------------------------------
// K7: cross-attention (8 slots).
__global__ void ca_attend_kernel(const float* __restrict__ Qc, const float* __restrict__ kv,
                                 float* __restrict__ Z) {
    const int tok = blockIdx.x * 64 + threadIdx.x;
    const int b = tok >> 12;
    __shared__ float kc[8][64], vc[8][64];
    for (int lin = threadIdx.x; lin < 512; lin += 64) {
        kc[lin >> 6][lin & 63] = kv[(size_t)b * 512 + lin];
        vc[lin >> 6][lin & 63] = kv[2048 + (size_t)b * 512 + lin];
    }
    __syncthreads();
    float q[64];
#pragma unroll
    for (int c = 0; c < 64; c++) q[c] = Qc[(size_t)tok * 64 + c];
#pragma unroll
    for (int h = 0; h < 2; h++) {
        float sarr[8];
        float mx = -3e38f;
#pragma unroll
        for (int j = 0; j < 8; j++) {
            float s = 0.f;
#pragma unroll
            for (int d = 0; d < 32; d++) s += q[h * 32 + d] * kc[j][h * 32 + d];
            s *= 0.125f;
            sarr[j] = s;
            mx = fmaxf(mx, s);
        }
        float sum = 0.f;
#pragma unroll
        for (int j = 0; j < 8; j++) { sarr[j] = __expf(sarr[j] - mx); sum += sarr[j]; }
        float inv = 1.f / sum;
#pragma unroll
        for (int d = 0; d < 32; d++) {
            float z = 0.f;
#pragma unroll
            for (int j = 0; j < 8; j++) z += sarr[j] * vc[j][h * 32 + d];
            Z[(size_t)tok * 64 + h * 32 + d] = z * inv;
        }
    }
}

// ---------------------------------------------------------------------------
extern "C" void kernel_launch(void* const* d_in, const int* in_sizes, int n_in,
                              void* d_out, int out_size, void* d_ws, size_t ws_size,
                              hipStream_t stream) {
    const float* x       = (const float*)d_in[0];
    const float* slots   = (const float*)d_in[1];
    const float* conv1_w = (const float*)d_in[2];
    const float* conv1_b = (const float*)d_in[3];
    const float* conv2_w = (const float*)d_in[4];
    const float* conv2_b = (const float*)d_in[5];
    const float* gn_g    = (const float*)d_in[6];
    const float* gn_b    = (const float*)d_in[7];
    const float* ln2_g   = (const float*)d_in[8];
    const float* ln2_b   = (const float*)d_in[9];
    const float* ln3_g   = (const float*)d_in[10];
    const float* ln3_b   = (const float*)d_in[11];
    const float* ln4_g   = (const float*)d_in[12];
    const float* ln4_b   = (const float*)d_in[13];
    const float* sa_qw   = (const float*)d_in[14];
    const float* sa_qb   = (const float*)d_in[15];
    const float* sa_kw   = (const float*)d_in[16];
    const float* sa_kb   = (const float*)d_in[17];
    const float* sa_vw   = (const float*)d_in[18];
    const float* sa_vb   = (const float*)d_in[19];
    const float* sa_ow   = (const float*)d_in[20];
    const float* sa_ob   = (const float*)d_in[21];
    const float* ca_qw   = (const float*)d_in[22];
    const float* ca_qb   = (const float*)d_in[23];
    const float* ca_kw   = (const float*)d_in[24];
    const float* ca_kb   = (const float*)d_in[25];
    const float* ca_vw   = (const float*)d_in[26];
    const float* ca_vb   = (const float*)d_in[27];
    const float* ca_ow   = (const float*)d_in[28];
    const float* ca_ob   = (const float*)d_in[29];
    const float* ff1_w   = (const float*)d_in[30];
    const float* ff1_b   = (const float*)d_in[31];

    float* ws = (float*)d_ws;
    const size_t NBUF = (size_t)NBATCH * LTOK * FD;   // 1,048,576 elements
    float* stats = ws;            // 32 floats
    float* kvca  = ws + 64;       // 4096 floats
    float* A  = ws + 8192;        // xs0 / xs2
    float* Bf = A + NBUF;         // bf16 Q lives here first, then t0/qca/t1/t2 (f32)
    float* C  = Bf + NBUF;        // xs1 / xs3
    float* D  = C + NBUF;         // bf16 K (first half) + bf16 V (second half)
    float* E  = (float*)d_out;    // z scratch; fully overwritten by final conv2

    ushort* Qb = (ushort*)Bf;
    ushort* Kb = (ushort*)D;
    ushort* Vb = Kb + NBUF;

    gn_stats_kernel<<<16, 256, 0, stream>>>(x, stats);
    gn_conv1_kernel<<<256, 256, 0, stream>>>(x, stats, gn_g, gn_b, conv1_w, conv1_b, A);
    qkv_kernel<<<256, 256, 0, stream>>>(A, sa_qw, sa_qb, sa_kw, sa_kb, sa_vw, sa_vb, Qb, Kb, Vb);
    flash_mfma<<<dim3(64, 8), 256, 0, stream>>>(Qb, Kb, Vb, E);
    matmul64_kernel<false><<<256, 256, 0, stream>>>(E, sa_ow, sa_ob, Bf);        // t0
    ln_kernel<true><<<4096, 256, 0, stream>>>(Bf, ln2_g, ln2_b, A, C);           // xs1
    matmul64_kernel<false><<<256, 256, 0, stream>>>(C, ca_qw, ca_qb, Bf);        // qca
    kv_ca_kernel<<<1, 256, 0, stream>>>(slots, ca_kw, ca_kb, ca_vw, ca_vb, kvca);
    ca_attend_kernel<<<256, 64, 0, stream>>>(Bf, kvca, E);                       // zca
    matmul64_kernel<false><<<256, 256, 0, stream>>>(E, ca_ow, ca_ob, Bf);        // t1
    ln_kernel<false><<<4096, 256, 0, stream>>>(Bf, ln3_g, ln3_b, C, A);          // xs2
    matmul64_kernel<false><<<256, 256, 0, stream>>>(A, ff1_w, ff1_b, Bf);        // t2
    ln_kernel<false><<<4096, 256, 0, stream>>>(Bf, ln4_g, ln4_b, A, C);          // xs3
    matmul64_kernel<true><<<256, 256, 0, stream>>>(C, conv2_w, conv2_b, (float*)d_out);
}

// Round 3
// 194.622 us; speedup vs baseline: 4.1510x; 1.9099x over previous
//
#include <hip/hip_runtime.h>
#include <hip/hip_bf16.h>
#include <math.h>

#define NBATCH 4
#define LTOK   4096
#define FD     64

typedef __attribute__((ext_vector_type(8))) short short8v;   // 8 bf16 = 4 VGPR
typedef __attribute__((ext_vector_type(4))) float f32x4;

static __device__ inline uint32_t packbf2(float a, float b) {
    float2 f; f.x = a; f.y = b;
    __hip_bfloat162 h = __float22bfloat162_rn(f);
    uint32_t u; __builtin_memcpy(&u, &h, 4);
    return u;
}
static __device__ inline ushort packbf1(float a) {
    __hip_bfloat16 h = __float2bfloat16(a);
    ushort u; __builtin_memcpy(&u, &h, 2);
    return u;
}
static __device__ inline float gelu_exact(float y) {
    return 0.5f * y * (1.0f + erff(y * 0.70710678118654752f));
}

// ---------------------------------------------------------------------------
// K1: GroupNorm stats — fully coalesced float4. One block per batch.
__global__ void gn_stats_kernel(const float* __restrict__ x, float* __restrict__ stats) {
    const int b = blockIdx.x;
    const float4* xb = (const float4*)(x + (size_t)b * 262144);
    float s[4] = {0, 0, 0, 0}, ss[4] = {0, 0, 0, 0};
    for (int i = threadIdx.x; i < 65536; i += 1024) {
        float4 v = xb[i];
        int g = (i & 15) >> 2;
        s[g] += (v.x + v.y) + (v.z + v.w);
        ss[g] += (v.x * v.x + v.y * v.y) + (v.z * v.z + v.w * v.w);
    }
    for (int o = 32; o; o >>= 1) {
#pragma unroll
        for (int g = 0; g < 4; g++) {
            s[g] += __shfl_xor(s[g], o, 64);
            ss[g] += __shfl_xor(ss[g], o, 64);
        }
    }
    __shared__ float ps[16][4], pss[16][4];
    const int wv = threadIdx.x >> 6;
    if ((threadIdx.x & 63) == 0) {
#pragma unroll
        for (int g = 0; g < 4; g++) { ps[wv][g] = s[g]; pss[wv][g] = ss[g]; }
    }
    __syncthreads();
    if (threadIdx.x < 4) {
        const int g = threadIdx.x;
        float S = 0, SS = 0;
        for (int w2 = 0; w2 < 16; w2++) { S += ps[w2][g]; SS += pss[w2][g]; }
        float mean = S * (1.f / 65536.f);
        float var = SS * (1.f / 65536.f) - mean * mean;
        stats[(b * 4 + g) * 2] = mean;
        stats[(b * 4 + g) * 2 + 1] = rsqrtf(var + 1e-5f);
    }
}

// ---------------------------------------------------------------------------
// K2: GN-apply + conv1 + channels-first reshape. wsm transposed for b128 reads.
__global__ void gn_conv1_kernel(const float* __restrict__ x, const float* __restrict__ stats,
                                const float* __restrict__ gg, const float* __restrict__ gb,
                                const float* __restrict__ w, const float* __restrict__ bias,
                                float* __restrict__ out) {
    const int b = blockIdx.x >> 6, i = blockIdx.x & 63;
    const int t = threadIdx.x;
    __shared__ float xn[64][65];
    __shared__ float wsm[64][64];   // [c][o]
    {
        const int j = t >> 2, c0 = (t & 3) * 16, g = c0 >> 4;
        const float mean = stats[(b * 4 + g) * 2], rstd = stats[(b * 4 + g) * 2 + 1];
        const float* src = x + (((size_t)b * 64 + i) * 64 + j) * 64 + c0;
#pragma unroll
        for (int k = 0; k < 4; k++) {
            float4 v = *(const float4*)(src + 4 * k);
            xn[j][c0 + 4 * k + 0] = (v.x - mean) * rstd * gg[c0 + 4 * k + 0] + gb[c0 + 4 * k + 0];
            xn[j][c0 + 4 * k + 1] = (v.y - mean) * rstd * gg[c0 + 4 * k + 1] + gb[c0 + 4 * k + 1];
            xn[j][c0 + 4 * k + 2] = (v.z - mean) * rstd * gg[c0 + 4 * k + 2] + gb[c0 + 4 * k + 2];
            xn[j][c0 + 4 * k + 3] = (v.w - mean) * rstd * gg[c0 + 4 * k + 3] + gb[c0 + 4 * k + 3];
        }
        const int o = t >> 2, cc0 = (t & 3) * 16;
#pragma unroll
        for (int k = 0; k < 16; k++) wsm[cc0 + k][o] = w[o * 64 + cc0 + k];
    }
    __syncthreads();
    const int jj = t & 63, olo = (t >> 6) * 16;
    float acc[16];
#pragma unroll
    for (int oi = 0; oi < 16; oi++) acc[oi] = bias[olo + oi];
    for (int c = 0; c < 64; c++) {
        float xv = xn[jj][c];
#pragma unroll
        for (int oi = 0; oi < 16; oi++) acc[oi] += xv * wsm[c][olo + oi];
    }
#pragma unroll
    for (int oi = 0; oi < 16; oi++)
        out[((size_t)b * LTOK + (size_t)(olo + oi) * 64 + i) * 64 + jj] = acc[oi];
}

// ---------------------------------------------------------------------------
// K3: fused Q/K/V projection -> bf16 Q,K (linear) + V^T (global [b*64+o][tok]).
__global__ void qkv_kernel(const float* __restrict__ in,
                           const float* __restrict__ qw, const float* __restrict__ qb,
                           const float* __restrict__ kw, const float* __restrict__ kb,
                           const float* __restrict__ vw, const float* __restrict__ vb,
                           ushort* __restrict__ Qo, ushort* __restrict__ Ko, ushort* __restrict__ VTg) {
    __shared__ float xt[64][68];
    __shared__ float wt[64][64];
    __shared__ ushort vtr[64 * 72];
    const int t = threadIdx.x;
    const size_t tok0 = (size_t)blockIdx.x * 64;
    const int b = blockIdx.x >> 6;
    const int tokb0 = (blockIdx.x & 63) * 64;
    const int r = t >> 2, cq = t & 3, olo = cq * 16;
    {
        const float4* src = (const float4*)(in + tok0 * 64) + (size_t)t * 4;
        float4* dst = (float4*)&xt[r][olo];
#pragma unroll
        for (int k = 0; k < 4; k++) dst[k] = src[k];
    }
    const float* Wp[3] = {qw, kw, vw};
    const float* Bp[3] = {qb, kb, vb};
#pragma unroll 1
    for (int ph = 0; ph < 3; ph++) {
        if (ph > 0) __syncthreads();
        {
            const float4* src = (const float4*)Wp[ph] + (size_t)t * 4;
            float4* dst = (float4*)wt + (size_t)t * 4;
#pragma unroll
            for (int k = 0; k < 4; k++) dst[k] = src[k];
        }
        __syncthreads();
        float acc[16];
#pragma unroll
        for (int k = 0; k < 4; k++) {
            float4 bv = *(const float4*)(Bp[ph] + olo + 4 * k);
            acc[4 * k] = bv.x; acc[4 * k + 1] = bv.y; acc[4 * k + 2] = bv.z; acc[4 * k + 3] = bv.w;
        }
        for (int f = 0; f < 64; f++) {
            float xv = xt[r][f];
#pragma unroll
            for (int oi = 0; oi < 16; oi++) acc[oi] += xv * wt[f][olo + oi];
        }
        if (ph < 2) {
            const float sc = (ph == 0) ? 0.180336880111f : 1.0f;   // 0.125 * log2(e)
            uint32_t u[8];
#pragma unroll
            for (int i = 0; i < 8; i++) u[i] = packbf2(acc[2 * i] * sc, acc[2 * i + 1] * sc);
            ushort* op = (ph == 0 ? Qo : Ko) + (tok0 + r) * 64 + olo;
            *(uint4*)op = make_uint4(u[0], u[1], u[2], u[3]);
            *(uint4*)(op + 8) = make_uint4(u[4], u[5], u[6], u[7]);
        } else {
#pragma unroll
            for (int oi = 0; oi < 16; oi++) vtr[(olo + oi) * 72 + r] = packbf1(acc[oi]);
            __syncthreads();
            const int o = t >> 2, ch = t & 3;
            uint4 a0 = *(const uint4*)&vtr[o * 72 + ch * 16];
            uint4 a1 = *(const uint4*)&vtr[o * 72 + ch * 16 + 8];
            ushort* op = VTg + (size_t)(b * 64 + o) * 4096 + tokb0 + ch * 16;
            *(uint4*)op = a0;
            *(uint4*)(op + 8) = a1;
        }
    }
}

// ---------------------------------------------------------------------------
// K4: MFMA flash self-attention. Double-buffered LDS, 1 barrier/iter,
// reg prefetch, defer-rescale, V^T pre-transposed globally.
__global__ __launch_bounds__(256) void flash_mfma(const ushort* __restrict__ Q,
                                                  const ushort* __restrict__ K,
                                                  const ushort* __restrict__ VTg,
                                                  float* __restrict__ Z) {
    const int qt = blockIdx.x;            // 0..63
    const int bh = blockIdx.y;            // 0..7
    const int b = bh >> 1, h = bh & 1;
    const int t = threadIdx.x;
    const int w = t >> 6, l = t & 63, lg = l >> 4, lq = l & 15;

    __shared__ ushort Ks[2][2048];        // [k][dh] swz ^((k&7)<<3)
    __shared__ ushort VT[2][2048];        // [dh][k] swz ^((dh&7)<<3)
    __shared__ ushort Pl[4096];           // per-wave [q][k] swz ^((q&7)<<3)

    const size_t base = (size_t)b * LTOK * 64 + h * 32;
    const size_t vrow0 = (size_t)(b * 64 + h * 32);

    const short8v qf = *(const short8v*)(Q + base + (size_t)(qt * 64 + w * 16 + lq) * 64 + 8 * lg);

    const int krow = t >> 2, kdg = t & 3;
    const int koff = (((krow << 5) + kdg * 8)) ^ ((krow & 7) << 3);
    const int vrow = t >> 3, vc8 = t & 7;
    const int voff = (((vrow << 6) + vc8 * 8)) ^ ((vrow & 7) << 3);
    const ushort* Kg = K + base + (size_t)krow * 64 + kdg * 8;
    const ushort* Vg = VTg + (vrow0 + vrow) * 4096 + vc8 * 8;

    uint4 kq = *(const uint4*)Kg;
    uint4 vq = *(const uint4*)Vg;
    *(uint4*)&Ks[0][koff] = kq;
    *(uint4*)&VT[0][voff] = vq;

    f32x4 accZ[2];
#pragma unroll
    for (int d = 0; d < 2; d++) accZ[d] = (f32x4){0.f, 0.f, 0.f, 0.f};
    float mreg = -3.0e38f, lreg = 0.0f;
    const f32x4 zero4 = {0.f, 0.f, 0.f, 0.f};
    int cur = 0;
    const int pb = w << 10;

    for (int kt = 0; kt < 64; kt++) {
        __syncthreads();
        if (kt < 63) {
            kq = *(const uint4*)(Kg + (size_t)(kt + 1) * 4096);
            vq = *(const uint4*)(Vg + (size_t)(kt + 1) * 64);
        }
        // --- S^T: 4 MFMAs ---
        f32x4 s4[4];
#pragma unroll
        for (int tk = 0; tk < 4; tk++) {
            const int kr = tk * 16 + lq;
            const short8v aK = *(const short8v*)&Ks[cur][(((kr << 5) + lg * 8)) ^ ((lq & 7) << 3)];
            s4[tk] = __builtin_amdgcn_mfma_f32_16x16x32_bf16(aK, qf, zero4, 0, 0, 0);
        }
        // --- online softmax with defer-rescale ---
        float mx = s4[0][0];
#pragma unroll
        for (int tk = 0; tk < 4; tk++)
#pragma unroll
            for (int rr = 0; rr < 4; rr++) mx = fmaxf(mx, s4[tk][rr]);
        mx = fmaxf(mx, __shfl_xor(mx, 16, 64));
        mx = fmaxf(mx, __shfl_xor(mx, 32, 64));
        if (!__all(mx <= mreg)) {
            const float mnew = fmaxf(mreg, mx);
            const float alpha = exp2f(mreg - mnew);
            mreg = mnew;
            lreg *= alpha;
#pragma unroll
            for (int rr = 0; rr < 4; rr++) {
                const float ar = __shfl(alpha, lg * 4 + rr, 64);
                accZ[0][rr] *= ar;
                accZ[1][rr] *= ar;
            }
        }
        float psum = 0.f;
        uint32_t pw[8];
#pragma unroll
        for (int tk = 0; tk < 4; tk++) {
            float p0 = exp2f(s4[tk][0] - mreg);
            float p1 = exp2f(s4[tk][1] - mreg);
            float p2 = exp2f(s4[tk][2] - mreg);
            float p3 = exp2f(s4[tk][3] - mreg);
            psum += (p0 + p1) + (p2 + p3);
            pw[2 * tk]     = packbf2(p0, p1);
            pw[2 * tk + 1] = packbf2(p2, p3);
        }
        psum += __shfl_xor(psum, 16, 64);
        psum += __shfl_xor(psum, 32, 64);
        lreg += psum;
        // --- P -> per-wave LDS ---
#pragma unroll
        for (int tk = 0; tk < 4; tk++) {
            const int idx = (((lq << 6) + tk * 16 + lg * 4)) ^ ((lq & 7) << 3);
            *(uint2*)&Pl[pb + idx] = make_uint2(pw[2 * tk], pw[2 * tk + 1]);
        }
        // --- PV ---
#pragma unroll
        for (int kc = 0; kc < 2; kc++) {
            const int ia = (((lq << 6) + kc * 32 + lg * 8)) ^ ((lq & 7) << 3);
            const short8v aP = *(const short8v*)&Pl[pb + ia];
#pragma unroll
            for (int dt = 0; dt < 2; dt++) {
                const int ib = ((((dt * 16 + lq) << 6) + kc * 32 + lg * 8)) ^ ((lq & 7) << 3);
                const short8v bV = *(const short8v*)&VT[cur][ib];
                accZ[dt] = __builtin_amdgcn_mfma_f32_16x16x32_bf16(aP, bV, accZ[dt], 0, 0, 0);
            }
        }
        if (kt < 63) {
            *(uint4*)&Ks[cur ^ 1][koff] = kq;
            *(uint4*)&VT[cur ^ 1][voff] = vq;
        }
        cur ^= 1;
    }

    const float inv = 1.0f / lreg;
#pragma unroll
    for (int rr = 0; rr < 4; rr++) {
        const float ivr = __shfl(inv, lg * 4 + rr, 64);
        const int qrow = qt * 64 + w * 16 + lg * 4 + rr;
#pragma unroll
        for (int dt = 0; dt < 2; dt++)
            Z[base + (size_t)qrow * 64 + dt * 16 + lq] = accZ[dt][rr] * ivr;
    }
}

// ---------------------------------------------------------------------------
// K6: cross-attn K/V from slots.
__global__ void kv_ca_kernel(const float* __restrict__ slots,
                             const float* __restrict__ kw, const float* __restrict__ kb,
                             const float* __restrict__ vw, const float* __restrict__ vb,
                             float* __restrict__ kv) {
    __shared__ float sl[2048];
    for (int i = threadIdx.x; i < 2048; i += 256) sl[i] = slots[i];
    __syncthreads();
    for (int idx = threadIdx.x; idx < 4096; idx += 256) {
        int which = idx >> 11, rem = idx & 2047, bj = rem >> 6, o = rem & 63;
        const float* W = which ? vw : kw;
        const float* Bb = which ? vb : kb;
        float acc = Bb[o];
        for (int c = 0; c < 64; c++) acc += sl[bj * 64 + c] * W[c * 64 + o];
        kv[idx] = acc;
    }
}

// ---------------------------------------------------------------------------
// K8: fused tail — ow-proj+LN2+GELU, ca_q, cross-attn, ca_ow+LN3, ff1+LN4, conv2.
// 512 threads: r = t>>3 (token row 0..63), c = t&7, 8 outputs each.
__global__ __launch_bounds__(512) void tail_fused(
    const float* __restrict__ Z, const float* __restrict__ xs0,
    const float* __restrict__ kvca,
    const float* __restrict__ ow, const float* __restrict__ ob,
    const float* __restrict__ g2, const float* __restrict__ b2,
    const float* __restrict__ qw, const float* __restrict__ qb,
    const float* __restrict__ cow, const float* __restrict__ cob,
    const float* __restrict__ g3, const float* __restrict__ b3,
    const float* __restrict__ fw, const float* __restrict__ fb,
    const float* __restrict__ g4, const float* __restrict__ b4,
    const float* __restrict__ cw, const float* __restrict__ cb,
    float* __restrict__ out)
{
    const int t = threadIdx.x;
    const size_t tok0 = (size_t)blockIdx.x * 64;
    const int b = blockIdx.x >> 6;
    const int r = t >> 3, c = t & 7, olo = c * 8;
    __shared__ float xt[64][68];
    __shared__ float wt[64][64];
    __shared__ float kcs[512], vcs[512];

    if (t < 128) ((float4*)kcs)[t] = ((const float4*)kvca)[b * 128 + t];
    else if (t < 256) ((float4*)vcs)[t - 128] = ((const float4*)kvca)[512 + b * 128 + (t - 128)];

    float acc[8], res[8];

    auto stage_w = [&](const float* W) {
        ((float4*)wt)[2 * t] = ((const float4*)W)[2 * t];
        ((float4*)wt)[2 * t + 1] = ((const float4*)W)[2 * t + 1];
    };
    auto stage_x_res = [&]() {
        float4* xd = (float4*)&xt[r][olo];
        xd[0] = make_float4(res[0], res[1], res[2], res[3]);
        xd[1] = make_float4(res[4], res[5], res[6], res[7]);
    };
    auto load8 = [&](float* dst, const float* p) {
        float4 u0 = *(const float4*)(p + olo);
        float4 u1 = *(const float4*)(p + olo + 4);
        dst[0] = u0.x; dst[1] = u0.y; dst[2] = u0.z; dst[3] = u0.w;
        dst[4] = u1.x; dst[5] = u1.y; dst[6] = u1.z; dst[7] = u1.w;
    };
    auto mm = [&](const float* bias) {
        load8(acc, bias);
        for (int f = 0; f < 64; f++) {
            float xv = xt[r][f];
#pragma unroll
            for (int oi = 0; oi < 8; oi++) acc[oi] += xv * wt[f][olo + oi];
        }
    };
    auto ln = [&](const float* gv, const float* bv, bool dogelu) {
        float s1 = 0.f, s2 = 0.f;
#pragma unroll
        for (int oi = 0; oi < 8; oi++) { s1 += acc[oi]; s2 += acc[oi] * acc[oi]; }
#pragma unroll
        for (int o = 1; o <= 4; o <<= 1) {
            s1 += __shfl_xor(s1, o, 64);
            s2 += __shfl_xor(s2, o, 64);
        }
        float mean = s1 * (1.f / 64.f);
        float var = s2 * (1.f / 64.f) - mean * mean;
        float rstd = rsqrtf(var + 1e-5f);
        float gl[8], bl[8];
        load8(gl, gv); load8(bl, bv);
#pragma unroll
        for (int oi = 0; oi < 8; oi++) {
            float y = (acc[oi] - mean) * rstd * gl[oi] + bl[oi] + res[oi];
            res[oi] = dogelu ? gelu_exact(y) : y;
        }
    };

    // ---- phase 1: t0 = Z@ow+ob ; res = xs1 = gelu(LN2(t0)+xs0)
    {
        const float4* zs = (const float4*)(Z + tok0 * 64);
        float4 a0 = zs[2 * t], a1 = zs[2 * t + 1];
        float4* xd = (float4*)&xt[r][olo];
        xd[0] = a0; xd[1] = a1;
        stage_w(ow);
        float4 r0 = *(const float4*)(xs0 + (tok0 + r) * 64 + olo);
        float4 r1 = *(const float4*)(xs0 + (tok0 + r) * 64 + olo + 4);
        res[0] = r0.x; res[1] = r0.y; res[2] = r0.z; res[3] = r0.w;
        res[4] = r1.x; res[5] = r1.y; res[6] = r1.z; res[7] = r1.w;
    }
    __syncthreads();
    mm(ob);
    ln(g2, b2, true);

    // ---- phase 2: qca = xs1@qw+qb ; acc = cross-attn(zca)
    __syncthreads();
    stage_x_res();
    stage_w(qw);
    __syncthreads();
    mm(qb);
    {
        float p[8];
        float mx = -3.0e38f;
#pragma unroll
        for (int j = 0; j < 8; j++) {
            float d = 0.f;
#pragma unroll
            for (int i2 = 0; i2 < 8; i2++) d += acc[i2] * kcs[j * 64 + olo + i2];
            d += __shfl_xor(d, 1, 64);
            d += __shfl_xor(d, 2, 64);
            d *= 0.125f;
            p[j] = d;
            mx = fmaxf(mx, d);
        }
        float es = 0.f;
#pragma unroll
        for (int j = 0; j < 8; j++) { p[j] = __expf(p[j] - mx); es += p[j]; }
        float inv = 1.f / es;
#pragma unroll
        for (int oi = 0; oi < 8; oi++) {
            float z = 0.f;
#pragma unroll
            for (int j = 0; j < 8; j++) z += p[j] * vcs[j * 64 + olo + oi];
            acc[oi] = z * inv;
        }
    }

    // ---- phase 3: t1 = zca@cow+cob ; res = xs2 = LN3(t1)+xs1
    __syncthreads();
    {
        float4* xd = (float4*)&xt[r][olo];
        xd[0] = make_float4(acc[0], acc[1], acc[2], acc[3]);
        xd[1] = make_float4(acc[4], acc[5], acc[6], acc[7]);
    }
    stage_w(cow);
    __syncthreads();
    mm(cob);
    ln(g3, b3, false);

    // ---- phase 4: t2 = xs2@fw+fb ; res = xs3 = LN4(t2)+xs2
    __syncthreads();
    stage_x_res();
    stage_w(fw);
    __syncthreads();
    mm(fb);
    ln(g4, b4, false);

    // ---- phase 5: out = xs3 @ conv2^T + cb
    __syncthreads();
    stage_x_res();
    {
        const int o5 = t >> 3, c5 = (t & 7) * 8;
#pragma unroll
        for (int k = 0; k < 8; k++) wt[c5 + k][o5] = cw[o5 * 64 + c5 + k];
    }
    __syncthreads();
    mm(cb);
    float* op = out + (tok0 + r) * 64 + olo;
    *(float4*)op = make_float4(acc[0], acc[1], acc[2], acc[3]);
    *(float4*)(op + 4) = make_float4(acc[4], acc[5], acc[6], acc[7]);
}

// ---------------------------------------------------------------------------
extern "C" void kernel_launch(void* const* d_in, const int* in_sizes, int n_in,
                              void* d_out, int out_size, void* d_ws, size_t ws_size,
                              hipStream_t stream) {
    const float* x       = (const float*)d_in[0];
    const float* slots   = (const float*)d_in[1];
    const float* conv1_w = (const float*)d_in[2];
    const float* conv1_b = (const float*)d_in[3];
    const float* conv2_w = (const float*)d_in[4];
    const float* conv2_b = (const float*)d_in[5];
    const float* gn_g    = (const float*)d_in[6];
    const float* gn_b    = (const float*)d_in[7];
    const float* ln2_g   = (const float*)d_in[8];
    const float* ln2_b   = (const float*)d_in[9];
    const float* ln3_g   = (const float*)d_in[10];
    const float* ln3_b   = (const float*)d_in[11];
    const float* ln4_g   = (const float*)d_in[12];
    const float* ln4_b   = (const float*)d_in[13];
    const float* sa_qw   = (const float*)d_in[14];
    const float* sa_qb   = (const float*)d_in[15];
    const float* sa_kw   = (const float*)d_in[16];
    const float* sa_kb   = (const float*)d_in[17];
    const float* sa_vw   = (const float*)d_in[18];
    const float* sa_vb   = (const float*)d_in[19];
    const float* sa_ow   = (const float*)d_in[20];
    const float* sa_ob   = (const float*)d_in[21];
    const float* ca_qw   = (const float*)d_in[22];
    const float* ca_qb   = (const float*)d_in[23];
    const float* ca_kw   = (const float*)d_in[24];
    const float* ca_kb   = (const float*)d_in[25];
    const float* ca_vw   = (const float*)d_in[26];
    const float* ca_vb   = (const float*)d_in[27];
    const float* ca_ow   = (const float*)d_in[28];
    const float* ca_ob   = (const float*)d_in[29];
    const float* ff1_w   = (const float*)d_in[30];
    const float* ff1_b   = (const float*)d_in[31];

    float* ws = (float*)d_ws;
    const size_t NBUF = (size_t)NBATCH * LTOK * FD;   // 1,048,576 elements
    float* stats = ws;            // 32 floats
    float* kvca  = ws + 64;       // 4096 floats
    float* A     = ws + 8192;     // xs0 (f32)
    ushort* Kb   = (ushort*)(A + NBUF);
    ushort* VTgb = Kb + NBUF;
    ushort* Qb   = VTgb + NBUF;
    float* E     = (float*)d_out; // flash Z scratch; fully overwritten by tail

    gn_stats_kernel<<<4, 1024, 0, stream>>>(x, stats);
    gn_conv1_kernel<<<256, 256, 0, stream>>>(x, stats, gn_g, gn_b, conv1_w, conv1_b, A);
    qkv_kernel<<<256, 256, 0, stream>>>(A, sa_qw, sa_qb, sa_kw, sa_kb, sa_vw, sa_vb, Qb, Kb, VTgb);
    flash_mfma<<<dim3(64, 8), 256, 0, stream>>>(Qb, Kb, VTgb, E);
    kv_ca_kernel<<<1, 256, 0, stream>>>(slots, ca_kw, ca_kb, ca_vw, ca_vb, kvca);
    tail_fused<<<256, 512, 0, stream>>>(E, A, kvca,
                                        sa_ow, sa_ob, ln2_g, ln2_b,
                                        ca_qw, ca_qb, ca_ow, ca_ob, ln3_g, ln3_b,
                                        ff1_w, ff1_b, ln4_g, ln4_b,
                                        conv2_w, conv2_b, (float*)d_out);
}

// Round 4
// 107.835 us; speedup vs baseline: 7.4917x; 1.8048x over previous
//
#include <hip/hip_runtime.h>
#include <hip/hip_bf16.h>
#include <math.h>

#define NBATCH 4
#define LTOK   4096
#define FD     64

typedef __attribute__((ext_vector_type(8))) short short8v;   // 8 bf16 = 4 VGPR
typedef __attribute__((ext_vector_type(4))) float f32x4;

static __device__ inline uint32_t packbf2(float a, float b) {
    float2 f; f.x = a; f.y = b;
    __hip_bfloat162 h = __float22bfloat162_rn(f);
    uint32_t u; __builtin_memcpy(&u, &h, 4);
    return u;
}
static __device__ inline ushort packbf1(float a) {
    __hip_bfloat16 h = __float2bfloat16(a);
    ushort u; __builtin_memcpy(&u, &h, 2);
    return u;
}
static __device__ inline float gelu_exact(float y) {
    return 0.5f * y * (1.0f + erff(y * 0.70710678118654752f));
}

// ---------------------------------------------------------------------------
// K1: GroupNorm partial sums. 256 blocks (64 chunks per batch), coalesced.
__global__ void gn_part_kernel(const float* __restrict__ x,
                               float* __restrict__ partS, float* __restrict__ partSS) {
    const int b = blockIdx.x >> 6, c = blockIdx.x & 63;
    const int t = threadIdx.x, l = t & 63, wv = t >> 6;
    const float4* xb = (const float4*)(x + (size_t)b * 262144) + (size_t)c * 1024;
    float s = 0.f, ss = 0.f;
#pragma unroll
    for (int k = 0; k < 4; k++) {
        float4 v = xb[t + 256 * k];
        s += (v.x + v.y) + (v.z + v.w);
        ss += (v.x * v.x + v.y * v.y) + (v.z * v.z + v.w * v.w);
    }
    // group of this thread = (t&15)>>2 (constant across its 4 loads).
    // reduce over lanes with same group: xor offsets 1,2,16,32.
#pragma unroll
    for (int o = 0; o < 4; o++) {
        const int off = (int[]){1, 2, 16, 32}[o];
        s += __shfl_xor(s, off, 64);
        ss += __shfl_xor(ss, off, 64);
    }
    __shared__ float ls_s[4][4], ls_ss[4][4];
    if ((l & 51) == 0) { ls_s[wv][(l >> 2) & 3] = s; ls_ss[wv][(l >> 2) & 3] = ss; }
    __syncthreads();
    if (t < 4) {
        float S = 0.f, SS = 0.f;
#pragma unroll
        for (int w2 = 0; w2 < 4; w2++) { S += ls_s[w2][t]; SS += ls_ss[w2][t]; }
        partS[b * 256 + t * 64 + c] = S;
        partSS[b * 256 + t * 64 + c] = SS;
    }
}

// ---------------------------------------------------------------------------
// K2: combine partials + GN-apply + conv1 + channels-first reshape.
__global__ void gn_conv1_kernel(const float* __restrict__ x,
                                const float* __restrict__ partS, const float* __restrict__ partSS,
                                const float* __restrict__ gg, const float* __restrict__ gb,
                                const float* __restrict__ w, const float* __restrict__ bias,
                                float* __restrict__ out) {
    const int b = blockIdx.x >> 6, i = blockIdx.x & 63;
    const int t = threadIdx.x;
    __shared__ float xn[64][65];
    __shared__ float wsm[64][64];   // [c][o]
    __shared__ float sm[4], sr[4];
    {
        float sv = partS[b * 256 + t];     // g = t>>6, chunk = t&63
        float ssv = partSS[b * 256 + t];
        for (int o = 32; o; o >>= 1) { sv += __shfl_xor(sv, o, 64); ssv += __shfl_xor(ssv, o, 64); }
        if ((t & 63) == 0) {
            float mean = sv * (1.f / 65536.f);
            float var = ssv * (1.f / 65536.f) - mean * mean;
            sm[t >> 6] = mean;
            sr[t >> 6] = rsqrtf(var + 1e-5f);
        }
    }
    __syncthreads();
    {
        const int j = t >> 2, c0 = (t & 3) * 16, g = c0 >> 4;
        const float mean = sm[g], rstd = sr[g];
        const float* src = x + (((size_t)b * 64 + i) * 64 + j) * 64 + c0;
#pragma unroll
        for (int k = 0; k < 4; k++) {
            float4 v = *(const float4*)(src + 4 * k);
            xn[j][c0 + 4 * k + 0] = (v.x - mean) * rstd * gg[c0 + 4 * k + 0] + gb[c0 + 4 * k + 0];
            xn[j][c0 + 4 * k + 1] = (v.y - mean) * rstd * gg[c0 + 4 * k + 1] + gb[c0 + 4 * k + 1];
            xn[j][c0 + 4 * k + 2] = (v.z - mean) * rstd * gg[c0 + 4 * k + 2] + gb[c0 + 4 * k + 2];
            xn[j][c0 + 4 * k + 3] = (v.w - mean) * rstd * gg[c0 + 4 * k + 3] + gb[c0 + 4 * k + 3];
        }
        const int o = t >> 2, cc0 = (t & 3) * 16;
#pragma unroll
        for (int k = 0; k < 16; k++) wsm[cc0 + k][o] = w[o * 64 + cc0 + k];
    }
    __syncthreads();
    const int jj = t & 63, olo = (t >> 6) * 16;
    float acc[16];
#pragma unroll
    for (int oi = 0; oi < 16; oi++) acc[oi] = bias[olo + oi];
    for (int c = 0; c < 64; c++) {
        float xv = xn[jj][c];
#pragma unroll
        for (int oi = 0; oi < 16; oi++) acc[oi] += xv * wsm[c][olo + oi];
    }
#pragma unroll
    for (int oi = 0; oi < 16; oi++)
        out[((size_t)b * LTOK + (size_t)(olo + oi) * 64 + i) * 64 + jj] = acc[oi];
}

// ---------------------------------------------------------------------------
// K3: Q/K/V projection, one phase per block (grid 256 x 3).
__global__ void qkv_kernel(const float* __restrict__ in,
                           const float* __restrict__ qw, const float* __restrict__ qb,
                           const float* __restrict__ kw, const float* __restrict__ kb,
                           const float* __restrict__ vw, const float* __restrict__ vb,
                           ushort* __restrict__ Qo, ushort* __restrict__ Ko, ushort* __restrict__ VTg) {
    __shared__ float xt[64][68];
    __shared__ float wt[64][64];
    __shared__ ushort vtr[64 * 72];
    const int t = threadIdx.x;
    const int ph = blockIdx.y;
    const size_t tok0 = (size_t)blockIdx.x * 64;
    const int b = blockIdx.x >> 6;
    const int tokb0 = (blockIdx.x & 63) * 64;
    const int r = t >> 2, cq = t & 3, olo = cq * 16;
    const float* W = (ph == 0) ? qw : (ph == 1) ? kw : vw;
    const float* Bb = (ph == 0) ? qb : (ph == 1) ? kb : vb;
    {
        const float4* src = (const float4*)(in + tok0 * 64) + (size_t)t * 4;
        float4* dst = (float4*)&xt[r][olo];
#pragma unroll
        for (int k = 0; k < 4; k++) dst[k] = src[k];
        const float4* ws2 = (const float4*)W + (size_t)t * 4;
        float4* wd = (float4*)wt + (size_t)t * 4;
#pragma unroll
        for (int k = 0; k < 4; k++) wd[k] = ws2[k];
    }
    __syncthreads();
    float acc[16];
#pragma unroll
    for (int k = 0; k < 4; k++) {
        float4 bv = *(const float4*)(Bb + olo + 4 * k);
        acc[4 * k] = bv.x; acc[4 * k + 1] = bv.y; acc[4 * k + 2] = bv.z; acc[4 * k + 3] = bv.w;
    }
    for (int f = 0; f < 64; f++) {
        float xv = xt[r][f];
#pragma unroll
        for (int oi = 0; oi < 16; oi++) acc[oi] += xv * wt[f][olo + oi];
    }
    if (ph < 2) {
        const float sc = (ph == 0) ? 0.180336880111f : 1.0f;   // 0.125 * log2(e)
        uint32_t u[8];
#pragma unroll
        for (int i = 0; i < 8; i++) u[i] = packbf2(acc[2 * i] * sc, acc[2 * i + 1] * sc);
        ushort* op = (ph == 0 ? Qo : Ko) + (tok0 + r) * 64 + olo;
        *(uint4*)op = make_uint4(u[0], u[1], u[2], u[3]);
        *(uint4*)(op + 8) = make_uint4(u[4], u[5], u[6], u[7]);
    } else {
#pragma unroll
        for (int oi = 0; oi < 16; oi++) vtr[(olo + oi) * 72 + r] = packbf1(acc[oi]);
        __syncthreads();
        const int o = t >> 2, ch = t & 3;
        uint4 a0 = *(const uint4*)&vtr[o * 72 + ch * 16];
        uint4 a1 = *(const uint4*)&vtr[o * 72 + ch * 16 + 8];
        ushort* op = VTg + (size_t)(b * 64 + o) * 4096 + tokb0 + ch * 16;
        *(uint4*)op = a0;
        *(uint4*)(op + 8) = a1;
    }
}

// ---------------------------------------------------------------------------
// K4: MFMA flash self-attention, max-free softmax, K-split x2.
// Grid (64 qt, 8 bh, 2 ks). Writes unnormalized Zpart + per-row l-sum.
__global__ __launch_bounds__(256) void flash_mfma(const ushort* __restrict__ Q,
                                                  const ushort* __restrict__ K,
                                                  const ushort* __restrict__ VTg,
                                                  float* __restrict__ Zp0, float* __restrict__ Zp1,
                                                  float* __restrict__ Ls) {
    const int qt = blockIdx.x;            // 0..63
    const int bh = blockIdx.y;            // 0..7
    const int ks = blockIdx.z;            // 0..1
    const int b = bh >> 1, h = bh & 1;
    const int t = threadIdx.x;
    const int w = t >> 6, l = t & 63, lg = l >> 4, lq = l & 15;

    __shared__ ushort Ks[2][2048];        // [k][dh] swz ^((k&7)<<3)
    __shared__ ushort VT[2][2048];        // [dh][k] swz ^((dh&7)<<3)
    __shared__ ushort Pl[4096];           // per-wave [q][k] swz ^((q&7)<<3)

    const size_t base = (size_t)b * LTOK * 64 + h * 32;
    const size_t vrow0 = (size_t)(b * 64 + h * 32);

    const short8v qf = *(const short8v*)(Q + base + (size_t)(qt * 64 + w * 16 + lq) * 64 + 8 * lg);

    const int krow = t >> 2, kdg = t & 3;
    const int koff = (((krow << 5) + kdg * 8)) ^ ((krow & 7) << 3);
    const int vrow = t >> 3, vc8 = t & 7;
    const int voff = (((vrow << 6) + vc8 * 8)) ^ ((vrow & 7) << 3);
    const ushort* Kg = K + base + (size_t)(ks * 2048 + krow) * 64 + kdg * 8;
    const ushort* Vg = VTg + (vrow0 + vrow) * 4096 + ks * 2048 + vc8 * 8;

    uint4 kq = *(const uint4*)Kg;
    uint4 vq = *(const uint4*)Vg;
    *(uint4*)&Ks[0][koff] = kq;
    *(uint4*)&VT[0][voff] = vq;

    f32x4 accZ[2];
#pragma unroll
    for (int d = 0; d < 2; d++) accZ[d] = (f32x4){0.f, 0.f, 0.f, 0.f};
    float lacc = 0.0f;
    const f32x4 zero4 = {0.f, 0.f, 0.f, 0.f};
    int cur = 0;
    const int pb = w << 10;

    for (int kt = 0; kt < 32; kt++) {
        __syncthreads();
        if (kt < 31) {
            kq = *(const uint4*)(Kg + (size_t)(kt + 1) * 4096);
            vq = *(const uint4*)(Vg + (size_t)(kt + 1) * 64);
        }
        // --- S^T: 4 MFMAs ---
        f32x4 s4[4];
#pragma unroll
        for (int tk = 0; tk < 4; tk++) {
            const int kr = tk * 16 + lq;
            const short8v aK = *(const short8v*)&Ks[cur][(((kr << 5) + lg * 8)) ^ ((lq & 7) << 3)];
            s4[tk] = __builtin_amdgcn_mfma_f32_16x16x32_bf16(aK, qf, zero4, 0, 0, 0);
        }
        // --- max-free softmax: p = exp2(s), l accumulated per-lane ---
        uint32_t pw[8];
#pragma unroll
        for (int tk = 0; tk < 4; tk++) {
            float p0 = exp2f(s4[tk][0]);
            float p1 = exp2f(s4[tk][1]);
            float p2 = exp2f(s4[tk][2]);
            float p3 = exp2f(s4[tk][3]);
            lacc += (p0 + p1) + (p2 + p3);
            pw[2 * tk]     = packbf2(p0, p1);
            pw[2 * tk + 1] = packbf2(p2, p3);
        }
        // --- P -> per-wave LDS ---
#pragma unroll
        for (int tk = 0; tk < 4; tk++) {
            const int idx = (((lq << 6) + tk * 16 + lg * 4)) ^ ((lq & 7) << 3);
            *(uint2*)&Pl[pb + idx] = make_uint2(pw[2 * tk], pw[2 * tk + 1]);
        }
        // --- PV ---
#pragma unroll
        for (int kc = 0; kc < 2; kc++) {
            const int ia = (((lq << 6) + kc * 32 + lg * 8)) ^ ((lq & 7) << 3);
            const short8v aP = *(const short8v*)&Pl[pb + ia];
#pragma unroll
            for (int dt = 0; dt < 2; dt++) {
                const int ib = ((((dt * 16 + lq) << 6) + kc * 32 + lg * 8)) ^ ((lq & 7) << 3);
                const short8v bV = *(const short8v*)&VT[cur][ib];
                accZ[dt] = __builtin_amdgcn_mfma_f32_16x16x32_bf16(aP, bV, accZ[dt], 0, 0, 0);
            }
        }
        if (kt < 31) {
            *(uint4*)&Ks[cur ^ 1][koff] = kq;
            *(uint4*)&VT[cur ^ 1][voff] = vq;
        }
        cur ^= 1;
    }

    float* Zo = ks ? Zp1 : Zp0;
#pragma unroll
    for (int rr = 0; rr < 4; rr++) {
        const int qrow = qt * 64 + w * 16 + lg * 4 + rr;
#pragma unroll
        for (int dt = 0; dt < 2; dt++)
            Zo[base + (size_t)qrow * 64 + dt * 16 + lq] = accZ[dt][rr];
    }
    lacc += __shfl_xor(lacc, 16, 64);
    lacc += __shfl_xor(lacc, 32, 64);
    if (l < 16)
        Ls[ks * 32768 + bh * 4096 + qt * 64 + w * 16 + lq] = lacc;
}

// ---------------------------------------------------------------------------
// K8: fused tail — Z-combine + ow+LN2+GELU, ca_kv, ca_q, cross-attn,
// ca_ow+LN3, ff1+LN4, conv2. 512 threads, 64 tokens per block.
__global__ __launch_bounds__(512) void tail_fused(
    const float* __restrict__ Zp0, const float* __restrict__ Zp1,
    const float* __restrict__ Ls, const float* __restrict__ xs0,
    const float* __restrict__ slots,
    const float* __restrict__ ckw, const float* __restrict__ ckb,
    const float* __restrict__ cvw, const float* __restrict__ cvb,
    const float* __restrict__ ow, const float* __restrict__ ob,
    const float* __restrict__ g2, const float* __restrict__ b2,
    const float* __restrict__ qw, const float* __restrict__ qb,
    const float* __restrict__ cow, const float* __restrict__ cob,
    const float* __restrict__ g3, const float* __restrict__ b3,
    const float* __restrict__ fw, const float* __restrict__ fb,
    const float* __restrict__ g4, const float* __restrict__ b4,
    const float* __restrict__ cw, const float* __restrict__ cb,
    float* __restrict__ out)
{
    const int t = threadIdx.x;
    const size_t tok0 = (size_t)blockIdx.x * 64;
    const int b = blockIdx.x >> 6;
    const int r = t >> 3, c = t & 7, olo = c * 8;
    __shared__ float xt[64][68];
    __shared__ float wt[64][64];
    __shared__ float kcs[512], vcs[512], sls[512];

    float acc[8], res[8];

    auto stage_w = [&](const float* W) {
        ((float4*)wt)[2 * t] = ((const float4*)W)[2 * t];
        ((float4*)wt)[2 * t + 1] = ((const float4*)W)[2 * t + 1];
    };
    auto stage_x_res = [&]() {
        float4* xd = (float4*)&xt[r][olo];
        xd[0] = make_float4(res[0], res[1], res[2], res[3]);
        xd[1] = make_float4(res[4], res[5], res[6], res[7]);
    };
    auto load8 = [&](float* dst, const float* p) {
        float4 u0 = *(const float4*)(p + olo);
        float4 u1 = *(const float4*)(p + olo + 4);
        dst[0] = u0.x; dst[1] = u0.y; dst[2] = u0.z; dst[3] = u0.w;
        dst[4] = u1.x; dst[5] = u1.y; dst[6] = u1.z; dst[7] = u1.w;
    };
    auto mm = [&](const float* bias) {
        load8(acc, bias);
        for (int f = 0; f < 64; f++) {
            float xv = xt[r][f];
#pragma unroll
            for (int oi = 0; oi < 8; oi++) acc[oi] += xv * wt[f][olo + oi];
        }
    };
    auto ln = [&](const float* gv, const float* bv, bool dogelu) {
        float s1 = 0.f, s2 = 0.f;
#pragma unroll
        for (int oi = 0; oi < 8; oi++) { s1 += acc[oi]; s2 += acc[oi] * acc[oi]; }
#pragma unroll
        for (int o = 1; o <= 4; o <<= 1) {
            s1 += __shfl_xor(s1, o, 64);
            s2 += __shfl_xor(s2, o, 64);
        }
        float mean = s1 * (1.f / 64.f);
        float var = s2 * (1.f / 64.f) - mean * mean;
        float rstd = rsqrtf(var + 1e-5f);
        float gl[8], bl[8];
        load8(gl, gv); load8(bl, bv);
#pragma unroll
        for (int oi = 0; oi < 8; oi++) {
            float y = (acc[oi] - mean) * rstd * gl[oi] + bl[oi] + res[oi];
            res[oi] = dogelu ? gelu_exact(y) : y;
        }
    };

    // ---- phase 1: combine flash partials, t0 = Z@ow+ob ; res = xs1
    {
        if (t < 128) ((float4*)sls)[t] = ((const float4*)(slots + (size_t)b * 512))[t];
        const float4* z0 = (const float4*)(Zp0 + tok0 * 64);
        const float4* z1 = (const float4*)(Zp1 + tok0 * 64);
        float4 a0 = z0[2 * t], a1 = z0[2 * t + 1];
        float4 c0 = z1[2 * t], c1 = z1[2 * t + 1];
        const int hh = olo >> 5;
        const int bh_ = b * 2 + hh;
        const int tokb = (blockIdx.x & 63) * 64 + r;
        const float lt = Ls[bh_ * 4096 + tokb] + Ls[32768 + bh_ * 4096 + tokb];
        const float inv = 1.0f / lt;
        float4* xd = (float4*)&xt[r][olo];
        xd[0] = make_float4((a0.x + c0.x) * inv, (a0.y + c0.y) * inv,
                            (a0.z + c0.z) * inv, (a0.w + c0.w) * inv);
        xd[1] = make_float4((a1.x + c1.x) * inv, (a1.y + c1.y) * inv,
                            (a1.z + c1.z) * inv, (a1.w + c1.w) * inv);
        stage_w(ow);
        float4 r0 = *(const float4*)(xs0 + (tok0 + r) * 64 + olo);
        float4 r1 = *(const float4*)(xs0 + (tok0 + r) * 64 + olo + 4);
        res[0] = r0.x; res[1] = r0.y; res[2] = r0.z; res[3] = r0.w;
        res[4] = r1.x; res[5] = r1.y; res[6] = r1.z; res[7] = r1.w;
    }
    __syncthreads();
    // ---- cross-attn K/V from slots (redundant per block, cheap)
    {
        const int j = t >> 6, o = t & 63;
        float ak = ckb[o], av = cvb[o];
#pragma unroll 8
        for (int c2 = 0; c2 < 64; c2++) {
            float sv = sls[j * 64 + c2];
            ak += sv * ckw[c2 * 64 + o];
            av += sv * cvw[c2 * 64 + o];
        }
        kcs[t] = ak; vcs[t] = av;
    }
    mm(ob);
    ln(g2, b2, true);

    // ---- phase 2: qca = xs1@qw+qb ; acc = cross-attn(zca)
    __syncthreads();
    stage_x_res();
    stage_w(qw);
    __syncthreads();
    mm(qb);
    {
        float p[8];
        float mx = -3.0e38f;
#pragma unroll
        for (int j = 0; j < 8; j++) {
            float d = 0.f;
#pragma unroll
            for (int i2 = 0; i2 < 8; i2++) d += acc[i2] * kcs[j * 64 + olo + i2];
            d += __shfl_xor(d, 1, 64);
            d += __shfl_xor(d, 2, 64);
            d *= 0.125f;
            p[j] = d;
            mx = fmaxf(mx, d);
        }
        float es = 0.f;
#pragma unroll
        for (int j = 0; j < 8; j++) { p[j] = __expf(p[j] - mx); es += p[j]; }
        float inv = 1.f / es;
#pragma unroll
        for (int oi = 0; oi < 8; oi++) {
            float z = 0.f;
#pragma unroll
            for (int j = 0; j < 8; j++) z += p[j] * vcs[j * 64 + olo + oi];
            acc[oi] = z * inv;
        }
    }

    // ---- phase 3: t1 = zca@cow+cob ; res = xs2 = LN3(t1)+xs1
    __syncthreads();
    {
        float4* xd = (float4*)&xt[r][olo];
        xd[0] = make_float4(acc[0], acc[1], acc[2], acc[3]);
        xd[1] = make_float4(acc[4], acc[5], acc[6], acc[7]);
    }
    stage_w(cow);
    __syncthreads();
    mm(cob);
    ln(g3, b3, false);

    // ---- phase 4: t2 = xs2@fw+fb ; res = xs3 = LN4(t2)+xs2
    __syncthreads();
    stage_x_res();
    stage_w(fw);
    __syncthreads();
    mm(fb);
    ln(g4, b4, false);

    // ---- phase 5: out = xs3 @ conv2^T + cb
    __syncthreads();
    stage_x_res();
    {
        const int o5 = t >> 3, c5 = (t & 7) * 8;
#pragma unroll
        for (int k = 0; k < 8; k++) wt[c5 + k][o5] = cw[o5 * 64 + c5 + k];
    }
    __syncthreads();
    mm(cb);
    float* op = out + (tok0 + r) * 64 + olo;
    *(float4*)op = make_float4(acc[0], acc[1], acc[2], acc[3]);
    *(float4*)(op + 4) = make_float4(acc[4], acc[5], acc[6], acc[7]);
}

// ---------------------------------------------------------------------------
extern "C" void kernel_launch(void* const* d_in, const int* in_sizes, int n_in,
                              void* d_out, int out_size, void* d_ws, size_t ws_size,
                              hipStream_t stream) {
    const float* x       = (const float*)d_in[0];
    const float* slots   = (const float*)d_in[1];
    const float* conv1_w = (const float*)d_in[2];
    const float* conv1_b = (const float*)d_in[3];
    const float* conv2_w = (const float*)d_in[4];
    const float* conv2_b = (const float*)d_in[5];
    const float* gn_g    = (const float*)d_in[6];
    const float* gn_b    = (const float*)d_in[7];
    const float* ln2_g   = (const float*)d_in[8];
    const float* ln2_b   = (const float*)d_in[9];
    const float* ln3_g   = (const float*)d_in[10];
    const float* ln3_b   = (const float*)d_in[11];
    const float* ln4_g   = (const float*)d_in[12];
    const float* ln4_b   = (const float*)d_in[13];
    const float* sa_qw   = (const float*)d_in[14];
    const float* sa_qb   = (const float*)d_in[15];
    const float* sa_kw   = (const float*)d_in[16];
    const float* sa_kb   = (const float*)d_in[17];
    const float* sa_vw   = (const float*)d_in[18];
    const float* sa_vb   = (const float*)d_in[19];
    const float* sa_ow   = (const float*)d_in[20];
    const float* sa_ob   = (const float*)d_in[21];
    const float* ca_qw   = (const float*)d_in[22];
    const float* ca_qb   = (const float*)d_in[23];
    const float* ca_kw   = (const float*)d_in[24];
    const float* ca_kb   = (const float*)d_in[25];
    const float* ca_vw   = (const float*)d_in[26];
    const float* ca_vb   = (const float*)d_in[27];
    const float* ca_ow   = (const float*)d_in[28];
    const float* ca_ob   = (const float*)d_in[29];
    const float* ff1_w   = (const float*)d_in[30];
    const float* ff1_b   = (const float*)d_in[31];

    float* ws = (float*)d_ws;
    const size_t NBUF = (size_t)NBATCH * LTOK * FD;   // 1,048,576 elements
    float* partS  = ws;              // 1024
    float* partSS = ws + 1024;       // 1024
    float* A      = ws + 4096;       // xs0 (4 MB)
    ushort* Kb    = (ushort*)(A + NBUF);   // 2 MB
    ushort* VTgb  = Kb + NBUF;             // 2 MB
    ushort* Qb    = VTgb + NBUF;           // 2 MB
    float* Zp1    = (float*)(Qb + NBUF);   // 4 MB
    float* Ls     = Zp1 + NBUF;            // 256 KB
    float* Zp0    = (float*)d_out;         // 4 MB scratch; overwritten by tail

    gn_part_kernel<<<256, 256, 0, stream>>>(x, partS, partSS);
    gn_conv1_kernel<<<256, 256, 0, stream>>>(x, partS, partSS, gn_g, gn_b, conv1_w, conv1_b, A);
    qkv_kernel<<<dim3(256, 3), 256, 0, stream>>>(A, sa_qw, sa_qb, sa_kw, sa_kb, sa_vw, sa_vb, Qb, Kb, VTgb);
    flash_mfma<<<dim3(64, 8, 2), 256, 0, stream>>>(Qb, Kb, VTgb, Zp0, Zp1, Ls);
    tail_fused<<<256, 512, 0, stream>>>(Zp0, Zp1, Ls, A, slots,
                                        ca_kw, ca_kb, ca_vw, ca_vb,
                                        sa_ow, sa_ob, ln2_g, ln2_b,
                                        ca_qw, ca_qb, ca_ow, ca_ob, ln3_g, ln3_b,
                                        ff1_w, ff1_b, ln4_g, ln4_b,
                                        conv2_w, conv2_b, (float*)d_out);
}

// Round 5
// 95.208 us; speedup vs baseline: 8.4854x; 1.1326x over previous
//
#include <hip/hip_runtime.h>
#include <hip/hip_bf16.h>
#include <math.h>

#define NBATCH 4
#define LTOK   4096
#define FD     64
#define NIT    16    // k-tiles (of 64) per flash block; KSPLIT=4

typedef __attribute__((ext_vector_type(8))) short short8v;   // 8 bf16 = 4 VGPR
typedef __attribute__((ext_vector_type(4))) float f32x4;

static __device__ inline uint32_t packbf2(float a, float b) {
    float2 f; f.x = a; f.y = b;
    __hip_bfloat162 h = __float22bfloat162_rn(f);
    uint32_t u; __builtin_memcpy(&u, &h, 4);
    return u;
}
static __device__ inline ushort packbf1(float a) {
    __hip_bfloat16 h = __float2bfloat16(a);
    ushort u; __builtin_memcpy(&u, &h, 2);
    return u;
}
static __device__ inline float gelu_exact(float y) {
    return 0.5f * y * (1.0f + erff(y * 0.70710678118654752f));
}

// ---------------------------------------------------------------------------
// K1: GroupNorm partial sums. 256 blocks (64 chunks per batch), coalesced.
__global__ void gn_part_kernel(const float* __restrict__ x,
                               float* __restrict__ partS, float* __restrict__ partSS) {
    const int b = blockIdx.x >> 6, c = blockIdx.x & 63;
    const int t = threadIdx.x, l = t & 63, wv = t >> 6;
    const float4* xb = (const float4*)(x + (size_t)b * 262144) + (size_t)c * 1024;
    float s = 0.f, ss = 0.f;
#pragma unroll
    for (int k = 0; k < 4; k++) {
        float4 v = xb[t + 256 * k];
        s += (v.x + v.y) + (v.z + v.w);
        ss += (v.x * v.x + v.y * v.y) + (v.z * v.z + v.w * v.w);
    }
#pragma unroll
    for (int o = 0; o < 4; o++) {
        const int off = (int[]){1, 2, 16, 32}[o];
        s += __shfl_xor(s, off, 64);
        ss += __shfl_xor(ss, off, 64);
    }
    __shared__ float ls_s[4][4], ls_ss[4][4];
    if ((l & 51) == 0) { ls_s[wv][(l >> 2) & 3] = s; ls_ss[wv][(l >> 2) & 3] = ss; }
    __syncthreads();
    if (t < 4) {
        float S = 0.f, SS = 0.f;
#pragma unroll
        for (int w2 = 0; w2 < 4; w2++) { S += ls_s[w2][t]; SS += ls_ss[w2][t]; }
        partS[b * 256 + t * 64 + c] = S;
        partSS[b * 256 + t * 64 + c] = SS;
    }
}

// ---------------------------------------------------------------------------
// K2: combine partials + GN-apply + conv1 + channels-first reshape.
__global__ void gn_conv1_kernel(const float* __restrict__ x,
                                const float* __restrict__ partS, const float* __restrict__ partSS,
                                const float* __restrict__ gg, const float* __restrict__ gb,
                                const float* __restrict__ w, const float* __restrict__ bias,
                                float* __restrict__ out) {
    const int b = blockIdx.x >> 6, i = blockIdx.x & 63;
    const int t = threadIdx.x;
    __shared__ float xn[64][65];
    __shared__ float wsm[64][64];   // [c][o]
    __shared__ float sm[4], sr[4];
    {
        float sv = partS[b * 256 + t];     // g = t>>6, chunk = t&63
        float ssv = partSS[b * 256 + t];
        for (int o = 32; o; o >>= 1) { sv += __shfl_xor(sv, o, 64); ssv += __shfl_xor(ssv, o, 64); }
        if ((t & 63) == 0) {
            float mean = sv * (1.f / 65536.f);
            float var = ssv * (1.f / 65536.f) - mean * mean;
            sm[t >> 6] = mean;
            sr[t >> 6] = rsqrtf(var + 1e-5f);
        }
    }
    __syncthreads();
    {
        const int j = t >> 2, c0 = (t & 3) * 16, g = c0 >> 4;
        const float mean = sm[g], rstd = sr[g];
        const float* src = x + (((size_t)b * 64 + i) * 64 + j) * 64 + c0;
#pragma unroll
        for (int k = 0; k < 4; k++) {
            float4 v = *(const float4*)(src + 4 * k);
            xn[j][c0 + 4 * k + 0] = (v.x - mean) * rstd * gg[c0 + 4 * k + 0] + gb[c0 + 4 * k + 0];
            xn[j][c0 + 4 * k + 1] = (v.y - mean) * rstd * gg[c0 + 4 * k + 1] + gb[c0 + 4 * k + 1];
            xn[j][c0 + 4 * k + 2] = (v.z - mean) * rstd * gg[c0 + 4 * k + 2] + gb[c0 + 4 * k + 2];
            xn[j][c0 + 4 * k + 3] = (v.w - mean) * rstd * gg[c0 + 4 * k + 3] + gb[c0 + 4 * k + 3];
        }
        const int o = t >> 2, cc0 = (t & 3) * 16;
#pragma unroll
        for (int k = 0; k < 16; k++) wsm[cc0 + k][o] = w[o * 64 + cc0 + k];
    }
    __syncthreads();
    const int jj = t & 63, olo = (t >> 6) * 16;
    float acc[16];
#pragma unroll
    for (int oi = 0; oi < 16; oi++) acc[oi] = bias[olo + oi];
    for (int c = 0; c < 64; c++) {
        float xv = xn[jj][c];
#pragma unroll
        for (int oi = 0; oi < 16; oi++) acc[oi] += xv * wsm[c][olo + oi];
    }
#pragma unroll
    for (int oi = 0; oi < 16; oi++)
        out[((size_t)b * LTOK + (size_t)(olo + oi) * 64 + i) * 64 + jj] = acc[oi];
}

// ---------------------------------------------------------------------------
// K3: Q/K/V projection, one phase per block (grid 256 x 3).
__global__ void qkv_kernel(const float* __restrict__ in,
                           const float* __restrict__ qw, const float* __restrict__ qb,
                           const float* __restrict__ kw, const float* __restrict__ kb,
                           const float* __restrict__ vw, const float* __restrict__ vb,
                           ushort* __restrict__ Qo, ushort* __restrict__ Ko, ushort* __restrict__ VTg) {
    __shared__ float xt[64][68];
    __shared__ float wt[64][64];
    __shared__ ushort vtr[64 * 72];
    const int t = threadIdx.x;
    const int ph = blockIdx.y;
    const size_t tok0 = (size_t)blockIdx.x * 64;
    const int b = blockIdx.x >> 6;
    const int tokb0 = (blockIdx.x & 63) * 64;
    const int r = t >> 2, cq = t & 3, olo = cq * 16;
    const float* W = (ph == 0) ? qw : (ph == 1) ? kw : vw;
    const float* Bb = (ph == 0) ? qb : (ph == 1) ? kb : vb;
    {
        const float4* src = (const float4*)(in + tok0 * 64) + (size_t)t * 4;
        float4* dst = (float4*)&xt[r][olo];
#pragma unroll
        for (int k = 0; k < 4; k++) dst[k] = src[k];
        const float4* ws2 = (const float4*)W + (size_t)t * 4;
        float4* wd = (float4*)wt + (size_t)t * 4;
#pragma unroll
        for (int k = 0; k < 4; k++) wd[k] = ws2[k];
    }
    __syncthreads();
    float acc[16];
#pragma unroll
    for (int k = 0; k < 4; k++) {
        float4 bv = *(const float4*)(Bb + olo + 4 * k);
        acc[4 * k] = bv.x; acc[4 * k + 1] = bv.y; acc[4 * k + 2] = bv.z; acc[4 * k + 3] = bv.w;
    }
    for (int f = 0; f < 64; f++) {
        float xv = xt[r][f];
#pragma unroll
        for (int oi = 0; oi < 16; oi++) acc[oi] += xv * wt[f][olo + oi];
    }
    if (ph < 2) {
        const float sc = (ph == 0) ? 0.180336880111f : 1.0f;   // 0.125 * log2(e)
        uint32_t u[8];
#pragma unroll
        for (int i = 0; i < 8; i++) u[i] = packbf2(acc[2 * i] * sc, acc[2 * i + 1] * sc);
        ushort* op = (ph == 0 ? Qo : Ko) + (tok0 + r) * 64 + olo;
        *(uint4*)op = make_uint4(u[0], u[1], u[2], u[3]);
        *(uint4*)(op + 8) = make_uint4(u[4], u[5], u[6], u[7]);
    } else {
#pragma unroll
        for (int oi = 0; oi < 16; oi++) vtr[(olo + oi) * 72 + r] = packbf1(acc[oi]);
        __syncthreads();
        const int o = t >> 2, ch = t & 3;
        uint4 a0 = *(const uint4*)&vtr[o * 72 + ch * 16];
        uint4 a1 = *(const uint4*)&vtr[o * 72 + ch * 16 + 8];
        ushort* op = VTg + (size_t)(b * 64 + o) * 4096 + tokb0 + ch * 16;
        *(uint4*)op = a0;
        *(uint4*)(op + 8) = a1;
    }
}

// ---------------------------------------------------------------------------
// K4: MFMA flash self-attention, max-free softmax, K-split x4, raw v_exp_f32,
// unrolled double-buffer with pointer-bumped prefetch.
__global__ __launch_bounds__(256) void flash_mfma(const ushort* __restrict__ Q,
                                                  const ushort* __restrict__ K,
                                                  const ushort* __restrict__ VTg,
                                                  float* __restrict__ Zp0, float* __restrict__ Zp1,
                                                  float* __restrict__ Zp2, float* __restrict__ Zp3,
                                                  float* __restrict__ Ls) {
    const int qt = blockIdx.x;            // 0..63
    const int bh = blockIdx.y;            // 0..7
    const int ks = blockIdx.z;            // 0..3
    const int b = bh >> 1, h = bh & 1;
    const int t = threadIdx.x;
    const int w = t >> 6, l = t & 63, lg = l >> 4, lq = l & 15;

    __shared__ ushort KsB[2][2048];       // [k][dh] swz ^((k&7)<<3)
    __shared__ ushort VTB[2][2048];       // [dh][k] swz ^((dh&7)<<3)
    __shared__ ushort Pl[4096];           // per-wave [q][k] swz ^((q&7)<<3)

    const size_t base = (size_t)b * LTOK * 64 + h * 32;
    const size_t vrow0 = (size_t)(b * 64 + h * 32);

    const short8v qf = *(const short8v*)(Q + base + (size_t)(qt * 64 + w * 16 + lq) * 64 + 8 * lg);

    const int krow = t >> 2, kdg = t & 3;
    const int koff = ((krow << 5) + kdg * 8) ^ ((krow & 7) << 3);
    const int vrow = t >> 3, vc8 = t & 7;
    const int voff = ((vrow << 6) + vc8 * 8) ^ ((vrow & 7) << 3);
    const ushort* kgp = K + base + (size_t)(ks * NIT * 64 + krow) * 64 + kdg * 8;
    const ushort* vgp = VTg + (vrow0 + vrow) * 4096 + ks * NIT * 64 + vc8 * 8;

    *(uint4*)&KsB[0][koff] = *(const uint4*)kgp;  kgp += 64 * 64;
    *(uint4*)&VTB[0][voff] = *(const uint4*)vgp;  vgp += 64;

    f32x4 accZ[2];
#pragma unroll
    for (int d = 0; d < 2; d++) accZ[d] = (f32x4){0.f, 0.f, 0.f, 0.f};
    float lacc = 0.0f;
    const f32x4 zero4 = {0.f, 0.f, 0.f, 0.f};
    const int pb = w << 10;

    auto body = [&](const ushort* Kc, const ushort* Vc, ushort* Kn, ushort* Vn, bool pref) {
        __syncthreads();
        uint4 kq = make_uint4(0, 0, 0, 0), vq = make_uint4(0, 0, 0, 0);
        if (pref) {
            kq = *(const uint4*)kgp; kgp += 64 * 64;
            vq = *(const uint4*)vgp; vgp += 64;
        }
        // --- S^T: 4 MFMAs ---
        f32x4 s4[4];
#pragma unroll
        for (int tk = 0; tk < 4; tk++) {
            const int kr = tk * 16 + lq;
            const short8v aK = *(const short8v*)&Kc[((kr << 5) + lg * 8) ^ ((lq & 7) << 3)];
            s4[tk] = __builtin_amdgcn_mfma_f32_16x16x32_bf16(aK, qf, zero4, 0, 0, 0);
        }
        // --- max-free softmax: raw v_exp_f32 ---
        uint32_t pw[8];
#pragma unroll
        for (int tk = 0; tk < 4; tk++) {
            float p0 = __builtin_amdgcn_exp2f(s4[tk][0]);
            float p1 = __builtin_amdgcn_exp2f(s4[tk][1]);
            float p2 = __builtin_amdgcn_exp2f(s4[tk][2]);
            float p3 = __builtin_amdgcn_exp2f(s4[tk][3]);
            lacc += (p0 + p1) + (p2 + p3);
            pw[2 * tk]     = packbf2(p0, p1);
            pw[2 * tk + 1] = packbf2(p2, p3);
        }
        // --- P -> per-wave LDS ---
#pragma unroll
        for (int tk = 0; tk < 4; tk++) {
            const int idx = ((lq << 6) + tk * 16 + lg * 4) ^ ((lq & 7) << 3);
            *(uint2*)&Pl[pb + idx] = make_uint2(pw[2 * tk], pw[2 * tk + 1]);
        }
        // --- PV ---
#pragma unroll
        for (int kc = 0; kc < 2; kc++) {
            const int ia = ((lq << 6) + kc * 32 + lg * 8) ^ ((lq & 7) << 3);
            const short8v aP = *(const short8v*)&Pl[pb + ia];
#pragma unroll
            for (int dt = 0; dt < 2; dt++) {
                const int ib = (((dt * 16 + lq) << 6) + kc * 32 + lg * 8) ^ ((lq & 7) << 3);
                const short8v bV = *(const short8v*)&Vc[ib];
                accZ[dt] = __builtin_amdgcn_mfma_f32_16x16x32_bf16(aP, bV, accZ[dt], 0, 0, 0);
            }
        }
        if (pref) {
            *(uint4*)&Kn[koff] = kq;
            *(uint4*)&Vn[voff] = vq;
        }
    };

#pragma unroll 1
    for (int it = 0; it < NIT / 2; it++) {
        body(KsB[0], VTB[0], KsB[1], VTB[1], true);            // compute tile 2it, prefetch 2it+1
        body(KsB[1], VTB[1], KsB[0], VTB[0], it < NIT / 2 - 1); // compute 2it+1, prefetch 2it+2
    }

    float* Zo = (ks == 0) ? Zp0 : (ks == 1) ? Zp1 : (ks == 2) ? Zp2 : Zp3;
#pragma unroll
    for (int rr = 0; rr < 4; rr++) {
        const int qrow = qt * 64 + w * 16 + lg * 4 + rr;
#pragma unroll
        for (int dt = 0; dt < 2; dt++)
            Zo[base + (size_t)qrow * 64 + dt * 16 + lq] = accZ[dt][rr];
    }
    lacc += __shfl_xor(lacc, 16, 64);
    lacc += __shfl_xor(lacc, 32, 64);
    if (l < 16)
        Ls[ks * 32768 + bh * 4096 + qt * 64 + w * 16 + lq] = lacc;
}

// ---------------------------------------------------------------------------
// K8: fused tail — Z-combine(4) + ow+LN2+GELU, ca_kv, ca_q, cross-attn,
// ca_ow+LN3, ff1+LN4, conv2. 512 threads, 64 tokens per block.
__global__ __launch_bounds__(512) void tail_fused(
    const float* __restrict__ Zp0, const float* __restrict__ Zp1,
    const float* __restrict__ Zp2, const float* __restrict__ Zp3,
    const float* __restrict__ Ls, const float* __restrict__ xs0,
    const float* __restrict__ slots,
    const float* __restrict__ ckw, const float* __restrict__ ckb,
    const float* __restrict__ cvw, const float* __restrict__ cvb,
    const float* __restrict__ ow, const float* __restrict__ ob,
    const float* __restrict__ g2, const float* __restrict__ b2,
    const float* __restrict__ qw, const float* __restrict__ qb,
    const float* __restrict__ cow, const float* __restrict__ cob,
    const float* __restrict__ g3, const float* __restrict__ b3,
    const float* __restrict__ fw, const float* __restrict__ fb,
    const float* __restrict__ g4, const float* __restrict__ b4,
    const float* __restrict__ cw, const float* __restrict__ cb,
    float* __restrict__ out)
{
    const int t = threadIdx.x;
    const size_t tok0 = (size_t)blockIdx.x * 64;
    const int b = blockIdx.x >> 6;
    const int r = t >> 3, c = t & 7, olo = c * 8;
    __shared__ float xt[64][68];
    __shared__ float wt[64][64];
    __shared__ float kcs[512], vcs[512], sls[512];

    float acc[8], res[8];

    auto stage_w = [&](const float* W) {
        ((float4*)wt)[2 * t] = ((const float4*)W)[2 * t];
        ((float4*)wt)[2 * t + 1] = ((const float4*)W)[2 * t + 1];
    };
    auto stage_x_res = [&]() {
        float4* xd = (float4*)&xt[r][olo];
        xd[0] = make_float4(res[0], res[1], res[2], res[3]);
        xd[1] = make_float4(res[4], res[5], res[6], res[7]);
    };
    auto load8 = [&](float* dst, const float* p) {
        float4 u0 = *(const float4*)(p + olo);
        float4 u1 = *(const float4*)(p + olo + 4);
        dst[0] = u0.x; dst[1] = u0.y; dst[2] = u0.z; dst[3] = u0.w;
        dst[4] = u1.x; dst[5] = u1.y; dst[6] = u1.z; dst[7] = u1.w;
    };
    auto mm = [&](const float* bias) {
        load8(acc, bias);
        for (int f = 0; f < 64; f++) {
            float xv = xt[r][f];
#pragma unroll
            for (int oi = 0; oi < 8; oi++) acc[oi] += xv * wt[f][olo + oi];
        }
    };
    auto ln = [&](const float* gv, const float* bv, bool dogelu) {
        float s1 = 0.f, s2 = 0.f;
#pragma unroll
        for (int oi = 0; oi < 8; oi++) { s1 += acc[oi]; s2 += acc[oi] * acc[oi]; }
#pragma unroll
        for (int o = 1; o <= 4; o <<= 1) {
            s1 += __shfl_xor(s1, o, 64);
            s2 += __shfl_xor(s2, o, 64);
        }
        float mean = s1 * (1.f / 64.f);
        float var = s2 * (1.f / 64.f) - mean * mean;
        float rstd = rsqrtf(var + 1e-5f);
        float gl[8], bl[8];
        load8(gl, gv); load8(bl, bv);
#pragma unroll
        for (int oi = 0; oi < 8; oi++) {
            float y = (acc[oi] - mean) * rstd * gl[oi] + bl[oi] + res[oi];
            res[oi] = dogelu ? gelu_exact(y) : y;
        }
    };

    // ---- phase 1: combine 4 flash partials, t0 = Z@ow+ob ; res = xs1
    {
        if (t < 128) ((float4*)sls)[t] = ((const float4*)(slots + (size_t)b * 512))[t];
        const float4* z0 = (const float4*)(Zp0 + tok0 * 64);
        const float4* z1 = (const float4*)(Zp1 + tok0 * 64);
        const float4* z2 = (const float4*)(Zp2 + tok0 * 64);
        const float4* z3 = (const float4*)(Zp3 + tok0 * 64);
        float4 a0 = z0[2 * t], a1 = z0[2 * t + 1];
        float4 b0 = z1[2 * t], b1 = z1[2 * t + 1];
        float4 c0 = z2[2 * t], c1 = z2[2 * t + 1];
        float4 d0 = z3[2 * t], d1 = z3[2 * t + 1];
        const int hh = olo >> 5;
        const int bh_ = b * 2 + hh;
        const int tokb = (blockIdx.x & 63) * 64 + r;
        const float lt = Ls[bh_ * 4096 + tokb] + Ls[32768 + bh_ * 4096 + tokb]
                       + Ls[65536 + bh_ * 4096 + tokb] + Ls[98304 + bh_ * 4096 + tokb];
        const float inv = 1.0f / lt;
        float4* xd = (float4*)&xt[r][olo];
        xd[0] = make_float4(((a0.x + b0.x) + (c0.x + d0.x)) * inv,
                            ((a0.y + b0.y) + (c0.y + d0.y)) * inv,
                            ((a0.z + b0.z) + (c0.z + d0.z)) * inv,
                            ((a0.w + b0.w) + (c0.w + d0.w)) * inv);
        xd[1] = make_float4(((a1.x + b1.x) + (c1.x + d1.x)) * inv,
                            ((a1.y + b1.y) + (c1.y + d1.y)) * inv,
                            ((a1.z + b1.z) + (c1.z + d1.z)) * inv,
                            ((a1.w + b1.w) + (c1.w + d1.w)) * inv);
        stage_w(ow);
        float4 r0 = *(const float4*)(xs0 + (tok0 + r) * 64 + olo);
        float4 r1 = *(const float4*)(xs0 + (tok0 + r) * 64 + olo + 4);
        res[0] = r0.x; res[1] = r0.y; res[2] = r0.z; res[3] = r0.w;
        res[4] = r1.x; res[5] = r1.y; res[6] = r1.z; res[7] = r1.w;
    }
    __syncthreads();
    // ---- cross-attn K/V from slots (redundant per block, cheap)
    {
        const int j = t >> 6, o = t & 63;
        float ak = ckb[o], av = cvb[o];
#pragma unroll 8
        for (int c2 = 0; c2 < 64; c2++) {
            float sv = sls[j * 64 + c2];
            ak += sv * ckw[c2 * 64 + o];
            av += sv * cvw[c2 * 64 + o];
        }
        kcs[t] = ak; vcs[t] = av;
    }
    mm(ob);
    ln(g2, b2, true);

    // ---- phase 2: qca = xs1@qw+qb ; acc = cross-attn(zca)
    __syncthreads();
    stage_x_res();
    stage_w(qw);
    __syncthreads();
    mm(qb);
    {
        float p[8];
        float mx = -3.0e38f;
#pragma unroll
        for (int j = 0; j < 8; j++) {
            float d = 0.f;
#pragma unroll
            for (int i2 = 0; i2 < 8; i2++) d += acc[i2] * kcs[j * 64 + olo + i2];
            d += __shfl_xor(d, 1, 64);
            d += __shfl_xor(d, 2, 64);
            d *= 0.125f;
            p[j] = d;
            mx = fmaxf(mx, d);
        }
        float es = 0.f;
#pragma unroll
        for (int j = 0; j < 8; j++) { p[j] = __expf(p[j] - mx); es += p[j]; }
        float inv = 1.f / es;
#pragma unroll
        for (int oi = 0; oi < 8; oi++) {
            float z = 0.f;
#pragma unroll
            for (int j = 0; j < 8; j++) z += p[j] * vcs[j * 64 + olo + oi];
            acc[oi] = z * inv;
        }
    }

    // ---- phase 3: t1 = zca@cow+cob ; res = xs2 = LN3(t1)+xs1
    __syncthreads();
    {
        float4* xd = (float4*)&xt[r][olo];
        xd[0] = make_float4(acc[0], acc[1], acc[2], acc[3]);
        xd[1] = make_float4(acc[4], acc[5], acc[6], acc[7]);
    }
    stage_w(cow);
    __syncthreads();
    mm(cob);
    ln(g3, b3, false);

    // ---- phase 4: t2 = xs2@fw+fb ; res = xs3 = LN4(t2)+xs2
    __syncthreads();
    stage_x_res();
    stage_w(fw);
    __syncthreads();
    mm(fb);
    ln(g4, b4, false);

    // ---- phase 5: out = xs3 @ conv2^T + cb
    __syncthreads();
    stage_x_res();
    {
        const int o5 = t >> 3, c5 = (t & 7) * 8;
#pragma unroll
        for (int k = 0; k < 8; k++) wt[c5 + k][o5] = cw[o5 * 64 + c5 + k];
    }
    __syncthreads();
    mm(cb);
    float* op = out + (tok0 + r) * 64 + olo;
    *(float4*)op = make_float4(acc[0], acc[1], acc[2], acc[3]);
    *(float4*)(op + 4) = make_float4(acc[4], acc[5], acc[6], acc[7]);
}

// ---------------------------------------------------------------------------
extern "C" void kernel_launch(void* const* d_in, const int* in_sizes, int n_in,
                              void* d_out, int out_size, void* d_ws, size_t ws_size,
                              hipStream_t stream) {
    const float* x       = (const float*)d_in[0];
    const float* slots   = (const float*)d_in[1];
    const float* conv1_w = (const float*)d_in[2];
    const float* conv1_b = (const float*)d_in[3];
    const float* conv2_w = (const float*)d_in[4];
    const float* conv2_b = (const float*)d_in[5];
    const float* gn_g    = (const float*)d_in[6];
    const float* gn_b    = (const float*)d_in[7];
    const float* ln2_g   = (const float*)d_in[8];
    const float* ln2_b   = (const float*)d_in[9];
    const float* ln3_g   = (const float*)d_in[10];
    const float* ln3_b   = (const float*)d_in[11];
    const float* ln4_g   = (const float*)d_in[12];
    const float* ln4_b   = (const float*)d_in[13];
    const float* sa_qw   = (const float*)d_in[14];
    const float* sa_qb   = (const float*)d_in[15];
    const float* sa_kw   = (const float*)d_in[16];
    const float* sa_kb   = (const float*)d_in[17];
    const float* sa_vw   = (const float*)d_in[18];
    const float* sa_vb   = (const float*)d_in[19];
    const float* sa_ow   = (const float*)d_in[20];
    const float* sa_ob   = (const float*)d_in[21];
    const float* ca_qw   = (const float*)d_in[22];
    const float* ca_qb   = (const float*)d_in[23];
    const float* ca_kw   = (const float*)d_in[24];
    const float* ca_kb   = (const float*)d_in[25];
    const float* ca_vw   = (const float*)d_in[26];
    const float* ca_vb   = (const float*)d_in[27];
    const float* ca_ow   = (const float*)d_in[28];
    const float* ca_ob   = (const float*)d_in[29];
    const float* ff1_w   = (const float*)d_in[30];
    const float* ff1_b   = (const float*)d_in[31];

    float* ws = (float*)d_ws;
    const size_t NBUF = (size_t)NBATCH * LTOK * FD;   // 1,048,576 elements
    float* partS  = ws;                    // 1024
    float* partSS = ws + 1024;             // 1024
    float* A      = ws + 4096;             // xs0, 4 MB
    ushort* Kb    = (ushort*)(A + NBUF);   // 2 MB
    ushort* VTgb  = Kb + NBUF;             // 2 MB
    ushort* Qb    = VTgb + NBUF;           // 2 MB
    float* Zp1    = (float*)(Qb + NBUF);   // 4 MB
    float* Zp2    = Zp1 + NBUF;            // 4 MB
    float* Zp3    = Zp2 + NBUF;            // 4 MB
    float* Ls     = Zp3 + NBUF;            // 512 KB (4 x 32768 floats)
    float* Zp0    = (float*)d_out;         // 4 MB scratch; tail reads == writes per block

    gn_part_kernel<<<256, 256, 0, stream>>>(x, partS, partSS);
    gn_conv1_kernel<<<256, 256, 0, stream>>>(x, partS, partSS, gn_g, gn_b, conv1_w, conv1_b, A);
    qkv_kernel<<<dim3(256, 3), 256, 0, stream>>>(A, sa_qw, sa_qb, sa_kw, sa_kb, sa_vw, sa_vb, Qb, Kb, VTgb);
    flash_mfma<<<dim3(64, 8, 4), 256, 0, stream>>>(Qb, Kb, VTgb, Zp0, Zp1, Zp2, Zp3, Ls);
    tail_fused<<<256, 512, 0, stream>>>(Zp0, Zp1, Zp2, Zp3, Ls, A, slots,
                                        ca_kw, ca_kb, ca_vw, ca_vb,
                                        sa_ow, sa_ob, ln2_g, ln2_b,
                                        ca_qw, ca_qb, ca_ow, ca_ob, ln3_g, ln3_b,
                                        ff1_w, ff1_b, ln4_g, ln4_b,
                                        conv2_w, conv2_b, (float*)d_out);
}

// Round 6
// 94.538 us; speedup vs baseline: 8.5455x; 1.0071x over previous
//
#include <hip/hip_runtime.h>
#include <hip/hip_bf16.h>
#include <math.h>

#define NBATCH 4
#define LTOK   4096
#define FD     64
#define KSPLIT 4
#define NIT    16    // staged 64-k tiles per flash block = 4096/KSPLIT/64

typedef __attribute__((ext_vector_type(8))) short short8v;   // 8 bf16 = 4 VGPR
typedef __attribute__((ext_vector_type(4))) float f32x4;
typedef __attribute__((ext_vector_type(16))) float f32x16;

static __device__ inline uint32_t packbf2(float a, float b) {
    float2 f; f.x = a; f.y = b;
    __hip_bfloat162 h = __float22bfloat162_rn(f);
    uint32_t u; __builtin_memcpy(&u, &h, 4);
    return u;
}
static __device__ inline ushort packbf1(float a) {
    __hip_bfloat16 h = __float2bfloat16(a);
    ushort u; __builtin_memcpy(&u, &h, 2);
    return u;
}
static __device__ inline float gelu_exact(float y) {
    return 0.5f * y * (1.0f + erff(y * 0.70710678118654752f));
}

// ---------------------------------------------------------------------------
// K1: GroupNorm partial sums. 256 blocks (64 chunks per batch), coalesced.
__global__ void gn_part_kernel(const float* __restrict__ x,
                               float* __restrict__ partS, float* __restrict__ partSS) {
    const int b = blockIdx.x >> 6, c = blockIdx.x & 63;
    const int t = threadIdx.x, l = t & 63, wv = t >> 6;
    const float4* xb = (const float4*)(x + (size_t)b * 262144) + (size_t)c * 1024;
    float s = 0.f, ss = 0.f;
#pragma unroll
    for (int k = 0; k < 4; k++) {
        float4 v = xb[t + 256 * k];
        s += (v.x + v.y) + (v.z + v.w);
        ss += (v.x * v.x + v.y * v.y) + (v.z * v.z + v.w * v.w);
    }
#pragma unroll
    for (int o = 0; o < 4; o++) {
        const int off = (int[]){1, 2, 16, 32}[o];
        s += __shfl_xor(s, off, 64);
        ss += __shfl_xor(ss, off, 64);
    }
    __shared__ float ls_s[4][4], ls_ss[4][4];
    if ((l & 51) == 0) { ls_s[wv][(l >> 2) & 3] = s; ls_ss[wv][(l >> 2) & 3] = ss; }
    __syncthreads();
    if (t < 4) {
        float S = 0.f, SS = 0.f;
#pragma unroll
        for (int w2 = 0; w2 < 4; w2++) { S += ls_s[w2][t]; SS += ls_ss[w2][t]; }
        partS[b * 256 + t * 64 + c] = S;
        partSS[b * 256 + t * 64 + c] = SS;
    }
}

// ---------------------------------------------------------------------------
// K2: combine partials + GN-apply + conv1 + channels-first reshape.
__global__ void gn_conv1_kernel(const float* __restrict__ x,
                                const float* __restrict__ partS, const float* __restrict__ partSS,
                                const float* __restrict__ gg, const float* __restrict__ gb,
                                const float* __restrict__ w, const float* __restrict__ bias,
                                float* __restrict__ out) {
    const int b = blockIdx.x >> 6, i = blockIdx.x & 63;
    const int t = threadIdx.x;
    __shared__ float xn[64][65];
    __shared__ float wsm[64][64];   // [c][o]
    __shared__ float sm[4], sr[4];
    {
        float sv = partS[b * 256 + t];     // g = t>>6, chunk = t&63
        float ssv = partSS[b * 256 + t];
        for (int o = 32; o; o >>= 1) { sv += __shfl_xor(sv, o, 64); ssv += __shfl_xor(ssv, o, 64); }
        if ((t & 63) == 0) {
            float mean = sv * (1.f / 65536.f);
            float var = ssv * (1.f / 65536.f) - mean * mean;
            sm[t >> 6] = mean;
            sr[t >> 6] = rsqrtf(var + 1e-5f);
        }
    }
    __syncthreads();
    {
        const int j = t >> 2, c0 = (t & 3) * 16, g = c0 >> 4;
        const float mean = sm[g], rstd = sr[g];
        const float* src = x + (((size_t)b * 64 + i) * 64 + j) * 64 + c0;
#pragma unroll
        for (int k = 0; k < 4; k++) {
            float4 v = *(const float4*)(src + 4 * k);
            xn[j][c0 + 4 * k + 0] = (v.x - mean) * rstd * gg[c0 + 4 * k + 0] + gb[c0 + 4 * k + 0];
            xn[j][c0 + 4 * k + 1] = (v.y - mean) * rstd * gg[c0 + 4 * k + 1] + gb[c0 + 4 * k + 1];
            xn[j][c0 + 4 * k + 2] = (v.z - mean) * rstd * gg[c0 + 4 * k + 2] + gb[c0 + 4 * k + 2];
            xn[j][c0 + 4 * k + 3] = (v.w - mean) * rstd * gg[c0 + 4 * k + 3] + gb[c0 + 4 * k + 3];
        }
        const int o = t >> 2, cc0 = (t & 3) * 16;
#pragma unroll
        for (int k = 0; k < 16; k++) wsm[cc0 + k][o] = w[o * 64 + cc0 + k];
    }
    __syncthreads();
    const int jj = t & 63, olo = (t >> 6) * 16;
    float acc[16];
#pragma unroll
    for (int oi = 0; oi < 16; oi++) acc[oi] = bias[olo + oi];
    for (int c = 0; c < 64; c++) {
        float xv = xn[jj][c];
#pragma unroll
        for (int oi = 0; oi < 16; oi++) acc[oi] += xv * wsm[c][olo + oi];
    }
#pragma unroll
    for (int oi = 0; oi < 16; oi++)
        out[((size_t)b * LTOK + (size_t)(olo + oi) * 64 + i) * 64 + jj] = acc[oi];
}

// ---------------------------------------------------------------------------
// K3: Q/K/V projection, one phase per block (grid 256 x 3).
__global__ void qkv_kernel(const float* __restrict__ in,
                           const float* __restrict__ qw, const float* __restrict__ qb,
                           const float* __restrict__ kw, const float* __restrict__ kb,
                           const float* __restrict__ vw, const float* __restrict__ vb,
                           ushort* __restrict__ Qo, ushort* __restrict__ Ko, ushort* __restrict__ VTg) {
    __shared__ float xt[64][68];
    __shared__ float wt[64][64];
    __shared__ ushort vtr[64 * 72];
    const int t = threadIdx.x;
    const int ph = blockIdx.y;
    const size_t tok0 = (size_t)blockIdx.x * 64;
    const int b = blockIdx.x >> 6;
    const int tokb0 = (blockIdx.x & 63) * 64;
    const int r = t >> 2, cq = t & 3, olo = cq * 16;
    const float* W = (ph == 0) ? qw : (ph == 1) ? kw : vw;
    const float* Bb = (ph == 0) ? qb : (ph == 1) ? kb : vb;
    {
        const float4* src = (const float4*)(in + tok0 * 64) + (size_t)t * 4;
        float4* dst = (float4*)&xt[r][olo];
#pragma unroll
        for (int k = 0; k < 4; k++) dst[k] = src[k];
        const float4* ws2 = (const float4*)W + (size_t)t * 4;
        float4* wd = (float4*)wt + (size_t)t * 4;
#pragma unroll
        for (int k = 0; k < 4; k++) wd[k] = ws2[k];
    }
    __syncthreads();
    float acc[16];
#pragma unroll
    for (int k = 0; k < 4; k++) {
        float4 bv = *(const float4*)(Bb + olo + 4 * k);
        acc[4 * k] = bv.x; acc[4 * k + 1] = bv.y; acc[4 * k + 2] = bv.z; acc[4 * k + 3] = bv.w;
    }
    for (int f = 0; f < 64; f++) {
        float xv = xt[r][f];
#pragma unroll
        for (int oi = 0; oi < 16; oi++) acc[oi] += xv * wt[f][olo + oi];
    }
    if (ph < 2) {
        const float sc = (ph == 0) ? 0.180336880111f : 1.0f;   // 0.125 * log2(e)
        uint32_t u[8];
#pragma unroll
        for (int i = 0; i < 8; i++) u[i] = packbf2(acc[2 * i] * sc, acc[2 * i + 1] * sc);
        ushort* op = (ph == 0 ? Qo : Ko) + (tok0 + r) * 64 + olo;
        *(uint4*)op = make_uint4(u[0], u[1], u[2], u[3]);
        *(uint4*)(op + 8) = make_uint4(u[4], u[5], u[6], u[7]);
    } else {
#pragma unroll
        for (int oi = 0; oi < 16; oi++) vtr[(olo + oi) * 72 + r] = packbf1(acc[oi]);
        __syncthreads();
        const int o = t >> 2, ch = t & 3;
        uint4 a0 = *(const uint4*)&vtr[o * 72 + ch * 16];
        uint4 a1 = *(const uint4*)&vtr[o * 72 + ch * 16 + 8];
        ushort* op = VTg + (size_t)(b * 64 + o) * 4096 + tokb0 + ch * 16;
        *(uint4*)op = a0;
        *(uint4*)(op + 8) = a1;
    }
}

// ---------------------------------------------------------------------------
// K4: MFMA flash self-attention, 32x32x16 MFMA, max-free softmax, K-split x4.
// Block: 4 waves x 32 q (QBLK=128). Grid (32, 8, 4). No P LDS round-trip:
// P is redistributed to the A-fragment via cvt_pk + shfl_xor(32) (sigma-swap).
__global__ __launch_bounds__(256) void flash_mfma(const ushort* __restrict__ Q,
                                                  const ushort* __restrict__ K,
                                                  const ushort* __restrict__ VTg,
                                                  float* __restrict__ Zp0, float* __restrict__ Zp1,
                                                  float* __restrict__ Zp2, float* __restrict__ Zp3,
                                                  float* __restrict__ Ls) {
    const int qt = blockIdx.x;            // 0..31
    const int bh = blockIdx.y;            // 0..7
    const int ks = blockIdx.z;            // 0..3
    const int b = bh >> 1, h = bh & 1;
    const int t = threadIdx.x;
    const int w = t >> 6, l = t & 63, lq = l & 31, sig = l >> 5;

    __shared__ ushort KsB[2][2048];       // [k][dh] swz ^((k&7)<<3)
    __shared__ ushort VTB[2][2048];       // [dh][k] swz ^((dh&7)<<3)

    const size_t base = (size_t)b * LTOK * 64 + h * 32;
    const size_t vrow0 = (size_t)(b * 64 + h * 32);

    const int qrow = qt * 128 + w * 32 + lq;
    const short8v qf0 = *(const short8v*)(Q + base + (size_t)qrow * 64 + 8 * sig);
    const short8v qf1 = *(const short8v*)(Q + base + (size_t)qrow * 64 + 16 + 8 * sig);

    const int krow = t >> 2, kdg = t & 3;
    const int koff = ((krow << 5) + kdg * 8) ^ ((krow & 7) << 3);
    const int vrow = t >> 3, vc8 = t & 7;
    const int voff = ((vrow << 6) + vc8 * 8) ^ ((vrow & 7) << 3);
    const ushort* kgp = K + base + (size_t)(ks * NIT * 64 + krow) * 64 + kdg * 8;
    const ushort* vgp = VTg + (vrow0 + vrow) * 4096 + ks * NIT * 64 + vc8 * 8;

    *(uint4*)&KsB[0][koff] = *(const uint4*)kgp;  kgp += 64 * 64;
    *(uint4*)&VTB[0][voff] = *(const uint4*)vgp;  vgp += 64;

    f32x16 accZ;
#pragma unroll
    for (int i = 0; i < 16; i++) accZ[i] = 0.f;
    f32x16 zero16;
#pragma unroll
    for (int i = 0; i < 16; i++) zero16[i] = 0.f;
    float lacc = 0.0f;

    auto body = [&](const ushort* Kc, const ushort* Vc, ushort* Kn, ushort* Vn, bool pref) {
        __syncthreads();
        uint4 kq = make_uint4(0, 0, 0, 0), vq = make_uint4(0, 0, 0, 0);
        if (pref) {
            kq = *(const uint4*)kgp; kgp += 64 * 64;
            vq = *(const uint4*)vgp; vgp += 64;
        }
#pragma unroll
        for (int kb2 = 0; kb2 < 2; kb2++) {
            const int kb = kb2 * 32;
            const int kr = kb + lq;
            // --- S^T = K . Q^T : 2 MFMAs over dh chunks ---
            const short8v aK0 = *(const short8v*)&Kc[((kr << 5) + 8 * sig) ^ ((kr & 7) << 3)];
            const short8v aK1 = *(const short8v*)&Kc[((kr << 5) + 16 + 8 * sig) ^ ((kr & 7) << 3)];
            f32x16 st = __builtin_amdgcn_mfma_f32_32x32x16_bf16(aK0, qf0, zero16, 0, 0, 0);
            st = __builtin_amdgcn_mfma_f32_32x32x16_bf16(aK1, qf1, st, 0, 0, 0);
            // --- max-free softmax, lane-local: p = exp2(s) ---
            uint32_t pk[8];
#pragma unroll
            for (int i = 0; i < 8; i++) {
                float p0 = __builtin_amdgcn_exp2f(st[2 * i]);
                float p1 = __builtin_amdgcn_exp2f(st[2 * i + 1]);
                lacc += p0 + p1;
                pk[i] = packbf2(p0, p1);
            }
            // --- P -> A-fragment: sigma half-swap (no LDS) ---
            const uint32_t r1 = __shfl_xor(sig ? pk[0] : pk[2], 32, 64);
            const uint32_t r2 = __shfl_xor(sig ? pk[1] : pk[3], 32, 64);
            const uint32_t r3 = __shfl_xor(sig ? pk[4] : pk[6], 32, 64);
            const uint32_t r4 = __shfl_xor(sig ? pk[5] : pk[7], 32, 64);
            uint4 A0 = make_uint4(sig ? r1 : pk[0], sig ? r2 : pk[1],
                                  sig ? pk[2] : r1, sig ? pk[3] : r2);
            uint4 A1 = make_uint4(sig ? r3 : pk[4], sig ? r4 : pk[5],
                                  sig ? pk[6] : r3, sig ? pk[7] : r4);
            short8v aP0, aP1;
            __builtin_memcpy(&aP0, &A0, 16);
            __builtin_memcpy(&aP1, &A1, 16);
            // --- PV: B = V^T fragment reads ---
            const short8v vt0 = *(const short8v*)&Vc[((lq << 6) + kb + 8 * sig) ^ ((lq & 7) << 3)];
            const short8v vt1 = *(const short8v*)&Vc[((lq << 6) + kb + 16 + 8 * sig) ^ ((lq & 7) << 3)];
            accZ = __builtin_amdgcn_mfma_f32_32x32x16_bf16(aP0, vt0, accZ, 0, 0, 0);
            accZ = __builtin_amdgcn_mfma_f32_32x32x16_bf16(aP1, vt1, accZ, 0, 0, 0);
        }
        if (pref) {
            *(uint4*)&Kn[koff] = kq;
            *(uint4*)&Vn[voff] = vq;
        }
    };

#pragma unroll 1
    for (int it = 0; it < NIT / 2; it++) {
        body(KsB[0], VTB[0], KsB[1], VTB[1], true);
        body(KsB[1], VTB[1], KsB[0], VTB[0], it < NIT / 2 - 1);
    }

    float* Zo = (ks == 0) ? Zp0 : (ks == 1) ? Zp1 : (ks == 2) ? Zp2 : Zp3;
#pragma unroll
    for (int r = 0; r < 16; r++) {
        const int qr = qt * 128 + w * 32 + (r & 3) + 8 * (r >> 2) + 4 * sig;
        Zo[base + (size_t)qr * 64 + lq] = accZ[r];
    }
    lacc += __shfl_xor(lacc, 32, 64);
    if (l < 32)
        Ls[ks * 32768 + bh * 4096 + qt * 128 + w * 32 + lq] = lacc;
}

// ---------------------------------------------------------------------------
// K8: fused tail — Z-combine(4) + ow+LN2+GELU, ca_kv, ca_q, cross-attn,
// ca_ow+LN3, ff1+LN4, conv2. 512 blocks x 256 threads, 32 tokens per block.
__global__ __launch_bounds__(256) void tail_fused(
    const float* __restrict__ Zp0, const float* __restrict__ Zp1,
    const float* __restrict__ Zp2, const float* __restrict__ Zp3,
    const float* __restrict__ Ls, const float* __restrict__ xs0,
    const float* __restrict__ slots,
    const float* __restrict__ ckw, const float* __restrict__ ckb,
    const float* __restrict__ cvw, const float* __restrict__ cvb,
    const float* __restrict__ ow, const float* __restrict__ ob,
    const float* __restrict__ g2, const float* __restrict__ b2,
    const float* __restrict__ qw, const float* __restrict__ qb,
    const float* __restrict__ cow, const float* __restrict__ cob,
    const float* __restrict__ g3, const float* __restrict__ b3,
    const float* __restrict__ fw, const float* __restrict__ fb,
    const float* __restrict__ g4, const float* __restrict__ b4,
    const float* __restrict__ cw, const float* __restrict__ cb,
    float* __restrict__ out)
{
    const int t = threadIdx.x;
    const size_t tok0 = (size_t)blockIdx.x * 32;
    const int b = blockIdx.x >> 7;
    const int r = t >> 3, c = t & 7, olo = c * 8;
    __shared__ float xt[32][68];
    __shared__ float wt[64][64];
    __shared__ float kcs[512], vcs[512], sls[512];

    float acc[8], res[8];

    auto stage_w = [&](const float* W) {
#pragma unroll
        for (int k = 0; k < 4; k++)
            ((float4*)wt)[4 * t + k] = ((const float4*)W)[4 * t + k];
    };
    auto stage_x_res = [&]() {
        float4* xd = (float4*)&xt[r][olo];
        xd[0] = make_float4(res[0], res[1], res[2], res[3]);
        xd[1] = make_float4(res[4], res[5], res[6], res[7]);
    };
    auto load8 = [&](float* dst, const float* p) {
        float4 u0 = *(const float4*)(p + olo);
        float4 u1 = *(const float4*)(p + olo + 4);
        dst[0] = u0.x; dst[1] = u0.y; dst[2] = u0.z; dst[3] = u0.w;
        dst[4] = u1.x; dst[5] = u1.y; dst[6] = u1.z; dst[7] = u1.w;
    };
    auto mm = [&](const float* bias) {
        load8(acc, bias);
        for (int f = 0; f < 64; f++) {
            float xv = xt[r][f];
#pragma unroll
            for (int oi = 0; oi < 8; oi++) acc[oi] += xv * wt[f][olo + oi];
        }
    };
    auto ln = [&](const float* gv, const float* bv, bool dogelu) {
        float s1 = 0.f, s2 = 0.f;
#pragma unroll
        for (int oi = 0; oi < 8; oi++) { s1 += acc[oi]; s2 += acc[oi] * acc[oi]; }
#pragma unroll
        for (int o = 1; o <= 4; o <<= 1) {
            s1 += __shfl_xor(s1, o, 64);
            s2 += __shfl_xor(s2, o, 64);
        }
        float mean = s1 * (1.f / 64.f);
        float var = s2 * (1.f / 64.f) - mean * mean;
        float rstd = rsqrtf(var + 1e-5f);
        float gl[8], bl[8];
        load8(gl, gv); load8(bl, bv);
#pragma unroll
        for (int oi = 0; oi < 8; oi++) {
            float y = (acc[oi] - mean) * rstd * gl[oi] + bl[oi] + res[oi];
            res[oi] = dogelu ? gelu_exact(y) : y;
        }
    };

    // ---- phase 1: combine 4 flash partials, t0 = Z@ow+ob ; res = xs1
    {
        if (t < 128) ((float4*)sls)[t] = ((const float4*)(slots + (size_t)b * 512))[t];
        const float4* z0 = (const float4*)(Zp0 + tok0 * 64);
        const float4* z1 = (const float4*)(Zp1 + tok0 * 64);
        const float4* z2 = (const float4*)(Zp2 + tok0 * 64);
        const float4* z3 = (const float4*)(Zp3 + tok0 * 64);
        float4 a0 = z0[2 * t], a1 = z0[2 * t + 1];
        float4 b0 = z1[2 * t], b1 = z1[2 * t + 1];
        float4 c0 = z2[2 * t], c1 = z2[2 * t + 1];
        float4 d0 = z3[2 * t], d1 = z3[2 * t + 1];
        const int hh = olo >> 5;
        const int bh_ = b * 2 + hh;
        const int tokb = (blockIdx.x & 127) * 32 + r;
        const float lt = Ls[bh_ * 4096 + tokb] + Ls[32768 + bh_ * 4096 + tokb]
                       + Ls[65536 + bh_ * 4096 + tokb] + Ls[98304 + bh_ * 4096 + tokb];
        const float inv = 1.0f / lt;
        float4* xd = (float4*)&xt[r][olo];
        xd[0] = make_float4(((a0.x + b0.x) + (c0.x + d0.x)) * inv,
                            ((a0.y + b0.y) + (c0.y + d0.y)) * inv,
                            ((a0.z + b0.z) + (c0.z + d0.z)) * inv,
                            ((a0.w + b0.w) + (c0.w + d0.w)) * inv);
        xd[1] = make_float4(((a1.x + b1.x) + (c1.x + d1.x)) * inv,
                            ((a1.y + b1.y) + (c1.y + d1.y)) * inv,
                            ((a1.z + b1.z) + (c1.z + d1.z)) * inv,
                            ((a1.w + b1.w) + (c1.w + d1.w)) * inv);
        stage_w(ow);
        float4 r0 = *(const float4*)(xs0 + (tok0 + r) * 64 + olo);
        float4 r1 = *(const float4*)(xs0 + (tok0 + r) * 64 + olo + 4);
        res[0] = r0.x; res[1] = r0.y; res[2] = r0.z; res[3] = r0.w;
        res[4] = r1.x; res[5] = r1.y; res[6] = r1.z; res[7] = r1.w;
    }
    __syncthreads();
    // ---- cross-attn K/V from slots (redundant per block, cheap)
    for (int jo = t; jo < 512; jo += 256) {
        const int j = jo >> 6, o = jo & 63;
        float ak = ckb[o], av = cvb[o];
#pragma unroll 8
        for (int c2 = 0; c2 < 64; c2++) {
            float sv = sls[j * 64 + c2];
            ak += sv * ckw[c2 * 64 + o];
            av += sv * cvw[c2 * 64 + o];
        }
        kcs[jo] = ak; vcs[jo] = av;
    }
    mm(ob);
    ln(g2, b2, true);

    // ---- phase 2: qca = xs1@qw+qb ; acc = cross-attn(zca)
    __syncthreads();
    stage_x_res();
    stage_w(qw);
    __syncthreads();
    mm(qb);
    {
        float p[8];
        float mx = -3.0e38f;
#pragma unroll
        for (int j = 0; j < 8; j++) {
            float d = 0.f;
#pragma unroll
            for (int i2 = 0; i2 < 8; i2++) d += acc[i2] * kcs[j * 64 + olo + i2];
            d += __shfl_xor(d, 1, 64);
            d += __shfl_xor(d, 2, 64);
            d *= 0.125f;
            p[j] = d;
            mx = fmaxf(mx, d);
        }
        float es = 0.f;
#pragma unroll
        for (int j = 0; j < 8; j++) { p[j] = __expf(p[j] - mx); es += p[j]; }
        float inv = 1.f / es;
#pragma unroll
        for (int oi = 0; oi < 8; oi++) {
            float z = 0.f;
#pragma unroll
            for (int j = 0; j < 8; j++) z += p[j] * vcs[j * 64 + olo + oi];
            acc[oi] = z * inv;
        }
    }

    // ---- phase 3: t1 = zca@cow+cob ; res = xs2 = LN3(t1)+xs1
    __syncthreads();
    {
        float4* xd = (float4*)&xt[r][olo];
        xd[0] = make_float4(acc[0], acc[1], acc[2], acc[3]);
        xd[1] = make_float4(acc[4], acc[5], acc[6], acc[7]);
    }
    stage_w(cow);
    __syncthreads();
    mm(cob);
    ln(g3, b3, false);

    // ---- phase 4: t2 = xs2@fw+fb ; res = xs3 = LN4(t2)+xs2
    __syncthreads();
    stage_x_res();
    stage_w(fw);
    __syncthreads();
    mm(fb);
    ln(g4, b4, false);

    // ---- phase 5: out = xs3 @ conv2^T + cb
    __syncthreads();
    stage_x_res();
    {
        const int o5 = t >> 2, c5 = (t & 3) * 16;
#pragma unroll
        for (int k = 0; k < 16; k++) wt[c5 + k][o5] = cw[o5 * 64 + c5 + k];
    }
    __syncthreads();
    mm(cb);
    float* op = out + (tok0 + r) * 64 + olo;
    *(float4*)op = make_float4(acc[0], acc[1], acc[2], acc[3]);
    *(float4*)(op + 4) = make_float4(acc[4], acc[5], acc[6], acc[7]);
}

// ---------------------------------------------------------------------------
extern "C" void kernel_launch(void* const* d_in, const int* in_sizes, int n_in,
                              void* d_out, int out_size, void* d_ws, size_t ws_size,
                              hipStream_t stream) {
    const float* x       = (const float*)d_in[0];
    const float* slots   = (const float*)d_in[1];
    const float* conv1_w = (const float*)d_in[2];
    const float* conv1_b = (const float*)d_in[3];
    const float* conv2_w = (const float*)d_in[4];
    const float* conv2_b = (const float*)d_in[5];
    const float* gn_g    = (const float*)d_in[6];
    const float* gn_b    = (const float*)d_in[7];
    const float* ln2_g   = (const float*)d_in[8];
    const float* ln2_b   = (const float*)d_in[9];
    const float* ln3_g   = (const float*)d_in[10];
    const float* ln3_b   = (const float*)d_in[11];
    const float* ln4_g   = (const float*)d_in[12];
    const float* ln4_b   = (const float*)d_in[13];
    const float* sa_qw   = (const float*)d_in[14];
    const float* sa_qb   = (const float*)d_in[15];
    const float* sa_kw   = (const float*)d_in[16];
    const float* sa_kb   = (const float*)d_in[17];
    const float* sa_vw   = (const float*)d_in[18];
    const float* sa_vb   = (const float*)d_in[19];
    const float* sa_ow   = (const float*)d_in[20];
    const float* sa_ob   = (const float*)d_in[21];
    const float* ca_qw   = (const float*)d_in[22];
    const float* ca_qb   = (const float*)d_in[23];
    const float* ca_kw   = (const float*)d_in[24];
    const float* ca_kb   = (const float*)d_in[25];
    const float* ca_vw   = (const float*)d_in[26];
    const float* ca_vb   = (const float*)d_in[27];
    const float* ca_ow   = (const float*)d_in[28];
    const float* ca_ob   = (const float*)d_in[29];
    const float* ff1_w   = (const float*)d_in[30];
    const float* ff1_b   = (const float*)d_in[31];

    float* ws = (float*)d_ws;
    const size_t NBUF = (size_t)NBATCH * LTOK * FD;   // 1,048,576 elements
    float* partS  = ws;                    // 1024
    float* partSS = ws + 1024;             // 1024
    float* A      = ws + 4096;             // xs0, 4 MB
    ushort* Kb    = (ushort*)(A + NBUF);   // 2 MB
    ushort* VTgb  = Kb + NBUF;             // 2 MB
    ushort* Qb    = VTgb + NBUF;           // 2 MB
    float* Zp1    = (float*)(Qb + NBUF);   // 4 MB
    float* Zp2    = Zp1 + NBUF;            // 4 MB
    float* Zp3    = Zp2 + NBUF;            // 4 MB
    float* Ls     = Zp3 + NBUF;            // 512 KB (4 x 32768 floats)
    float* Zp0    = (float*)d_out;         // 4 MB scratch; tail reads == writes per block

    gn_part_kernel<<<256, 256, 0, stream>>>(x, partS, partSS);
    gn_conv1_kernel<<<256, 256, 0, stream>>>(x, partS, partSS, gn_g, gn_b, conv1_w, conv1_b, A);
    qkv_kernel<<<dim3(256, 3), 256, 0, stream>>>(A, sa_qw, sa_qb, sa_kw, sa_kb, sa_vw, sa_vb, Qb, Kb, VTgb);
    flash_mfma<<<dim3(32, 8, KSPLIT), 256, 0, stream>>>(Qb, Kb, VTgb, Zp0, Zp1, Zp2, Zp3, Ls);
    tail_fused<<<512, 256, 0, stream>>>(Zp0, Zp1, Zp2, Zp3, Ls, A, slots,
                                        ca_kw, ca_kb, ca_vw, ca_vb,
                                        sa_ow, sa_ob, ln2_g, ln2_b,
                                        ca_qw, ca_qb, ca_ow, ca_ob, ln3_g, ln3_b,
                                        ff1_w, ff1_b, ln4_g, ln4_b,
                                        conv2_w, conv2_b, (float*)d_out);
}

// Round 7
// 90.847 us; speedup vs baseline: 8.8926x; 1.0406x over previous
//
#include <hip/hip_runtime.h>
#include <hip/hip_bf16.h>
#include <math.h>

#define NBATCH 4
#define LTOK   4096
#define FD     64
#define KSPLIT 8
#define NIT    8     // staged 64-k tiles per flash block = 4096/KSPLIT/64

typedef __attribute__((ext_vector_type(8))) short short8v;   // 8 bf16 = 4 VGPR
typedef __attribute__((ext_vector_type(4))) float f32x4;
typedef __attribute__((ext_vector_type(16))) float f32x16;

static __device__ inline uint32_t packbf2(float a, float b) {
    float2 f; f.x = a; f.y = b;
    __hip_bfloat162 h = __float22bfloat162_rn(f);
    uint32_t u; __builtin_memcpy(&u, &h, 4);
    return u;
}
static __device__ inline ushort packbf1(float a) {
    __hip_bfloat16 h = __float2bfloat16(a);
    ushort u; __builtin_memcpy(&u, &h, 2);
    return u;
}
static __device__ inline float gelu_exact(float y) {
    return 0.5f * y * (1.0f + erff(y * 0.70710678118654752f));
}

// ---------------------------------------------------------------------------
// K1: GroupNorm partial sums. 256 blocks (64 chunks per batch), coalesced.
__global__ void gn_part_kernel(const float* __restrict__ x,
                               float* __restrict__ partS, float* __restrict__ partSS) {
    const int b = blockIdx.x >> 6, c = blockIdx.x & 63;
    const int t = threadIdx.x, l = t & 63, wv = t >> 6;
    const float4* xb = (const float4*)(x + (size_t)b * 262144) + (size_t)c * 1024;
    float s = 0.f, ss = 0.f;
#pragma unroll
    for (int k = 0; k < 4; k++) {
        float4 v = xb[t + 256 * k];
        s += (v.x + v.y) + (v.z + v.w);
        ss += (v.x * v.x + v.y * v.y) + (v.z * v.z + v.w * v.w);
    }
#pragma unroll
    for (int o = 0; o < 4; o++) {
        const int off = (int[]){1, 2, 16, 32}[o];
        s += __shfl_xor(s, off, 64);
        ss += __shfl_xor(ss, off, 64);
    }
    __shared__ float ls_s[4][4], ls_ss[4][4];
    if ((l & 51) == 0) { ls_s[wv][(l >> 2) & 3] = s; ls_ss[wv][(l >> 2) & 3] = ss; }
    __syncthreads();
    if (t < 4) {
        float S = 0.f, SS = 0.f;
#pragma unroll
        for (int w2 = 0; w2 < 4; w2++) { S += ls_s[w2][t]; SS += ls_ss[w2][t]; }
        partS[b * 256 + t * 64 + c] = S;
        partSS[b * 256 + t * 64 + c] = SS;
    }
}

// ---------------------------------------------------------------------------
// K2: combine partials + GN-apply + conv1 + channels-first reshape.
__global__ void gn_conv1_kernel(const float* __restrict__ x,
                                const float* __restrict__ partS, const float* __restrict__ partSS,
                                const float* __restrict__ gg, const float* __restrict__ gb,
                                const float* __restrict__ w, const float* __restrict__ bias,
                                float* __restrict__ out) {
    const int b = blockIdx.x >> 6, i = blockIdx.x & 63;
    const int t = threadIdx.x;
    __shared__ float xn[64][65];
    __shared__ float wsm[64][64];   // [c][o]
    __shared__ float sm[4], sr[4];
    {
        float sv = partS[b * 256 + t];     // g = t>>6, chunk = t&63
        float ssv = partSS[b * 256 + t];
        for (int o = 32; o; o >>= 1) { sv += __shfl_xor(sv, o, 64); ssv += __shfl_xor(ssv, o, 64); }
        if ((t & 63) == 0) {
            float mean = sv * (1.f / 65536.f);
            float var = ssv * (1.f / 65536.f) - mean * mean;
            sm[t >> 6] = mean;
            sr[t >> 6] = rsqrtf(var + 1e-5f);
        }
    }
    __syncthreads();
    {
        const int j = t >> 2, c0 = (t & 3) * 16, g = c0 >> 4;
        const float mean = sm[g], rstd = sr[g];
        const float* src = x + (((size_t)b * 64 + i) * 64 + j) * 64 + c0;
#pragma unroll
        for (int k = 0; k < 4; k++) {
            float4 v = *(const float4*)(src + 4 * k);
            xn[j][c0 + 4 * k + 0] = (v.x - mean) * rstd * gg[c0 + 4 * k + 0] + gb[c0 + 4 * k + 0];
            xn[j][c0 + 4 * k + 1] = (v.y - mean) * rstd * gg[c0 + 4 * k + 1] + gb[c0 + 4 * k + 1];
            xn[j][c0 + 4 * k + 2] = (v.z - mean) * rstd * gg[c0 + 4 * k + 2] + gb[c0 + 4 * k + 2];
            xn[j][c0 + 4 * k + 3] = (v.w - mean) * rstd * gg[c0 + 4 * k + 3] + gb[c0 + 4 * k + 3];
        }
        const int o = t >> 2, cc0 = (t & 3) * 16;
#pragma unroll
        for (int k = 0; k < 16; k++) wsm[cc0 + k][o] = w[o * 64 + cc0 + k];
    }
    __syncthreads();
    const int jj = t & 63, olo = (t >> 6) * 16;
    float acc[16];
#pragma unroll
    for (int oi = 0; oi < 16; oi++) acc[oi] = bias[olo + oi];
    for (int c = 0; c < 64; c++) {
        float xv = xn[jj][c];
#pragma unroll
        for (int oi = 0; oi < 16; oi++) acc[oi] += xv * wsm[c][olo + oi];
    }
#pragma unroll
    for (int oi = 0; oi < 16; oi++)
        out[((size_t)b * LTOK + (size_t)(olo + oi) * 64 + i) * 64 + jj] = acc[oi];
}

// ---------------------------------------------------------------------------
// K3: Q/K/V projection, one phase per block (grid 256 x 3).
__global__ void qkv_kernel(const float* __restrict__ in,
                           const float* __restrict__ qw, const float* __restrict__ qb,
                           const float* __restrict__ kw, const float* __restrict__ kb,
                           const float* __restrict__ vw, const float* __restrict__ vb,
                           ushort* __restrict__ Qo, ushort* __restrict__ Ko, ushort* __restrict__ VTg) {
    __shared__ float xt[64][68];
    __shared__ float wt[64][64];
    __shared__ ushort vtr[64 * 72];
    const int t = threadIdx.x;
    const int ph = blockIdx.y;
    const size_t tok0 = (size_t)blockIdx.x * 64;
    const int b = blockIdx.x >> 6;
    const int tokb0 = (blockIdx.x & 63) * 64;
    const int r = t >> 2, cq = t & 3, olo = cq * 16;
    const float* W = (ph == 0) ? qw : (ph == 1) ? kw : vw;
    const float* Bb = (ph == 0) ? qb : (ph == 1) ? kb : vb;
    {
        const float4* src = (const float4*)(in + tok0 * 64) + (size_t)t * 4;
        float4* dst = (float4*)&xt[r][olo];
#pragma unroll
        for (int k = 0; k < 4; k++) dst[k] = src[k];
        const float4* ws2 = (const float4*)W + (size_t)t * 4;
        float4* wd = (float4*)wt + (size_t)t * 4;
#pragma unroll
        for (int k = 0; k < 4; k++) wd[k] = ws2[k];
    }
    __syncthreads();
    float acc[16];
#pragma unroll
    for (int k = 0; k < 4; k++) {
        float4 bv = *(const float4*)(Bb + olo + 4 * k);
        acc[4 * k] = bv.x; acc[4 * k + 1] = bv.y; acc[4 * k + 2] = bv.z; acc[4 * k + 3] = bv.w;
    }
    for (int f = 0; f < 64; f++) {
        float xv = xt[r][f];
#pragma unroll
        for (int oi = 0; oi < 16; oi++) acc[oi] += xv * wt[f][olo + oi];
    }
    if (ph < 2) {
        const float sc = (ph == 0) ? 0.180336880111f : 1.0f;   // 0.125 * log2(e)
        uint32_t u[8];
#pragma unroll
        for (int i = 0; i < 8; i++) u[i] = packbf2(acc[2 * i] * sc, acc[2 * i + 1] * sc);
        ushort* op = (ph == 0 ? Qo : Ko) + (tok0 + r) * 64 + olo;
        *(uint4*)op = make_uint4(u[0], u[1], u[2], u[3]);
        *(uint4*)(op + 8) = make_uint4(u[4], u[5], u[6], u[7]);
    } else {
#pragma unroll
        for (int oi = 0; oi < 16; oi++) vtr[(olo + oi) * 72 + r] = packbf1(acc[oi]);
        __syncthreads();
        const int o = t >> 2, ch = t & 3;
        uint4 a0 = *(const uint4*)&vtr[o * 72 + ch * 16];
        uint4 a1 = *(const uint4*)&vtr[o * 72 + ch * 16 + 8];
        ushort* op = VTg + (size_t)(b * 64 + o) * 4096 + tokb0 + ch * 16;
        *(uint4*)op = a0;
        *(uint4*)(op + 8) = a1;
    }
}

// ---------------------------------------------------------------------------
// K4: MFMA flash self-attention, 32x32x16 MFMA, max-free softmax, K-split x8.
// Block: 4 waves x 32 q (QBLK=128). Grid (32, 8, 8). Sigma half-swap via
// v_permlane32_swap_b32 (1 inst per word pair). Partials written bf16.
__global__ __launch_bounds__(256) void flash_mfma(const ushort* __restrict__ Q,
                                                  const ushort* __restrict__ K,
                                                  const ushort* __restrict__ VTg,
                                                  ushort* __restrict__ ZpAll,
                                                  float* __restrict__ Ls) {
    const int qt = blockIdx.x;            // 0..31
    const int bh = blockIdx.y;            // 0..7
    const int ks = blockIdx.z;            // 0..7
    const int b = bh >> 1, h = bh & 1;
    const int t = threadIdx.x;
    const int w = t >> 6, l = t & 63, lq = l & 31, sig = l >> 5;

    __shared__ ushort KsB[2][2048];       // [k][dh] swz ^((k&7)<<3)
    __shared__ ushort VTB[2][2048];       // [dh][k] swz ^((dh&7)<<3)

    const size_t base = (size_t)b * LTOK * 64 + h * 32;
    const size_t vrow0 = (size_t)(b * 64 + h * 32);

    const int qrow = qt * 128 + w * 32 + lq;
    const short8v qf0 = *(const short8v*)(Q + base + (size_t)qrow * 64 + 8 * sig);
    const short8v qf1 = *(const short8v*)(Q + base + (size_t)qrow * 64 + 16 + 8 * sig);

    const int krow = t >> 2, kdg = t & 3;
    const int koff = ((krow << 5) + kdg * 8) ^ ((krow & 7) << 3);
    const int vrow = t >> 3, vc8 = t & 7;
    const int voff = ((vrow << 6) + vc8 * 8) ^ ((vrow & 7) << 3);
    const ushort* kgp = K + base + (size_t)(ks * NIT * 64 + krow) * 64 + kdg * 8;
    const ushort* vgp = VTg + (vrow0 + vrow) * 4096 + ks * NIT * 64 + vc8 * 8;

    *(uint4*)&KsB[0][koff] = *(const uint4*)kgp;  kgp += 64 * 64;
    *(uint4*)&VTB[0][voff] = *(const uint4*)vgp;  vgp += 64;

    f32x16 accZ;
#pragma unroll
    for (int i = 0; i < 16; i++) accZ[i] = 0.f;
    f32x16 zero16;
#pragma unroll
    for (int i = 0; i < 16; i++) zero16[i] = 0.f;
    float lacc = 0.0f;

    auto body = [&](const ushort* Kc, const ushort* Vc, ushort* Kn, ushort* Vn, bool pref) {
        __syncthreads();
        uint4 kq = make_uint4(0, 0, 0, 0), vq = make_uint4(0, 0, 0, 0);
        if (pref) {
            kq = *(const uint4*)kgp; kgp += 64 * 64;
            vq = *(const uint4*)vgp; vgp += 64;
        }
#pragma unroll
        for (int kb2 = 0; kb2 < 2; kb2++) {
            const int kb = kb2 * 32;
            const int kr = kb + lq;
            // --- S^T = K . Q^T : 2 MFMAs over dh chunks ---
            const short8v aK0 = *(const short8v*)&Kc[((kr << 5) + 8 * sig) ^ ((kr & 7) << 3)];
            const short8v aK1 = *(const short8v*)&Kc[((kr << 5) + 16 + 8 * sig) ^ ((kr & 7) << 3)];
            f32x16 st = __builtin_amdgcn_mfma_f32_32x32x16_bf16(aK0, qf0, zero16, 0, 0, 0);
            st = __builtin_amdgcn_mfma_f32_32x32x16_bf16(aK1, qf1, st, 0, 0, 0);
            // --- max-free softmax, lane-local: p = exp2(s) ---
            uint32_t pk[8];
#pragma unroll
            for (int i = 0; i < 8; i++) {
                float p0 = __builtin_amdgcn_exp2f(st[2 * i]);
                float p1 = __builtin_amdgcn_exp2f(st[2 * i + 1]);
                lacc += p0 + p1;
                pk[i] = packbf2(p0, p1);
            }
            // --- P -> A-fragment: sigma half-swap via v_permlane32_swap_b32 ---
            uint32_t a0w0 = pk[0], a0w2 = pk[2];
            uint32_t a0w1 = pk[1], a0w3 = pk[3];
            uint32_t a1w0 = pk[4], a1w2 = pk[6];
            uint32_t a1w1 = pk[5], a1w3 = pk[7];
            asm volatile("v_permlane32_swap_b32 %0, %1" : "+v"(a0w0), "+v"(a0w2));
            asm volatile("v_permlane32_swap_b32 %0, %1" : "+v"(a0w1), "+v"(a0w3));
            asm volatile("v_permlane32_swap_b32 %0, %1" : "+v"(a1w0), "+v"(a1w2));
            asm volatile("v_permlane32_swap_b32 %0, %1" : "+v"(a1w1), "+v"(a1w3));
            uint4 A0 = make_uint4(a0w0, a0w1, a0w2, a0w3);
            uint4 A1 = make_uint4(a1w0, a1w1, a1w2, a1w3);
            short8v aP0, aP1;
            __builtin_memcpy(&aP0, &A0, 16);
            __builtin_memcpy(&aP1, &A1, 16);
            // --- PV: B = V^T fragment reads ---
            const short8v vt0 = *(const short8v*)&Vc[((lq << 6) + kb + 8 * sig) ^ ((lq & 7) << 3)];
            const short8v vt1 = *(const short8v*)&Vc[((lq << 6) + kb + 16 + 8 * sig) ^ ((lq & 7) << 3)];
            accZ = __builtin_amdgcn_mfma_f32_32x32x16_bf16(aP0, vt0, accZ, 0, 0, 0);
            accZ = __builtin_amdgcn_mfma_f32_32x32x16_bf16(aP1, vt1, accZ, 0, 0, 0);
        }
        if (pref) {
            *(uint4*)&Kn[koff] = kq;
            *(uint4*)&Vn[voff] = vq;
        }
    };

#pragma unroll 1
    for (int it = 0; it < NIT / 2; it++) {
        body(KsB[0], VTB[0], KsB[1], VTB[1], true);
        body(KsB[1], VTB[1], KsB[0], VTB[0], it < NIT / 2 - 1);
    }

    ushort* Zo = ZpAll + (size_t)ks * (NBATCH * LTOK * FD);
#pragma unroll
    for (int r = 0; r < 16; r++) {
        const int qr = qt * 128 + w * 32 + (r & 3) + 8 * (r >> 2) + 4 * sig;
        Zo[base + (size_t)qr * 64 + lq] = packbf1(accZ[r]);
    }
    lacc += __shfl_xor(lacc, 32, 64);
    if (l < 32)
        Ls[ks * 32768 + bh * 4096 + qt * 128 + w * 32 + lq] = lacc;
}

// ---------------------------------------------------------------------------
// K8: fused tail — Z-combine(8 bf16) + ow+LN2+GELU, ca_kv, ca_q, cross-attn,
// ca_ow+LN3, ff1+LN4, conv2. 512 blocks x 256 threads, 32 tokens per block.
__global__ __launch_bounds__(256) void tail_fused(
    const ushort* __restrict__ ZpAll,
    const float* __restrict__ Ls, const float* __restrict__ xs0,
    const float* __restrict__ slots,
    const float* __restrict__ ckw, const float* __restrict__ ckb,
    const float* __restrict__ cvw, const float* __restrict__ cvb,
    const float* __restrict__ ow, const float* __restrict__ ob,
    const float* __restrict__ g2, const float* __restrict__ b2,
    const float* __restrict__ qw, const float* __restrict__ qb,
    const float* __restrict__ cow, const float* __restrict__ cob,
    const float* __restrict__ g3, const float* __restrict__ b3,
    const float* __restrict__ fw, const float* __restrict__ fb,
    const float* __restrict__ g4, const float* __restrict__ b4,
    const float* __restrict__ cw, const float* __restrict__ cb,
    float* __restrict__ out)
{
    const int t = threadIdx.x;
    const size_t tok0 = (size_t)blockIdx.x * 32;
    const int b = blockIdx.x >> 7;
    const int r = t >> 3, c = t & 7, olo = c * 8;
    __shared__ float xt[32][68];
    __shared__ float wt[64][64];
    __shared__ float kcs[512], vcs[512], sls[512];

    float acc[8], res[8];

    auto stage_w = [&](const float* W) {
#pragma unroll
        for (int k = 0; k < 4; k++)
            ((float4*)wt)[4 * t + k] = ((const float4*)W)[4 * t + k];
    };
    auto stage_x_res = [&]() {
        float4* xd = (float4*)&xt[r][olo];
        xd[0] = make_float4(res[0], res[1], res[2], res[3]);
        xd[1] = make_float4(res[4], res[5], res[6], res[7]);
    };
    auto load8 = [&](float* dst, const float* p) {
        float4 u0 = *(const float4*)(p + olo);
        float4 u1 = *(const float4*)(p + olo + 4);
        dst[0] = u0.x; dst[1] = u0.y; dst[2] = u0.z; dst[3] = u0.w;
        dst[4] = u1.x; dst[5] = u1.y; dst[6] = u1.z; dst[7] = u1.w;
    };
    auto mm = [&](const float* bias) {
        load8(acc, bias);
        for (int f = 0; f < 64; f++) {
            float xv = xt[r][f];
#pragma unroll
            for (int oi = 0; oi < 8; oi++) acc[oi] += xv * wt[f][olo + oi];
        }
    };
    auto ln = [&](const float* gv, const float* bv, bool dogelu) {
        float s1 = 0.f, s2 = 0.f;
#pragma unroll
        for (int oi = 0; oi < 8; oi++) { s1 += acc[oi]; s2 += acc[oi] * acc[oi]; }
#pragma unroll
        for (int o = 1; o <= 4; o <<= 1) {
            s1 += __shfl_xor(s1, o, 64);
            s2 += __shfl_xor(s2, o, 64);
        }
        float mean = s1 * (1.f / 64.f);
        float var = s2 * (1.f / 64.f) - mean * mean;
        float rstd = rsqrtf(var + 1e-5f);
        float gl[8], bl[8];
        load8(gl, gv); load8(bl, bv);
#pragma unroll
        for (int oi = 0; oi < 8; oi++) {
            float y = (acc[oi] - mean) * rstd * gl[oi] + bl[oi] + res[oi];
            res[oi] = dogelu ? gelu_exact(y) : y;
        }
    };

    // ---- phase 1: combine 8 bf16 flash partials, t0 = Z@ow+ob ; res = xs1
    {
        if (t < 128) ((float4*)sls)[t] = ((const float4*)(slots + (size_t)b * 512))[t];
        float zs[8];
#pragma unroll
        for (int j = 0; j < 8; j++) zs[j] = 0.f;
#pragma unroll
        for (int kb = 0; kb < KSPLIT; kb++) {
            const uint4 u = *(const uint4*)(ZpAll + (size_t)kb * (NBATCH * LTOK * FD)
                                            + tok0 * 64 + (size_t)t * 8);
            const uint32_t arr[4] = {u.x, u.y, u.z, u.w};
#pragma unroll
            for (int j = 0; j < 4; j++) {
                zs[2 * j]     += __uint_as_float(arr[j] << 16);
                zs[2 * j + 1] += __uint_as_float(arr[j] & 0xffff0000u);
            }
        }
        const int hh = olo >> 5;
        const int bh_ = b * 2 + hh;
        const int tokb = (blockIdx.x & 127) * 32 + r;
        float lt = 0.f;
#pragma unroll
        for (int kb = 0; kb < KSPLIT; kb++) lt += Ls[kb * 32768 + bh_ * 4096 + tokb];
        const float inv = 1.0f / lt;
        float4* xd = (float4*)&xt[r][olo];
        xd[0] = make_float4(zs[0] * inv, zs[1] * inv, zs[2] * inv, zs[3] * inv);
        xd[1] = make_float4(zs[4] * inv, zs[5] * inv, zs[6] * inv, zs[7] * inv);
        stage_w(ow);
        float4 r0 = *(const float4*)(xs0 + (tok0 + r) * 64 + olo);
        float4 r1 = *(const float4*)(xs0 + (tok0 + r) * 64 + olo + 4);
        res[0] = r0.x; res[1] = r0.y; res[2] = r0.z; res[3] = r0.w;
        res[4] = r1.x; res[5] = r1.y; res[6] = r1.z; res[7] = r1.w;
    }
    __syncthreads();
    // ---- cross-attn K/V from slots (redundant per block, cheap)
    for (int jo = t; jo < 512; jo += 256) {
        const int j = jo >> 6, o = jo & 63;
        float ak = ckb[o], av = cvb[o];
#pragma unroll 8
        for (int c2 = 0; c2 < 64; c2++) {
            float sv = sls[j * 64 + c2];
            ak += sv * ckw[c2 * 64 + o];
            av += sv * cvw[c2 * 64 + o];
        }
        kcs[jo] = ak; vcs[jo] = av;
    }
    mm(ob);
    ln(g2, b2, true);

    // ---- phase 2: qca = xs1@qw+qb ; acc = cross-attn(zca)
    __syncthreads();
    stage_x_res();
    stage_w(qw);
    __syncthreads();
    mm(qb);
    {
        float p[8];
        float mx = -3.0e38f;
#pragma unroll
        for (int j = 0; j < 8; j++) {
            float d = 0.f;
#pragma unroll
            for (int i2 = 0; i2 < 8; i2++) d += acc[i2] * kcs[j * 64 + olo + i2];
            d += __shfl_xor(d, 1, 64);
            d += __shfl_xor(d, 2, 64);
            d *= 0.125f;
            p[j] = d;
            mx = fmaxf(mx, d);
        }
        float es = 0.f;
#pragma unroll
        for (int j = 0; j < 8; j++) { p[j] = __expf(p[j] - mx); es += p[j]; }
        float inv = 1.f / es;
#pragma unroll
        for (int oi = 0; oi < 8; oi++) {
            float z = 0.f;
#pragma unroll
            for (int j = 0; j < 8; j++) z += p[j] * vcs[j * 64 + olo + oi];
            acc[oi] = z * inv;
        }
    }

    // ---- phase 3: t1 = zca@cow+cob ; res = xs2 = LN3(t1)+xs1
    __syncthreads();
    {
        float4* xd = (float4*)&xt[r][olo];
        xd[0] = make_float4(acc[0], acc[1], acc[2], acc[3]);
        xd[1] = make_float4(acc[4], acc[5], acc[6], acc[7]);
    }
    stage_w(cow);
    __syncthreads();
    mm(cob);
    ln(g3, b3, false);

    // ---- phase 4: t2 = xs2@fw+fb ; res = xs3 = LN4(t2)+xs2
    __syncthreads();
    stage_x_res();
    stage_w(fw);
    __syncthreads();
    mm(fb);
    ln(g4, b4, false);

    // ---- phase 5: out = xs3 @ conv2^T + cb
    __syncthreads();
    stage_x_res();
    {
        const int o5 = t >> 2, c5 = (t & 3) * 16;
#pragma unroll
        for (int k = 0; k < 16; k++) wt[c5 + k][o5] = cw[o5 * 64 + c5 + k];
    }
    __syncthreads();
    mm(cb);
    float* op = out + (tok0 + r) * 64 + olo;
    *(float4*)op = make_float4(acc[0], acc[1], acc[2], acc[3]);
    *(float4*)(op + 4) = make_float4(acc[4], acc[5], acc[6], acc[7]);
}

// ---------------------------------------------------------------------------
extern "C" void kernel_launch(void* const* d_in, const int* in_sizes, int n_in,
                              void* d_out, int out_size, void* d_ws, size_t ws_size,
                              hipStream_t stream) {
    const float* x       = (const float*)d_in[0];
    const float* slots   = (const float*)d_in[1];
    const float* conv1_w = (const float*)d_in[2];
    const float* conv1_b = (const float*)d_in[3];
    const float* conv2_w = (const float*)d_in[4];
    const float* conv2_b = (const float*)d_in[5];
    const float* gn_g    = (const float*)d_in[6];
    const float* gn_b    = (const float*)d_in[7];
    const float* ln2_g   = (const float*)d_in[8];
    const float* ln2_b   = (const float*)d_in[9];
    const float* ln3_g   = (const float*)d_in[10];
    const float* ln3_b   = (const float*)d_in[11];
    const float* ln4_g   = (const float*)d_in[12];
    const float* ln4_b   = (const float*)d_in[13];
    const float* sa_qw   = (const float*)d_in[14];
    const float* sa_qb   = (const float*)d_in[15];
    const float* sa_kw   = (const float*)d_in[16];
    const float* sa_kb   = (const float*)d_in[17];
    const float* sa_vw   = (const float*)d_in[18];
    const float* sa_vb   = (const float*)d_in[19];
    const float* sa_ow   = (const float*)d_in[20];
    const float* sa_ob   = (const float*)d_in[21];
    const float* ca_qw   = (const float*)d_in[22];
    const float* ca_qb   = (const float*)d_in[23];
    const float* ca_kw   = (const float*)d_in[24];
    const float* ca_kb   = (const float*)d_in[25];
    const float* ca_vw   = (const float*)d_in[26];
    const float* ca_vb   = (const float*)d_in[27];
    const float* ca_ow   = (const float*)d_in[28];
    const float* ca_ob   = (const float*)d_in[29];
    const float* ff1_w   = (const float*)d_in[30];
    const float* ff1_b   = (const float*)d_in[31];

    float* ws = (float*)d_ws;
    const size_t NBUF = (size_t)NBATCH * LTOK * FD;   // 1,048,576 elements
    float* partS  = ws;                    // 1024
    float* partSS = ws + 1024;             // 1024
    float* A      = ws + 4096;             // xs0, 4 MB
    ushort* Kb    = (ushort*)(A + NBUF);   // 2 MB
    ushort* VTgb  = Kb + NBUF;             // 2 MB
    ushort* Qb    = VTgb + NBUF;           // 2 MB
    ushort* ZpAll = Qb + NBUF;             // 8 x 2 MB bf16 partials
    float* Ls     = (float*)(ZpAll + (size_t)KSPLIT * NBUF);  // 8 x 32768 floats

    gn_part_kernel<<<256, 256, 0, stream>>>(x, partS, partSS);
    gn_conv1_kernel<<<256, 256, 0, stream>>>(x, partS, partSS, gn_g, gn_b, conv1_w, conv1_b, A);
    qkv_kernel<<<dim3(256, 3), 256, 0, stream>>>(A, sa_qw, sa_qb, sa_kw, sa_kb, sa_vw, sa_vb, Qb, Kb, VTgb);
    flash_mfma<<<dim3(32, 8, KSPLIT), 256, 0, stream>>>(Qb, Kb, VTgb, ZpAll, Ls);
    tail_fused<<<512, 256, 0, stream>>>(ZpAll, Ls, A, slots,
                                        ca_kw, ca_kb, ca_vw, ca_vb,
                                        sa_ow, sa_ob, ln2_g, ln2_b,
                                        ca_qw, ca_qb, ca_ow, ca_ob, ln3_g, ln3_b,
                                        ff1_w, ff1_b, ln4_g, ln4_b,
                                        conv2_w, conv2_b, (float*)d_out);
}

// Round 8
// 88.250 us; speedup vs baseline: 9.1544x; 1.0294x over previous
//
#include <hip/hip_runtime.h>
#include <hip/hip_bf16.h>
#include <math.h>

#define NBATCH 4
#define LTOK   4096
#define FD     64
#define KSPLIT 8
#define MBLK   16    // 32-k fragment blocks per flash block = 4096/KSPLIT/32

typedef __attribute__((ext_vector_type(8))) short short8v;   // 8 bf16 = 4 VGPR
typedef __attribute__((ext_vector_type(4))) float f32x4;
typedef __attribute__((ext_vector_type(16))) float f32x16;

static __device__ inline uint32_t packbf2(float a, float b) {
    float2 f; f.x = a; f.y = b;
    __hip_bfloat162 h = __float22bfloat162_rn(f);
    uint32_t u; __builtin_memcpy(&u, &h, 4);
    return u;
}
static __device__ inline ushort packbf1(float a) {
    __hip_bfloat16 h = __float2bfloat16(a);
    ushort u; __builtin_memcpy(&u, &h, 2);
    return u;
}
static __device__ inline float gelu_exact(float y) {
    return 0.5f * y * (1.0f + erff(y * 0.70710678118654752f));
}

// ---------------------------------------------------------------------------
// K1: GroupNorm partial sums. 256 blocks (64 chunks per batch), coalesced.
__global__ void gn_part_kernel(const float* __restrict__ x,
                               float* __restrict__ partS, float* __restrict__ partSS) {
    const int b = blockIdx.x >> 6, c = blockIdx.x & 63;
    const int t = threadIdx.x, l = t & 63, wv = t >> 6;
    const float4* xb = (const float4*)(x + (size_t)b * 262144) + (size_t)c * 1024;
    float s = 0.f, ss = 0.f;
#pragma unroll
    for (int k = 0; k < 4; k++) {
        float4 v = xb[t + 256 * k];
        s += (v.x + v.y) + (v.z + v.w);
        ss += (v.x * v.x + v.y * v.y) + (v.z * v.z + v.w * v.w);
    }
#pragma unroll
    for (int o = 0; o < 4; o++) {
        const int off = (int[]){1, 2, 16, 32}[o];
        s += __shfl_xor(s, off, 64);
        ss += __shfl_xor(ss, off, 64);
    }
    __shared__ float ls_s[4][4], ls_ss[4][4];
    if ((l & 51) == 0) { ls_s[wv][(l >> 2) & 3] = s; ls_ss[wv][(l >> 2) & 3] = ss; }
    __syncthreads();
    if (t < 4) {
        float S = 0.f, SS = 0.f;
#pragma unroll
        for (int w2 = 0; w2 < 4; w2++) { S += ls_s[w2][t]; SS += ls_ss[w2][t]; }
        partS[b * 256 + t * 64 + c] = S;
        partSS[b * 256 + t * 64 + c] = SS;
    }
}

// ---------------------------------------------------------------------------
// K2: combine partials + GN-apply + conv1 + channels-first reshape.
__global__ void gn_conv1_kernel(const float* __restrict__ x,
                                const float* __restrict__ partS, const float* __restrict__ partSS,
                                const float* __restrict__ gg, const float* __restrict__ gb,
                                const float* __restrict__ w, const float* __restrict__ bias,
                                float* __restrict__ out) {
    const int b = blockIdx.x >> 6, i = blockIdx.x & 63;
    const int t = threadIdx.x;
    __shared__ float xn[64][65];
    __shared__ float wsm[64][64];   // [c][o]
    __shared__ float sm[4], sr[4];
    {
        float sv = partS[b * 256 + t];     // g = t>>6, chunk = t&63
        float ssv = partSS[b * 256 + t];
        for (int o = 32; o; o >>= 1) { sv += __shfl_xor(sv, o, 64); ssv += __shfl_xor(ssv, o, 64); }
        if ((t & 63) == 0) {
            float mean = sv * (1.f / 65536.f);
            float var = ssv * (1.f / 65536.f) - mean * mean;
            sm[t >> 6] = mean;
            sr[t >> 6] = rsqrtf(var + 1e-5f);
        }
    }
    __syncthreads();
    {
        const int j = t >> 2, c0 = (t & 3) * 16, g = c0 >> 4;
        const float mean = sm[g], rstd = sr[g];
        const float* src = x + (((size_t)b * 64 + i) * 64 + j) * 64 + c0;
#pragma unroll
        for (int k = 0; k < 4; k++) {
            float4 v = *(const float4*)(src + 4 * k);
            xn[j][c0 + 4 * k + 0] = (v.x - mean) * rstd * gg[c0 + 4 * k + 0] + gb[c0 + 4 * k + 0];
            xn[j][c0 + 4 * k + 1] = (v.y - mean) * rstd * gg[c0 + 4 * k + 1] + gb[c0 + 4 * k + 1];
            xn[j][c0 + 4 * k + 2] = (v.z - mean) * rstd * gg[c0 + 4 * k + 2] + gb[c0 + 4 * k + 2];
            xn[j][c0 + 4 * k + 3] = (v.w - mean) * rstd * gg[c0 + 4 * k + 3] + gb[c0 + 4 * k + 3];
        }
        const int o = t >> 2, cc0 = (t & 3) * 16;
#pragma unroll
        for (int k = 0; k < 16; k++) wsm[cc0 + k][o] = w[o * 64 + cc0 + k];
    }
    __syncthreads();
    const int jj = t & 63, olo = (t >> 6) * 16;
    float acc[16];
#pragma unroll
    for (int oi = 0; oi < 16; oi++) acc[oi] = bias[olo + oi];
    for (int c = 0; c < 64; c++) {
        float xv = xn[jj][c];
#pragma unroll
        for (int oi = 0; oi < 16; oi++) acc[oi] += xv * wsm[c][olo + oi];
    }
#pragma unroll
    for (int oi = 0; oi < 16; oi++)
        out[((size_t)b * LTOK + (size_t)(olo + oi) * 64 + i) * 64 + jj] = acc[oi];
}

// ---------------------------------------------------------------------------
// K3: Q/K/V projection, one phase per block (grid 256 x 3).
// ph0: Q row-major (prescaled). ph1: K -> KF fragment layout.
// ph2: V -> VF fragment layout (via LDS transpose).
// Fragment layout: F[bh][m][f][lane=sig*32+idx][j] (16B per lane), where
//   KF: idx=tok%32, contents K[m*32+idx][h*32 + f*16 + sig*8 + j]
//   VF: idx=dh%32,  contents V[m*32 + f*16 + sig*8 + j][h*32 + idx]
__global__ void qkv_kernel(const float* __restrict__ in,
                           const float* __restrict__ qw, const float* __restrict__ qb,
                           const float* __restrict__ kw, const float* __restrict__ kb,
                           const float* __restrict__ vw, const float* __restrict__ vb,
                           ushort* __restrict__ Qo, ushort* __restrict__ KF, ushort* __restrict__ VF) {
    __shared__ float xt[64][68];
    __shared__ float wt[64][64];
    __shared__ ushort vtr[64 * 72];
    const int t = threadIdx.x;
    const int ph = blockIdx.y;
    const size_t tok0 = (size_t)blockIdx.x * 64;
    const int b = blockIdx.x >> 6;
    const int tokb0 = (blockIdx.x & 63) * 64;
    const int r = t >> 2, cq = t & 3, olo = cq * 16;
    const float* W = (ph == 0) ? qw : (ph == 1) ? kw : vw;
    const float* Bb = (ph == 0) ? qb : (ph == 1) ? kb : vb;
    {
        const float4* src = (const float4*)(in + tok0 * 64) + (size_t)t * 4;
        float4* dst = (float4*)&xt[r][olo];
#pragma unroll
        for (int k = 0; k < 4; k++) dst[k] = src[k];
        const float4* ws2 = (const float4*)W + (size_t)t * 4;
        float4* wd = (float4*)wt + (size_t)t * 4;
#pragma unroll
        for (int k = 0; k < 4; k++) wd[k] = ws2[k];
    }
    __syncthreads();
    float acc[16];
#pragma unroll
    for (int k = 0; k < 4; k++) {
        float4 bv = *(const float4*)(Bb + olo + 4 * k);
        acc[4 * k] = bv.x; acc[4 * k + 1] = bv.y; acc[4 * k + 2] = bv.z; acc[4 * k + 3] = bv.w;
    }
    for (int f = 0; f < 64; f++) {
        float xv = xt[r][f];
#pragma unroll
        for (int oi = 0; oi < 16; oi++) acc[oi] += xv * wt[f][olo + oi];
    }
    if (ph == 0) {
        const float sc = 0.180336880111f;   // 0.125 * log2(e)
        uint32_t u[8];
#pragma unroll
        for (int i = 0; i < 8; i++) u[i] = packbf2(acc[2 * i] * sc, acc[2 * i + 1] * sc);
        ushort* op = Qo + (tok0 + r) * 64 + olo;
        *(uint4*)op = make_uint4(u[0], u[1], u[2], u[3]);
        *(uint4*)(op + 8) = make_uint4(u[4], u[5], u[6], u[7]);
    } else if (ph == 1) {
        uint32_t u[8];
#pragma unroll
        for (int i = 0; i < 8; i++) u[i] = packbf2(acc[2 * i], acc[2 * i + 1]);
        const int tokb = tokb0 + r;
        const int m = tokb >> 5, tq = tokb & 31;
        const int hh = cq >> 1, f = cq & 1;
        const int bhh = b * 2 + hh;
        ushort* p0 = KF + ((size_t)(bhh * 128 + m) * 2 + f) * 512;
        *(uint4*)(p0 + tq * 8)        = make_uint4(u[0], u[1], u[2], u[3]);   // sig=0
        *(uint4*)(p0 + (32 + tq) * 8) = make_uint4(u[4], u[5], u[6], u[7]);   // sig=1
    } else {
#pragma unroll
        for (int oi = 0; oi < 16; oi++) vtr[(olo + oi) * 72 + r] = packbf1(acc[oi]);
        __syncthreads();
        const int o = t >> 2, ch = t & 3;
        const int lq2 = o & 31, hh = o >> 5, bhh = b * 2 + hh;
        const int m = (tokb0 >> 5) + (ch >> 1), f = ch & 1;
        uint4 a0 = *(const uint4*)&vtr[o * 72 + ch * 16];
        uint4 a1 = *(const uint4*)&vtr[o * 72 + ch * 16 + 8];
        ushort* p0 = VF + ((size_t)(bhh * 128 + m) * 2 + f) * 512;
        *(uint4*)(p0 + lq2 * 8)        = a0;   // sig=0
        *(uint4*)(p0 + (32 + lq2) * 8) = a1;   // sig=1
    }
}

// ---------------------------------------------------------------------------
// K4: MFMA flash self-attention — NO LDS, NO barriers. K/V read directly from
// L2 in pre-packed fragment order (1 KB coalesced per wave-load). Each wave
// owns 64 q (two 32-q halves sharing every K/V fragment). Max-free softmax,
// K-split x8, bf16 partial outputs.
__global__ __launch_bounds__(256, 4) void flash_mfma(const ushort* __restrict__ Q,
                                                     const ushort* __restrict__ KF,
                                                     const ushort* __restrict__ VF,
                                                     ushort* __restrict__ ZpAll,
                                                     float* __restrict__ Ls) {
    const int qt = blockIdx.x;            // 0..15 (256-q tiles)
    const int bh = blockIdx.y;            // 0..7
    const int ks = blockIdx.z;            // 0..7
    const int b = bh >> 1, h = bh & 1;
    const int t = threadIdx.x;
    const int w = t >> 6, l = t & 63, lq = l & 31, sig = l >> 5;

    const size_t base = (size_t)b * LTOK * 64 + h * 32;
    const int q0 = qt * 256 + w * 64;

    // Q B-fragments for both q-halves (A: rows q0+lq, B: rows q0+32+lq)
    const ushort* qp = Q + base + (size_t)(q0 + lq) * 64 + 8 * sig;
    const short8v qfA0 = *(const short8v*)(qp);
    const short8v qfA1 = *(const short8v*)(qp + 16);
    const short8v qfB0 = *(const short8v*)(qp + 32 * 64);
    const short8v qfB1 = *(const short8v*)(qp + 32 * 64 + 16);

    const ushort* kfp = KF + ((size_t)(bh * 128 + ks * MBLK) * 2) * 512 + l * 8;
    const ushort* vfp = VF + ((size_t)(bh * 128 + ks * MBLK) * 2) * 512 + l * 8;

    f32x16 accA, accB, zero16;
#pragma unroll
    for (int i = 0; i < 16; i++) { accA[i] = 0.f; accB[i] = 0.f; zero16[i] = 0.f; }
    float laccA = 0.f, laccB = 0.f;

    auto mk_aP = [&](const f32x16& st, float& lacc, short8v& aP0v, short8v& aP1v) {
        uint32_t pk[8];
#pragma unroll
        for (int i = 0; i < 8; i++) {
            float p0 = __builtin_amdgcn_exp2f(st[2 * i]);
            float p1 = __builtin_amdgcn_exp2f(st[2 * i + 1]);
            lacc += p0 + p1;
            pk[i] = packbf2(p0, p1);
        }
        uint32_t w0 = pk[0], w2 = pk[2], w1 = pk[1], w3 = pk[3];
        uint32_t x0 = pk[4], x2 = pk[6], x1 = pk[5], x3 = pk[7];
        asm volatile("v_permlane32_swap_b32 %0, %1" : "+v"(w0), "+v"(w2));
        asm volatile("v_permlane32_swap_b32 %0, %1" : "+v"(w1), "+v"(w3));
        asm volatile("v_permlane32_swap_b32 %0, %1" : "+v"(x0), "+v"(x2));
        asm volatile("v_permlane32_swap_b32 %0, %1" : "+v"(x1), "+v"(x3));
        uint4 A0 = make_uint4(w0, w1, w2, w3), A1 = make_uint4(x0, x1, x2, x3);
        __builtin_memcpy(&aP0v, &A0, 16);
        __builtin_memcpy(&aP1v, &A1, 16);
    };

#pragma unroll 4
    for (int m = 0; m < MBLK; m++) {
        const short8v kf0 = *(const short8v*)kfp;
        const short8v kf1 = *(const short8v*)(kfp + 512);
        const short8v vf0 = *(const short8v*)vfp;
        const short8v vf1 = *(const short8v*)(vfp + 512);
        kfp += 1024; vfp += 1024;

        f32x16 st = __builtin_amdgcn_mfma_f32_32x32x16_bf16(kf0, qfA0, zero16, 0, 0, 0);
        st = __builtin_amdgcn_mfma_f32_32x32x16_bf16(kf1, qfA1, st, 0, 0, 0);
        short8v aPA0, aPA1;
        mk_aP(st, laccA, aPA0, aPA1);

        f32x16 st2 = __builtin_amdgcn_mfma_f32_32x32x16_bf16(kf0, qfB0, zero16, 0, 0, 0);
        st2 = __builtin_amdgcn_mfma_f32_32x32x16_bf16(kf1, qfB1, st2, 0, 0, 0);
        short8v aPB0, aPB1;
        mk_aP(st2, laccB, aPB0, aPB1);

        accA = __builtin_amdgcn_mfma_f32_32x32x16_bf16(aPA0, vf0, accA, 0, 0, 0);
        accA = __builtin_amdgcn_mfma_f32_32x32x16_bf16(aPA1, vf1, accA, 0, 0, 0);
        accB = __builtin_amdgcn_mfma_f32_32x32x16_bf16(aPB0, vf0, accB, 0, 0, 0);
        accB = __builtin_amdgcn_mfma_f32_32x32x16_bf16(aPB1, vf1, accB, 0, 0, 0);
    }

    ushort* Zo = ZpAll + (size_t)ks * (NBATCH * LTOK * FD);
#pragma unroll
    for (int r = 0; r < 16; r++) {
        const int qr = q0 + (r & 3) + 8 * (r >> 2) + 4 * sig;
        Zo[base + (size_t)qr * 64 + lq] = packbf1(accA[r]);
        Zo[base + (size_t)(qr + 32) * 64 + lq] = packbf1(accB[r]);
    }
    laccA += __shfl_xor(laccA, 32, 64);
    laccB += __shfl_xor(laccB, 32, 64);
    if (l < 32) {
        Ls[ks * 32768 + bh * 4096 + q0 + lq] = laccA;
        Ls[ks * 32768 + bh * 4096 + q0 + 32 + lq] = laccB;
    }
}

// ---------------------------------------------------------------------------
// K8: fused tail — Z-combine(8 bf16) + ow+LN2+GELU, ca_kv, ca_q, cross-attn,
// ca_ow+LN3, ff1+LN4, conv2. 512 blocks x 256 threads, 32 tokens per block.
__global__ __launch_bounds__(256) void tail_fused(
    const ushort* __restrict__ ZpAll,
    const float* __restrict__ Ls, const float* __restrict__ xs0,
    const float* __restrict__ slots,
    const float* __restrict__ ckw, const float* __restrict__ ckb,
    const float* __restrict__ cvw, const float* __restrict__ cvb,
    const float* __restrict__ ow, const float* __restrict__ ob,
    const float* __restrict__ g2, const float* __restrict__ b2,
    const float* __restrict__ qw, const float* __restrict__ qb,
    const float* __restrict__ cow, const float* __restrict__ cob,
    const float* __restrict__ g3, const float* __restrict__ b3,
    const float* __restrict__ fw, const float* __restrict__ fb,
    const float* __restrict__ g4, const float* __restrict__ b4,
    const float* __restrict__ cw, const float* __restrict__ cb,
    float* __restrict__ out)
{
    const int t = threadIdx.x;
    const size_t tok0 = (size_t)blockIdx.x * 32;
    const int b = blockIdx.x >> 7;
    const int r = t >> 3, c = t & 7, olo = c * 8;
    __shared__ float xt[32][68];
    __shared__ float wt[64][64];
    __shared__ float kcs[512], vcs[512], sls[512];

    float acc[8], res[8];

    auto stage_w = [&](const float* W) {
#pragma unroll
        for (int k = 0; k < 4; k++)
            ((float4*)wt)[4 * t + k] = ((const float4*)W)[4 * t + k];
    };
    auto stage_x_res = [&]() {
        float4* xd = (float4*)&xt[r][olo];
        xd[0] = make_float4(res[0], res[1], res[2], res[3]);
        xd[1] = make_float4(res[4], res[5], res[6], res[7]);
    };
    auto load8 = [&](float* dst, const float* p) {
        float4 u0 = *(const float4*)(p + olo);
        float4 u1 = *(const float4*)(p + olo + 4);
        dst[0] = u0.x; dst[1] = u0.y; dst[2] = u0.z; dst[3] = u0.w;
        dst[4] = u1.x; dst[5] = u1.y; dst[6] = u1.z; dst[7] = u1.w;
    };
    auto mm = [&](const float* bias) {
        load8(acc, bias);
        for (int f = 0; f < 64; f++) {
            float xv = xt[r][f];
#pragma unroll
            for (int oi = 0; oi < 8; oi++) acc[oi] += xv * wt[f][olo + oi];
        }
    };
    auto ln = [&](const float* gv, const float* bv, bool dogelu) {
        float s1 = 0.f, s2 = 0.f;
#pragma unroll
        for (int oi = 0; oi < 8; oi++) { s1 += acc[oi]; s2 += acc[oi] * acc[oi]; }
#pragma unroll
        for (int o = 1; o <= 4; o <<= 1) {
            s1 += __shfl_xor(s1, o, 64);
            s2 += __shfl_xor(s2, o, 64);
        }
        float mean = s1 * (1.f / 64.f);
        float var = s2 * (1.f / 64.f) - mean * mean;
        float rstd = rsqrtf(var + 1e-5f);
        float gl[8], bl[8];
        load8(gl, gv); load8(bl, bv);
#pragma unroll
        for (int oi = 0; oi < 8; oi++) {
            float y = (acc[oi] - mean) * rstd * gl[oi] + bl[oi] + res[oi];
            res[oi] = dogelu ? gelu_exact(y) : y;
        }
    };

    // ---- phase 1: combine 8 bf16 flash partials, t0 = Z@ow+ob ; res = xs1
    {
        if (t < 128) ((float4*)sls)[t] = ((const float4*)(slots + (size_t)b * 512))[t];
        float zs[8];
#pragma unroll
        for (int j = 0; j < 8; j++) zs[j] = 0.f;
#pragma unroll
        for (int kb = 0; kb < KSPLIT; kb++) {
            const uint4 u = *(const uint4*)(ZpAll + (size_t)kb * (NBATCH * LTOK * FD)
                                            + tok0 * 64 + (size_t)t * 8);
            const uint32_t arr[4] = {u.x, u.y, u.z, u.w};
#pragma unroll
            for (int j = 0; j < 4; j++) {
                zs[2 * j]     += __uint_as_float(arr[j] << 16);
                zs[2 * j + 1] += __uint_as_float(arr[j] & 0xffff0000u);
            }
        }
        const int hh = olo >> 5;
        const int bh_ = b * 2 + hh;
        const int tokb = (blockIdx.x & 127) * 32 + r;
        float lt = 0.f;
#pragma unroll
        for (int kb = 0; kb < KSPLIT; kb++) lt += Ls[kb * 32768 + bh_ * 4096 + tokb];
        const float inv = 1.0f / lt;
        float4* xd = (float4*)&xt[r][olo];
        xd[0] = make_float4(zs[0] * inv, zs[1] * inv, zs[2] * inv, zs[3] * inv);
        xd[1] = make_float4(zs[4] * inv, zs[5] * inv, zs[6] * inv, zs[7] * inv);
        stage_w(ow);
        float4 r0 = *(const float4*)(xs0 + (tok0 + r) * 64 + olo);
        float4 r1 = *(const float4*)(xs0 + (tok0 + r) * 64 + olo + 4);
        res[0] = r0.x; res[1] = r0.y; res[2] = r0.z; res[3] = r0.w;
        res[4] = r1.x; res[5] = r1.y; res[6] = r1.z; res[7] = r1.w;
    }
    __syncthreads();
    // ---- cross-attn K/V from slots (redundant per block, cheap)
    for (int jo = t; jo < 512; jo += 256) {
        const int j = jo >> 6, o = jo & 63;
        float ak = ckb[o], av = cvb[o];
#pragma unroll 8
        for (int c2 = 0; c2 < 64; c2++) {
            float sv = sls[j * 64 + c2];
            ak += sv * ckw[c2 * 64 + o];
            av += sv * cvw[c2 * 64 + o];
        }
        kcs[jo] = ak; vcs[jo] = av;
    }
    mm(ob);
    ln(g2, b2, true);

    // ---- phase 2: qca = xs1@qw+qb ; acc = cross-attn(zca)
    __syncthreads();
    stage_x_res();
    stage_w(qw);
    __syncthreads();
    mm(qb);
    {
        float p[8];
        float mx = -3.0e38f;
#pragma unroll
        for (int j = 0; j < 8; j++) {
            float d = 0.f;
#pragma unroll
            for (int i2 = 0; i2 < 8; i2++) d += acc[i2] * kcs[j * 64 + olo + i2];
            d += __shfl_xor(d, 1, 64);
            d += __shfl_xor(d, 2, 64);
            d *= 0.125f;
            p[j] = d;
            mx = fmaxf(mx, d);
        }
        float es = 0.f;
#pragma unroll
        for (int j = 0; j < 8; j++) { p[j] = __expf(p[j] - mx); es += p[j]; }
        float inv = 1.f / es;
#pragma unroll
        for (int oi = 0; oi < 8; oi++) {
            float z = 0.f;
#pragma unroll
            for (int j = 0; j < 8; j++) z += p[j] * vcs[j * 64 + olo + oi];
            acc[oi] = z * inv;
        }
    }

    // ---- phase 3: t1 = zca@cow+cob ; res = xs2 = LN3(t1)+xs1
    __syncthreads();
    {
        float4* xd = (float4*)&xt[r][olo];
        xd[0] = make_float4(acc[0], acc[1], acc[2], acc[3]);
        xd[1] = make_float4(acc[4], acc[5], acc[6], acc[7]);
    }
    stage_w(cow);
    __syncthreads();
    mm(cob);
    ln(g3, b3, false);

    // ---- phase 4: t2 = xs2@fw+fb ; res = xs3 = LN4(t2)+xs2
    __syncthreads();
    stage_x_res();
    stage_w(fw);
    __syncthreads();
    mm(fb);
    ln(g4, b4, false);

    // ---- phase 5: out = xs3 @ conv2^T + cb
    __syncthreads();
    stage_x_res();
    {
        const int o5 = t >> 2, c5 = (t & 3) * 16;
#pragma unroll
        for (int k = 0; k < 16; k++) wt[c5 + k][o5] = cw[o5 * 64 + c5 + k];
    }
    __syncthreads();
    mm(cb);
    float* op = out + (tok0 + r) * 64 + olo;
    *(float4*)op = make_float4(acc[0], acc[1], acc[2], acc[3]);
    *(float4*)(op + 4) = make_float4(acc[4], acc[5], acc[6], acc[7]);
}

// ---------------------------------------------------------------------------
extern "C" void kernel_launch(void* const* d_in, const int* in_sizes, int n_in,
                              void* d_out, int out_size, void* d_ws, size_t ws_size,
                              hipStream_t stream) {
    const float* x       = (const float*)d_in[0];
    const float* slots   = (const float*)d_in[1];
    const float* conv1_w = (const float*)d_in[2];
    const float* conv1_b = (const float*)d_in[3];
    const float* conv2_w = (const float*)d_in[4];
    const float* conv2_b = (const float*)d_in[5];
    const float* gn_g    = (const float*)d_in[6];
    const float* gn_b    = (const float*)d_in[7];
    const float* ln2_g   = (const float*)d_in[8];
    const float* ln2_b   = (const float*)d_in[9];
    const float* ln3_g   = (const float*)d_in[10];
    const float* ln3_b   = (const float*)d_in[11];
    const float* ln4_g   = (const float*)d_in[12];
    const float* ln4_b   = (const float*)d_in[13];
    const float* sa_qw   = (const float*)d_in[14];
    const float* sa_qb   = (const float*)d_in[15];
    const float* sa_kw   = (const float*)d_in[16];
    const float* sa_kb   = (const float*)d_in[17];
    const float* sa_vw   = (const float*)d_in[18];
    const float* sa_vb   = (const float*)d_in[19];
    const float* sa_ow   = (const float*)d_in[20];
    const float* sa_ob   = (const float*)d_in[21];
    const float* ca_qw   = (const float*)d_in[22];
    const float* ca_qb   = (const float*)d_in[23];
    const float* ca_kw   = (const float*)d_in[24];
    const float* ca_kb   = (const float*)d_in[25];
    const float* ca_vw   = (const float*)d_in[26];
    const float* ca_vb   = (const float*)d_in[27];
    const float* ca_ow   = (const float*)d_in[28];
    const float* ca_ob   = (const float*)d_in[29];
    const float* ff1_w   = (const float*)d_in[30];
    const float* ff1_b   = (const float*)d_in[31];

    float* ws = (float*)d_ws;
    const size_t NBUF = (size_t)NBATCH * LTOK * FD;   // 1,048,576 elements
    float* partS  = ws;                    // 1024
    float* partSS = ws + 1024;             // 1024
    float* A      = ws + 4096;             // xs0, 4 MB
    ushort* KF    = (ushort*)(A + NBUF);   // 2 MB (fragment layout)
    ushort* VF    = KF + NBUF;             // 2 MB (fragment layout)
    ushort* Qb    = VF + NBUF;             // 2 MB
    ushort* ZpAll = Qb + NBUF;             // 8 x 2 MB bf16 partials
    float* Ls     = (float*)(ZpAll + (size_t)KSPLIT * NBUF);  // 8 x 32768 floats

    gn_part_kernel<<<256, 256, 0, stream>>>(x, partS, partSS);
    gn_conv1_kernel<<<256, 256, 0, stream>>>(x, partS, partSS, gn_g, gn_b, conv1_w, conv1_b, A);
    qkv_kernel<<<dim3(256, 3), 256, 0, stream>>>(A, sa_qw, sa_qb, sa_kw, sa_kb, sa_vw, sa_vb, Qb, KF, VF);
    flash_mfma<<<dim3(16, 8, KSPLIT), 256, 0, stream>>>(Qb, KF, VF, ZpAll, Ls);
    tail_fused<<<512, 256, 0, stream>>>(ZpAll, Ls, A, slots,
                                        ca_kw, ca_kb, ca_vw, ca_vb,
                                        sa_ow, sa_ob, ln2_g, ln2_b,
                                        ca_qw, ca_qb, ca_ow, ca_ob, ln3_g, ln3_b,
                                        ff1_w, ff1_b, ln4_g, ln4_b,
                                        conv2_w, conv2_b, (float*)d_out);
}